// Round 1
// baseline (3172.840 us; speedup 1.0000x reference)
//
#include <hip/hip_runtime.h>
#include <math.h>

namespace {

constexpr int B_ = 8;
constexpr int S_ = 2048;
constexpr int D_ = 768;
constexpr int N_ = 196;     // image spatial
constexpr int NF_ = 99;     // image freq bins
constexpr int NFREQ_ = 257;
constexpr int NSEG_ = 9;
constexpr int NP_ = 512;
constexpr int STEP_ = 256;
constexpr float TWOPI_ = 6.28318530717958647692f;

// ---------------- transpose (B,2048,768) -> (B,768,2048) ----------------
__global__ __launch_bounds__(256) void k_transpose(const float* __restrict__ x,
                                                   float* __restrict__ xt) {
  __shared__ float tile[32][33];
  const int b = blockIdx.z;
  const int t0 = blockIdx.x * 32;
  const int d0 = blockIdx.y * 32;
  const int lx = threadIdx.x;
  const int ly = threadIdx.y;
  for (int i = ly; i < 32; i += 8)
    tile[i][lx] = x[((size_t)(b * S_ + t0 + i)) * D_ + d0 + lx];
  __syncthreads();
  for (int i = ly; i < 32; i += 8)
    xt[((size_t)(b * D_ + d0 + i)) * S_ + t0 + lx] = tile[lx][i];
}

// ------------- image rfft (ortho) + filter -> imgF (complex) -------------
// imgF[b,f,d] = (rfft(image)[b,f,d]^2) * (-(bank0+bank1)) / (196*99)
__global__ __launch_bounds__(256) void k_img_rfft_filter(
    const float* __restrict__ image, const float2* __restrict__ bank2,
    float2* __restrict__ imgF) {
  const int f = blockIdx.x;  // 0..98
  const int b = blockIdx.y;
  const int tid = threadIdx.x;
  __shared__ float ct[N_], st[N_];
  if (tid < N_) {
    const int r = (f * tid) % N_;
    float s, c;
    sincosf(TWOPI_ * (float)r / (float)N_, &s, &c);
    ct[tid] = c; st[tid] = s;
  }
  __syncthreads();
  for (int d = tid; d < D_; d += 256) {
    float re = 0.f, im = 0.f;
    const float* ip = image + (size_t)b * N_ * D_ + d;
    for (int t = 0; t < N_; ++t) {
      const float v = ip[(size_t)t * D_];
      re = fmaf(v, ct[t], re);
      im = fmaf(-v, st[t], im);
    }
    const float sc = 1.0f / (196.0f * 99.0f);
    const float pr = (re * re - im * im) * sc;
    const float pi2 = (2.f * re * im) * sc;
    const size_t fd = (size_t)f * D_ + d;
    const float2 c0 = bank2[fd];
    const float2 c1 = bank2[(size_t)NF_ * D_ + fd];
    const float fcr = -(c0.x + c1.x), fci = -(c0.y + c1.y);
    imgF[(size_t)(b * NF_ + f) * D_ + d] =
        make_float2(pr * fcr - pi2 * fci, pr * fci + pi2 * fcr);
  }
}

// ---------------- gate pooling: mean_f Re(imgF * gate_sel) ----------------
__global__ __launch_bounds__(256) void k_gate_pool(const float2* __restrict__ imgF,
                                                   const float2* __restrict__ gsel2,
                                                   float* __restrict__ gate0) {
  const int b = blockIdx.x;
  for (int d = threadIdx.x; d < D_; d += 256) {
    float acc = 0.f;
    for (int f = 0; f < NF_; ++f) {
      const float2 z = imgF[(size_t)(b * NF_ + f) * D_ + d];
      const float2 w = gsel2[(size_t)f * D_ + d];
      acc += z.x * w.x - z.y * w.y;
    }
    gate0[b * D_ + d] = acc * (1.0f / 99.0f);
  }
}

// ---------------- gate = gate0 @ W^T + b ----------------
__global__ __launch_bounds__(256) void k_gate_mm(const float* __restrict__ gate0,
                                                 const float* __restrict__ W,
                                                 const float* __restrict__ bias,
                                                 float* __restrict__ gate) {
  const int b = blockIdx.x;
  __shared__ float row[D_];
  for (int e = threadIdx.x; e < D_; e += 256) row[e] = gate0[b * D_ + e];
  __syncthreads();
  for (int d = threadIdx.x; d < D_; d += 256) {
    float acc = bias[d];
    const float* w = W + (size_t)d * D_;
    for (int e = 0; e < D_; e += 4) {
      const float4 wv = *reinterpret_cast<const float4*>(w + e);
      acc = fmaf(row[e], wv.x, acc);
      acc = fmaf(row[e + 1], wv.y, acc);
      acc = fmaf(row[e + 2], wv.z, acc);
      acc = fmaf(row[e + 3], wv.w, acc);
    }
    gate[b * D_ + d] = acc;
  }
}

// -------- image irfft (ortho, c2r: Im of DC/Nyquist ignored) + residual --------
__global__ __launch_bounds__(256) void k_img_irfft_add(const float2* __restrict__ imgF,
                                                       const float* __restrict__ image,
                                                       float* __restrict__ ximg) {
  const int t = blockIdx.x;  // 0..195
  const int b = blockIdx.y;
  const int tid = threadIdx.x;
  __shared__ float cf[NF_], sf[NF_];
  if (tid < NF_) {
    const int r = (t * tid) % N_;
    float s, c;
    sincosf(TWOPI_ * (float)r / (float)N_, &s, &c);
    cf[tid] = c; sf[tid] = s;
  }
  __syncthreads();
  const float sgn_ny = (t & 1) ? -1.f : 1.f;
  for (int d = tid; d < D_; d += 256) {
    const float2* zp = imgF + (size_t)b * NF_ * D_ + d;
    float acc = zp[0].x;  // DC: real part only
    for (int f = 1; f < NF_ - 1; ++f) {
      const float2 z = zp[(size_t)f * D_];
      acc += 2.f * (z.x * cf[f] - z.y * sf[f]);
    }
    acc += zp[(size_t)(NF_ - 1) * D_].x * sgn_ny;  // Nyquist: real only
    const size_t idx = (size_t)(b * N_ + t) * D_ + d;
    ximg[idx] = acc * (1.0f / 14.0f) + image[idx];  // 1/sqrt(196) = 1/14
  }
}

// ---- fused ecg: STFT -> power/2313 * filter * gate -> ISTFT -> /norm -> +ecg ----
// one block per (b,d); everything in LDS (38.5 KB)
__global__ __launch_bounds__(256) void k_ecg_fused(
    const float* __restrict__ ecgT, const float2* __restrict__ bank2,
    const float* __restrict__ gate, float* __restrict__ xtext) {
  const int bd = blockIdx.x;
  const int b = bd / D_;
  const int d = bd - b * D_;
  const int tid = threadIdx.x;

  __shared__ float sig[S_];                         // 8 KB
  __shared__ float win[NP_];                        // 2 KB
  __shared__ float Yre[NFREQ_ * NSEG_];             // 9.25 KB
  __shared__ float Yim[NFREQ_ * NSEG_];             // 9.25 KB
  __shared__ float acc[NP_ + (NSEG_ - 1) * STEP_];  // 2560 floats, 10 KB

  const float* src = ecgT + (size_t)bd * S_;
  for (int i = tid; i < S_; i += 256) sig[i] = src[i];
  for (int i = tid; i < NP_; i += 256)
    win[i] = 0.5f - 0.5f * cosf(TWOPI_ * (float)i / (float)NP_);
  for (int i = tid; i < NP_ + (NSEG_ - 1) * STEP_; i += 256) acc[i] = 0.f;
  __syncthreads();

  const float g = gate[bd];

  // ---- forward STFT (rotation-recurrence DFT) + filter + gate ----
  for (int p = tid; p < NFREQ_ * NSEG_; p += 256) {
    const int f = p / NFREQ_;        // frame-major: wave shares frame -> LDS broadcast
    const int k = p - f * NFREQ_;
    const int tbase = f * STEP_ - STEP_;
    const int n0 = (f == 0) ? STEP_ : 0;              // zero-padded boundary frames
    const int n1 = (f == NSEG_ - 1) ? STEP_ : NP_;
    float ca, sa, cr, ci;
    sincosf(TWOPI_ * (float)k * (1.0f / 512.0f), &sa, &ca);
    sincosf(TWOPI_ * (float)((k * n0) & 511) * (1.0f / 512.0f), &ci, &cr);
    float zr = 0.f, zi = 0.f;
    for (int n = n0; n < n1; ++n) {
      const float v = sig[tbase + n] * win[n];
      zr = fmaf(v, cr, zr);
      zi = fmaf(-v, ci, zi);
      const float nc = fmaf(cr, ca, -ci * sa);
      ci = fmaf(cr, sa, ci * ca);
      cr = nc;
    }
    zr *= (1.f / 256.f);  // /win_sum
    zi *= (1.f / 256.f);
    const float pr = (zr * zr - zi * zi) * (1.f / 2313.f);   // complex square / length
    const float pim = (2.f * zr * zi) * (1.f / 2313.f);
    const int s = k * NSEG_ + f;
    const float2 c0 = bank2[(size_t)s * D_ + d];
    const float2 c1 = bank2[(size_t)2313 * D_ + (size_t)s * D_ + d];
    const float fcr = -(c0.x + c1.x), fci = -(c0.y + c1.y);  // coef = -1 for both k
    Yre[s] = (pr * fcr - pim * fci) * g;
    Yim[s] = (pr * fci + pim * fcr) * g;
  }
  __syncthreads();

  // ---- inverse: xs = 0.5*win*(irfft-sum), overlap-add into acc ----
  // thread m handles outputs m and m+256 of each frame via (-1)^k symmetry
  const int m = tid;
  float cb, sb;
  sincosf(TWOPI_ * (float)m * (1.0f / 512.0f), &sb, &cb);
  for (int f = 0; f < NSEG_; ++f) {
    const float dc = Yre[f];          // k=0, real only (c2r semantics)
    const float ny = Yre[2304 + f];   // k=256, real only
    float cr = cb, ci = sb;           // k = 1
    float aE = 0.f, aO = 0.f;
    for (int k = 1; k < 256; k += 2) {
      int s = k * NSEG_ + f;          // odd k
      aO = fmaf(Yre[s], cr, aO);
      aO = fmaf(-Yim[s], ci, aO);
      float nc = fmaf(cr, cb, -ci * sb);
      ci = fmaf(cr, sb, ci * cb);
      cr = nc;
      if (k + 1 < 256) {              // even k
        s += NSEG_;
        aE = fmaf(Yre[s], cr, aE);
        aE = fmaf(-Yim[s], ci, aE);
        nc = fmaf(cr, cb, -ci * sb);
        ci = fmaf(cr, sb, ci * cb);
        cr = nc;
      }
    }
    const float sgn = (m & 1) ? -1.f : 1.f;
    const float xs1 = 0.5f * win[m] * (dc + 2.f * (aE + aO) + ny * sgn);
    const float xs2 = 0.5f * win[m + 256] * (dc + 2.f * (aE - aO) + ny * sgn);
    acc[f * STEP_ + m] += xs1;
    acc[f * STEP_ + m + 256] += xs2;
    __syncthreads();
  }

  // ---- normalize (exactly 2 window-sq contributions interior), +ecg, store ----
  for (int t = tid; t < S_; t += 256) {
    const int n = t & 255;
    const float w1 = win[n], w2 = win[n + 256];
    const float nrm = w1 * w1 + w2 * w2;   // >= 0.5, never below 1e-10
    const float val = acc[t + 256] / nrm;
    xtext[((size_t)(b * S_ + t)) * D_ + d] = val + sig[t];
  }
}

// ---------------- LayerNorm over D=768, one block per row ----------------
__global__ __launch_bounds__(256) void k_layernorm(const float* __restrict__ x,
                                                   const float* __restrict__ g,
                                                   const float* __restrict__ b,
                                                   float* __restrict__ out) {
  const int row = blockIdx.x;
  const int tid = threadIdx.x;
  const float* xr = x + (size_t)row * D_;
  const float v0 = xr[tid], v1 = xr[tid + 256], v2 = xr[tid + 512];
  float s = v0 + v1 + v2;
  float q = v0 * v0 + v1 * v1 + v2 * v2;
  __shared__ float red[8];
  for (int off = 32; off > 0; off >>= 1) {
    s += __shfl_down(s, off);
    q += __shfl_down(q, off);
  }
  if ((tid & 63) == 0) { red[tid >> 6] = s; red[4 + (tid >> 6)] = q; }
  __syncthreads();
  s = red[0] + red[1] + red[2] + red[3];
  q = red[4] + red[5] + red[6] + red[7];
  const float mean = s * (1.0f / 768.0f);
  const float var = q * (1.0f / 768.0f) - mean * mean;
  const float inv = rsqrtf(var + 1e-5f);
  float* orow = out + (size_t)row * D_;
  orow[tid]       = (v0 - mean) * inv * g[tid]       + b[tid];
  orow[tid + 256] = (v1 - mean) * inv * g[tid + 256] + b[tid + 256];
  orow[tid + 512] = (v2 - mean) * inv * g[tid + 512] + b[tid + 512];
}

// ---------- GEMM: out = act(A @ W^T + bias [+ resid]); A (M,768), W (768,768) ----------
// MODE 0: exact GELU ; MODE 1: + residual
template <int MODE>
__global__ __launch_bounds__(256) void k_gemm_ffn(
    const float* __restrict__ A, const float* __restrict__ W,
    const float* __restrict__ bias, const float* __restrict__ resid,
    float* __restrict__ out, int M) {
  __shared__ float As[16][64];
  __shared__ float Bs[16][64];
  const int tid = threadIdx.x;
  const int n0 = blockIdx.x * 64;
  const int m0 = blockIdx.y * 64;
  const int tm = tid & 15;
  const int tn = tid >> 4;
  const int lrow = tid >> 2;
  const int lcol = (tid & 3) << 2;
  float acc[4][4] = {};
  for (int k0 = 0; k0 < 768; k0 += 16) {
    float4 av = make_float4(0.f, 0.f, 0.f, 0.f);
    const int arow = m0 + lrow;
    if (arow < M)
      av = *reinterpret_cast<const float4*>(A + (size_t)arow * 768 + k0 + lcol);
    const float4 bv =
        *reinterpret_cast<const float4*>(W + (size_t)(n0 + lrow) * 768 + k0 + lcol);
    __syncthreads();
    As[lcol + 0][lrow] = av.x; As[lcol + 1][lrow] = av.y;
    As[lcol + 2][lrow] = av.z; As[lcol + 3][lrow] = av.w;
    Bs[lcol + 0][lrow] = bv.x; Bs[lcol + 1][lrow] = bv.y;
    Bs[lcol + 2][lrow] = bv.z; Bs[lcol + 3][lrow] = bv.w;
    __syncthreads();
#pragma unroll
    for (int kk = 0; kk < 16; ++kk) {
      const float4 a4 = *reinterpret_cast<const float4*>(&As[kk][tm << 2]);
      const float4 b4 = *reinterpret_cast<const float4*>(&Bs[kk][tn << 2]);
      const float aa[4] = {a4.x, a4.y, a4.z, a4.w};
      const float bb[4] = {b4.x, b4.y, b4.z, b4.w};
#pragma unroll
      for (int i = 0; i < 4; ++i)
#pragma unroll
        for (int j = 0; j < 4; ++j) acc[i][j] = fmaf(aa[i], bb[j], acc[i][j]);
    }
  }
#pragma unroll
  for (int i = 0; i < 4; ++i) {
    const int mrow = m0 + (tm << 2) + i;
    if (mrow >= M) continue;
#pragma unroll
    for (int j = 0; j < 4; ++j) {
      const int ncol = n0 + (tn << 2) + j;
      float v = acc[i][j] + bias[ncol];
      if (MODE == 0) {
        v = 0.5f * v * (1.0f + erff(v * 0.70710678118654752440f));  // exact GELU
      } else {
        v += resid[(size_t)mrow * 768 + ncol];
      }
      out[(size_t)mrow * 768 + ncol] = v;
    }
  }
}

}  // namespace

extern "C" void kernel_launch(void* const* d_in, const int* in_sizes, int n_in,
                              void* d_out, int out_size, void* d_ws, size_t ws_size,
                              hipStream_t stream) {
  (void)in_sizes; (void)n_in; (void)out_size; (void)ws_size;
  const float* ecg     = (const float*)d_in[0];
  const float* image   = (const float*)d_in[1];
  const float* ebank   = (const float*)d_in[2];
  const float* cbank   = (const float*)d_in[3];
  const float* gsel    = (const float*)d_in[4];
  const float* gw      = (const float*)d_in[5];
  const float* gb      = (const float*)d_in[6];
  const float* e_ln1_g = (const float*)d_in[7];
  const float* e_ln1_b = (const float*)d_in[8];
  const float* e_w1    = (const float*)d_in[9];
  const float* e_b1    = (const float*)d_in[10];
  const float* e_w2    = (const float*)d_in[11];
  const float* e_b2    = (const float*)d_in[12];
  const float* e_ln2_g = (const float*)d_in[13];
  const float* e_ln2_b = (const float*)d_in[14];
  const float* c_ln1_g = (const float*)d_in[15];
  const float* c_ln1_b = (const float*)d_in[16];
  const float* c_w1    = (const float*)d_in[17];
  const float* c_b1    = (const float*)d_in[18];
  const float* c_w2    = (const float*)d_in[19];
  const float* c_b2    = (const float*)d_in[20];
  const float* c_ln2_g = (const float*)d_in[21];
  const float* c_ln2_b = (const float*)d_in[22];

  float* out = (float*)d_out;
  float* ws = (float*)d_ws;

  constexpr size_t TXT  = (size_t)8 * 2048 * 768;     // 12,582,912
  constexpr size_t IMG  = (size_t)8 * 196 * 768;      // 1,204,224
  constexpr size_t IMGF = (size_t)8 * 99 * 768 * 2;   // 1,216,512

  // buffer lifetime reuse: total ws = 110.4 MB
  float* buf0  = ws;                 // ecgT, then xhat_text
  float* buf1  = buf0 + TXT;         // xtext, then y_text
  float* buf2  = buf1 + TXT;         // imgF, then xhat_img
  float* buf3  = buf2 + IMGF;        // ximg, then y_img
  float* gate0 = buf3 + IMG;
  float* gatev = gate0 + 8 * 768;

  float* h_text = out;               // GELU activations scratch inside d_out
  float* h_img  = out + TXT;

  // ---- image path (produces gate for ecg path) ----
  k_img_rfft_filter<<<dim3(99, 8), 256, 0, stream>>>(image, (const float2*)cbank,
                                                     (float2*)buf2);
  k_gate_pool<<<8, 256, 0, stream>>>((const float2*)buf2, (const float2*)gsel, gate0);
  k_gate_mm<<<8, 256, 0, stream>>>(gate0, gw, gb, gatev);
  k_img_irfft_add<<<dim3(196, 8), 256, 0, stream>>>((const float2*)buf2, image, buf3);

  // ---- ecg path ----
  k_transpose<<<dim3(64, 24, 8), dim3(32, 8), 0, stream>>>(ecg, buf0);
  k_ecg_fused<<<8 * 768, 256, 0, stream>>>(buf0, (const float2*)ebank, gatev, buf1);

  // ---- text AddNorm ----
  k_layernorm<<<16384, 256, 0, stream>>>(buf1, e_ln1_g, e_ln1_b, buf0);
  k_gemm_ffn<0><<<dim3(12, 256), 256, 0, stream>>>(buf0, e_w1, e_b1, nullptr, h_text, 16384);
  k_gemm_ffn<1><<<dim3(12, 256), 256, 0, stream>>>(h_text, e_w2, e_b2, buf0, buf1, 16384);
  k_layernorm<<<16384, 256, 0, stream>>>(buf1, e_ln2_g, e_ln2_b, out);

  // ---- image AddNorm ----
  k_layernorm<<<1568, 256, 0, stream>>>(buf3, c_ln1_g, c_ln1_b, buf2);
  k_gemm_ffn<0><<<dim3(12, 25), 256, 0, stream>>>(buf2, c_w1, c_b1, nullptr, h_img, 1568);
  k_gemm_ffn<1><<<dim3(12, 25), 256, 0, stream>>>(h_img, c_w2, c_b2, buf2, buf3, 1568);
  k_layernorm<<<1568, 256, 0, stream>>>(buf3, c_ln2_g, c_ln2_b, out + TXT);
}

// Round 2
// 1312.886 us; speedup vs baseline: 2.4167x; 2.4167x over previous
//
#include <hip/hip_runtime.h>
#include <math.h>

namespace {

constexpr int B_ = 8;
constexpr int S_ = 2048;
constexpr int D_ = 768;
constexpr int N_ = 196;     // image spatial
constexpr int NF_ = 99;     // image freq bins
constexpr int NFREQ_ = 257;
constexpr int NSEG_ = 9;
constexpr int NBINS_ = NFREQ_ * NSEG_;  // 2313
constexpr float TWOPI_ = 6.28318530717958647692f;

__device__ __forceinline__ int rev9(int x) { return (int)(__brev((unsigned)x) >> 23); }

// ---------------- generic batched transpose (B,R,C) -> (B,C,R) ----------------
// R, C multiples of 32
__global__ __launch_bounds__(256) void k_transpose_g(const float* __restrict__ src,
                                                     float* __restrict__ dst,
                                                     int R, int C) {
  __shared__ float tile[32][33];
  const int b = blockIdx.z;
  const int c0 = blockIdx.x * 32;
  const int r0 = blockIdx.y * 32;
  const int tx = threadIdx.x, ty = threadIdx.y;
  for (int i = ty; i < 32; i += 8)
    tile[i][tx] = src[((size_t)b * R + r0 + i) * C + c0 + tx];
  __syncthreads();
  for (int i = ty; i < 32; i += 8)
    dst[((size_t)b * C + c0 + i) * R + r0 + tx] = tile[tx][i];
}

// ---- combine + transpose filter bank: FcT[d][s] = -(e0[s][d] + e1[s][d]) ----
__global__ __launch_bounds__(256) void k_fc_transpose(const float2* __restrict__ e2,
                                                      float2* __restrict__ FcT) {
  __shared__ float2 tile[32][33];
  const int s0 = blockIdx.x * 32;
  const int d0 = blockIdx.y * 32;
  const int tx = threadIdx.x, ty = threadIdx.y;
  for (int i = ty; i < 32; i += 8) {
    const int s = s0 + i;
    if (s < NBINS_) {
      const float2 a = e2[(size_t)s * D_ + d0 + tx];
      const float2 b = e2[(size_t)NBINS_ * D_ + (size_t)s * D_ + d0 + tx];
      tile[i][tx] = make_float2(-(a.x + b.x), -(a.y + b.y));
    }
  }
  __syncthreads();
  for (int i = ty; i < 32; i += 8) {
    const int s = s0 + tx;
    if (s < NBINS_)
      FcT[(size_t)(d0 + i) * NBINS_ + s] = tile[tx][i];
  }
}

// ------------- image rfft (ortho) + filter -> imgF (complex) -------------
__global__ __launch_bounds__(256) void k_img_rfft_filter(
    const float* __restrict__ image, const float2* __restrict__ bank2,
    float2* __restrict__ imgF) {
  const int f = blockIdx.x;  // 0..98
  const int b = blockIdx.y;
  const int tid = threadIdx.x;
  __shared__ float ct[N_], st[N_];
  if (tid < N_) {
    const int r = (f * tid) % N_;
    float s, c;
    sincosf(TWOPI_ * (float)r / (float)N_, &s, &c);
    ct[tid] = c; st[tid] = s;
  }
  __syncthreads();
  for (int d = tid; d < D_; d += 256) {
    float re = 0.f, im = 0.f;
    const float* ip = image + (size_t)b * N_ * D_ + d;
    for (int t = 0; t < N_; ++t) {
      const float v = ip[(size_t)t * D_];
      re = fmaf(v, ct[t], re);
      im = fmaf(-v, st[t], im);
    }
    const float sc = 1.0f / (196.0f * 99.0f);
    const float pr = (re * re - im * im) * sc;
    const float pi2 = (2.f * re * im) * sc;
    const size_t fd = (size_t)f * D_ + d;
    const float2 c0 = bank2[fd];
    const float2 c1 = bank2[(size_t)NF_ * D_ + fd];
    const float fcr = -(c0.x + c1.x), fci = -(c0.y + c1.y);
    imgF[(size_t)(b * NF_ + f) * D_ + d] =
        make_float2(pr * fcr - pi2 * fci, pr * fci + pi2 * fcr);
  }
}

// ---------------- gate pooling: mean_f Re(imgF * gate_sel) ----------------
__global__ __launch_bounds__(256) void k_gate_pool(const float2* __restrict__ imgF,
                                                   const float2* __restrict__ gsel2,
                                                   float* __restrict__ gate0) {
  const int b = blockIdx.x;
  for (int d = threadIdx.x; d < D_; d += 256) {
    float acc = 0.f;
    for (int f = 0; f < NF_; ++f) {
      const float2 z = imgF[(size_t)(b * NF_ + f) * D_ + d];
      const float2 w = gsel2[(size_t)f * D_ + d];
      acc += z.x * w.x - z.y * w.y;
    }
    gate0[b * D_ + d] = acc * (1.0f / 99.0f);
  }
}

// ---------------- gate = gate0 @ W^T + b ----------------
__global__ __launch_bounds__(256) void k_gate_mm(const float* __restrict__ gate0,
                                                 const float* __restrict__ W,
                                                 const float* __restrict__ bias,
                                                 float* __restrict__ gate) {
  const int b = blockIdx.x;
  __shared__ float row[D_];
  for (int e = threadIdx.x; e < D_; e += 256) row[e] = gate0[b * D_ + e];
  __syncthreads();
  for (int d = threadIdx.x; d < D_; d += 256) {
    float acc = bias[d];
    const float* w = W + (size_t)d * D_;
    for (int e = 0; e < D_; e += 4) {
      const float4 wv = *reinterpret_cast<const float4*>(w + e);
      acc = fmaf(row[e], wv.x, acc);
      acc = fmaf(row[e + 1], wv.y, acc);
      acc = fmaf(row[e + 2], wv.z, acc);
      acc = fmaf(row[e + 3], wv.w, acc);
    }
    gate[b * D_ + d] = acc;
  }
}

// -------- image irfft (ortho, c2r: Im of DC/Nyquist ignored) + residual --------
__global__ __launch_bounds__(256) void k_img_irfft_add(const float2* __restrict__ imgF,
                                                       const float* __restrict__ image,
                                                       float* __restrict__ ximg) {
  const int t = blockIdx.x;  // 0..195
  const int b = blockIdx.y;
  const int tid = threadIdx.x;
  __shared__ float cf[NF_], sf[NF_];
  if (tid < NF_) {
    const int r = (t * tid) % N_;
    float s, c;
    sincosf(TWOPI_ * (float)r / (float)N_, &s, &c);
    cf[tid] = c; sf[tid] = s;
  }
  __syncthreads();
  const float sgn_ny = (t & 1) ? -1.f : 1.f;
  for (int d = tid; d < D_; d += 256) {
    const float2* zp = imgF + (size_t)b * NF_ * D_ + d;
    float acc = zp[0].x;  // DC: real part only
    for (int f = 1; f < NF_ - 1; ++f) {
      const float2 z = zp[(size_t)f * D_];
      acc += 2.f * (z.x * cf[f] - z.y * sf[f]);
    }
    acc += zp[(size_t)(NF_ - 1) * D_].x * sgn_ny;  // Nyquist: real only
    const size_t idx = (size_t)(b * N_ + t) * D_ + d;
    ximg[idx] = acc * (1.0f / 14.0f) + image[idx];
  }
}

// ---- fused ecg via LDS radix-2 FFT: STFT -> filter*gate -> ISTFT -> +ecg ----
// one block per (b,d); output written TRANSPOSED: xtT[b][d][t]
__global__ __launch_bounds__(256) void k_ecg_fft(
    const float* __restrict__ ecgT, const float2* __restrict__ FcT,
    const float* __restrict__ gate, float* __restrict__ xtT) {
  const int bd = blockIdx.x;   // b*768 + d
  const int d = bd % D_;
  const int tid = threadIdx.x;

  __shared__ float sig[S_];        // 8 KB
  __shared__ float twc[256];       // cos(2*pi*r/512)
  __shared__ float tws[256];       // sin(2*pi*r/512)
  __shared__ float2 z[512];        // 4 KB FFT work
  __shared__ float2 Yf[NFREQ_];    // per-frame filtered spectrum
  __shared__ float acc[2560];      // overlap-add, 10 KB

  const float* src = ecgT + (size_t)bd * S_;
  for (int i = tid; i < S_; i += 256) sig[i] = src[i];
  {
    float s, c;
    sincosf(TWOPI_ * (float)tid * (1.0f / 512.0f), &s, &c);
    twc[tid] = c; tws[tid] = s;
  }
  for (int i = tid; i < 2560; i += 256) acc[i] = 0.f;
  __syncthreads();

  const float g = gate[bd];
  const float2* fc = FcT + (size_t)d * NBINS_;

  for (int f = 0; f < NSEG_; ++f) {
    const int tbase = f * 256 - 256;
    // ---- load frame windowed, bit-reversed positions (DIT input) ----
    {
      int n = tid;  // win[n] = 0.5 - 0.5*twc[n]
      float v = (f == 0) ? 0.f : sig[tbase + n] * (0.5f - 0.5f * twc[tid]);
      z[rev9(n)] = make_float2(v, 0.f);
      n = tid + 256;  // win[n] = 0.5 + 0.5*twc[n-256]
      v = (f == NSEG_ - 1) ? 0.f : sig[tbase + n] * (0.5f + 0.5f * twc[tid]);
      z[rev9(n)] = make_float2(v, 0.f);
    }
    __syncthreads();
    // ---- forward FFT (DIT, dir = -1) ----
#pragma unroll
    for (int s = 0; s < 9; ++s) {
      const int h = 1 << s;
      const int j = tid & (h - 1);
      const int i0 = ((tid >> s) << (s + 1)) | j;
      const int i1 = i0 + h;
      const int r = j << (8 - s);
      const float wc = twc[r], ws = -tws[r];
      const float2 a = z[i0];
      const float2 bb = z[i1];
      const float br = bb.x * wc - bb.y * ws;
      const float bi = bb.x * ws + bb.y * wc;
      z[i0] = make_float2(a.x + br, a.y + bi);
      z[i1] = make_float2(a.x - br, a.y - bi);
      __syncthreads();
    }
    // ---- filter: power of Z/256, * FcT, * gate ----
    for (int k = tid; k <= 256; k += 256) {  // tid 0 does k=0 and k=256
      const float zr = z[k].x * (1.f / 256.f);
      const float zi = z[k].y * (1.f / 256.f);
      const float pr = (zr * zr - zi * zi) * (1.f / 2313.f);
      const float pi = (2.f * zr * zi) * (1.f / 2313.f);
      const float2 c = fc[k * 9 + f];
      Yf[k] = make_float2((pr * c.x - pi * c.y) * g, (pr * c.y + pi * c.x) * g);
    }
    __syncthreads();
    // ---- build full spectrum (conj-symmetric, DC/Ny imag dropped), bitrev ----
#pragma unroll
    for (int mm = 0; mm < 2; ++mm) {
      const int m = tid + mm * 256;
      float2 v;
      if (m == 0)        v = make_float2(Yf[0].x, 0.f);
      else if (m == 256) v = make_float2(Yf[256].x, 0.f);
      else if (m < 256)  v = Yf[m];
      else {
        const float2 y = Yf[512 - m];
        v = make_float2(y.x, -y.y);
      }
      z[rev9(m)] = v;
    }
    __syncthreads();
    // ---- inverse FFT (DIT, dir = +1, unnormalized; 256*(1/512)=0.5 folded below) ----
#pragma unroll
    for (int s = 0; s < 9; ++s) {
      const int h = 1 << s;
      const int j = tid & (h - 1);
      const int i0 = ((tid >> s) << (s + 1)) | j;
      const int i1 = i0 + h;
      const int r = j << (8 - s);
      const float wc = twc[r], ws = tws[r];
      const float2 a = z[i0];
      const float2 bb = z[i1];
      const float br = bb.x * wc - bb.y * ws;
      const float bi = bb.x * ws + bb.y * wc;
      z[i0] = make_float2(a.x + br, a.y + bi);
      z[i1] = make_float2(a.x - br, a.y - bi);
      __syncthreads();
    }
    // ---- overlap-add: xs[n] = 0.5 * win[n] * Re(x[n]) ----
    acc[f * 256 + tid]       += (0.5f - 0.5f * twc[tid]) * 0.5f * z[tid].x;
    acc[f * 256 + tid + 256] += (0.5f + 0.5f * twc[tid]) * 0.5f * z[tid + 256].x;
    __syncthreads();
  }

  // ---- normalize (norm = win[n]^2 + win[n+256]^2 = 0.5 + 0.5*twc^2), +ecg ----
  float* dst = xtT + (size_t)bd * S_;
  for (int t = tid; t < S_; t += 256) {
    const int n = t & 255;
    const float hw = twc[n];
    const float nrm = 0.5f + 0.5f * hw * hw;
    dst[t] = acc[t + 256] / nrm + sig[t];
  }
}

// ---------------- LayerNorm over D=768, one block per row ----------------
__global__ __launch_bounds__(256) void k_layernorm(const float* __restrict__ x,
                                                   const float* __restrict__ g,
                                                   const float* __restrict__ b,
                                                   float* __restrict__ out) {
  const int row = blockIdx.x;
  const int tid = threadIdx.x;
  const float* xr = x + (size_t)row * D_;
  const float v0 = xr[tid], v1 = xr[tid + 256], v2 = xr[tid + 512];
  float s = v0 + v1 + v2;
  float q = v0 * v0 + v1 * v1 + v2 * v2;
  __shared__ float red[8];
  for (int off = 32; off > 0; off >>= 1) {
    s += __shfl_down(s, off);
    q += __shfl_down(q, off);
  }
  if ((tid & 63) == 0) { red[tid >> 6] = s; red[4 + (tid >> 6)] = q; }
  __syncthreads();
  s = red[0] + red[1] + red[2] + red[3];
  q = red[4] + red[5] + red[6] + red[7];
  const float mean = s * (1.0f / 768.0f);
  const float var = q * (1.0f / 768.0f) - mean * mean;
  const float inv = rsqrtf(var + 1e-5f);
  float* orow = out + (size_t)row * D_;
  orow[tid]       = (v0 - mean) * inv * g[tid]       + b[tid];
  orow[tid + 256] = (v1 - mean) * inv * g[tid + 256] + b[tid + 256];
  orow[tid + 512] = (v2 - mean) * inv * g[tid + 512] + b[tid + 512];
}

// ---------- GEMM: out = act(A @ W^T + bias [+ resid]); A (M,768), W (768,768) ----------
template <int MODE>  // 0: exact GELU ; 1: + residual
__global__ __launch_bounds__(256) void k_gemm_ffn(
    const float* __restrict__ A, const float* __restrict__ W,
    const float* __restrict__ bias, const float* __restrict__ resid,
    float* __restrict__ out, int M) {
  __shared__ float As[16][64];
  __shared__ float Bs[16][64];
  const int tid = threadIdx.x;
  const int n0 = blockIdx.x * 64;
  const int m0 = blockIdx.y * 64;
  const int tm = tid & 15;
  const int tn = tid >> 4;
  const int lrow = tid >> 2;
  const int lcol = (tid & 3) << 2;
  float acc[4][4] = {};
  for (int k0 = 0; k0 < 768; k0 += 16) {
    float4 av = make_float4(0.f, 0.f, 0.f, 0.f);
    const int arow = m0 + lrow;
    if (arow < M)
      av = *reinterpret_cast<const float4*>(A + (size_t)arow * 768 + k0 + lcol);
    const float4 bv =
        *reinterpret_cast<const float4*>(W + (size_t)(n0 + lrow) * 768 + k0 + lcol);
    __syncthreads();
    As[lcol + 0][lrow] = av.x; As[lcol + 1][lrow] = av.y;
    As[lcol + 2][lrow] = av.z; As[lcol + 3][lrow] = av.w;
    Bs[lcol + 0][lrow] = bv.x; Bs[lcol + 1][lrow] = bv.y;
    Bs[lcol + 2][lrow] = bv.z; Bs[lcol + 3][lrow] = bv.w;
    __syncthreads();
#pragma unroll
    for (int kk = 0; kk < 16; ++kk) {
      const float4 a4 = *reinterpret_cast<const float4*>(&As[kk][tm << 2]);
      const float4 b4 = *reinterpret_cast<const float4*>(&Bs[kk][tn << 2]);
      const float aa[4] = {a4.x, a4.y, a4.z, a4.w};
      const float bb[4] = {b4.x, b4.y, b4.z, b4.w};
#pragma unroll
      for (int i = 0; i < 4; ++i)
#pragma unroll
        for (int j = 0; j < 4; ++j) acc[i][j] = fmaf(aa[i], bb[j], acc[i][j]);
    }
  }
#pragma unroll
  for (int i = 0; i < 4; ++i) {
    const int mrow = m0 + (tm << 2) + i;
    if (mrow >= M) continue;
#pragma unroll
    for (int j = 0; j < 4; ++j) {
      const int ncol = n0 + (tn << 2) + j;
      float v = acc[i][j] + bias[ncol];
      if (MODE == 0) {
        v = 0.5f * v * (1.0f + erff(v * 0.70710678118654752440f));
      } else {
        v += resid[(size_t)mrow * 768 + ncol];
      }
      out[(size_t)mrow * 768 + ncol] = v;
    }
  }
}

}  // namespace

extern "C" void kernel_launch(void* const* d_in, const int* in_sizes, int n_in,
                              void* d_out, int out_size, void* d_ws, size_t ws_size,
                              hipStream_t stream) {
  (void)in_sizes; (void)n_in; (void)out_size; (void)ws_size;
  const float* ecg     = (const float*)d_in[0];
  const float* image   = (const float*)d_in[1];
  const float* ebank   = (const float*)d_in[2];
  const float* cbank   = (const float*)d_in[3];
  const float* gsel    = (const float*)d_in[4];
  const float* gw      = (const float*)d_in[5];
  const float* gb      = (const float*)d_in[6];
  const float* e_ln1_g = (const float*)d_in[7];
  const float* e_ln1_b = (const float*)d_in[8];
  const float* e_w1    = (const float*)d_in[9];
  const float* e_b1    = (const float*)d_in[10];
  const float* e_w2    = (const float*)d_in[11];
  const float* e_b2    = (const float*)d_in[12];
  const float* e_ln2_g = (const float*)d_in[13];
  const float* e_ln2_b = (const float*)d_in[14];
  const float* c_ln1_g = (const float*)d_in[15];
  const float* c_ln1_b = (const float*)d_in[16];
  const float* c_w1    = (const float*)d_in[17];
  const float* c_b1    = (const float*)d_in[18];
  const float* c_w2    = (const float*)d_in[19];
  const float* c_b2    = (const float*)d_in[20];
  const float* c_ln2_g = (const float*)d_in[21];
  const float* c_ln2_b = (const float*)d_in[22];

  float* out = (float*)d_out;
  float* ws = (float*)d_ws;

  constexpr size_t TXT = (size_t)8 * 2048 * 768;   // 12,582,912 floats
  constexpr size_t IMG = (size_t)8 * 196 * 768;    // 1,204,224 floats

  // ws layout: A (TXT) | Bb (TXT) | gate0 | gatev   -> ~100.7 MB
  float* A     = ws;
  float* Bb    = A + TXT;
  float* gate0 = Bb + TXT;
  float* gatev = gate0 + 8 * 768;

  // FcT (2313*768 float2 = 14.2 MB) parked in d_out[0:TXT] until text GEMM1
  float2* FcT = (float2*)out;

  // image-path scratch inside A (consumed before ecg path overwrites A)
  float* ximg  = A;             // (B,196,768)
  float* xh_i  = A + IMG;       // ln1 out
  float* y_i   = A + 2 * IMG;   // pre-ln2
  float* h_img = out + TXT;     // GELU act scratch in d_out image region

  // ---- one-time filter-bank combine+transpose ----
  k_fc_transpose<<<dim3(73, 24), dim3(32, 8), 0, stream>>>((const float2*)ebank, FcT);

  // ---- image path (also produces gate) ----
  k_img_rfft_filter<<<dim3(99, 8), 256, 0, stream>>>(image, (const float2*)cbank,
                                                     (float2*)Bb);
  k_gate_pool<<<8, 256, 0, stream>>>((const float2*)Bb, (const float2*)gsel, gate0);
  k_gate_mm<<<8, 256, 0, stream>>>(gate0, gw, gb, gatev);
  k_img_irfft_add<<<dim3(196, 8), 256, 0, stream>>>((const float2*)Bb, image, ximg);

  // ---- image AddNorm ----
  k_layernorm<<<1568, 256, 0, stream>>>(ximg, c_ln1_g, c_ln1_b, xh_i);
  k_gemm_ffn<0><<<dim3(12, 25), 256, 0, stream>>>(xh_i, c_w1, c_b1, nullptr, h_img, 1568);
  k_gemm_ffn<1><<<dim3(12, 25), 256, 0, stream>>>(h_img, c_w2, c_b2, xh_i, y_i, 1568);
  k_layernorm<<<1568, 256, 0, stream>>>(y_i, c_ln2_g, c_ln2_b, out + TXT);

  // ---- ecg path: transpose -> fused FFT pipeline -> untranspose ----
  k_transpose_g<<<dim3(24, 64, 8), dim3(32, 8), 0, stream>>>(ecg, A, 2048, 768);
  k_ecg_fft<<<8 * 768, 256, 0, stream>>>(A, FcT, gatev, Bb);
  k_transpose_g<<<dim3(64, 24, 8), dim3(32, 8), 0, stream>>>(Bb, A, 768, 2048);

  // ---- text AddNorm ----
  k_layernorm<<<16384, 256, 0, stream>>>(A, e_ln1_g, e_ln1_b, Bb);
  k_gemm_ffn<0><<<dim3(12, 256), 256, 0, stream>>>(Bb, e_w1, e_b1, nullptr, out, 16384);
  k_gemm_ffn<1><<<dim3(12, 256), 256, 0, stream>>>(out, e_w2, e_b2, Bb, A, 16384);
  k_layernorm<<<16384, 256, 0, stream>>>(A, e_ln2_g, e_ln2_b, out);
}

// Round 3
// 665.476 us; speedup vs baseline: 4.7678x; 1.9729x over previous
//
#include <hip/hip_runtime.h>
#include <math.h>

namespace {

constexpr int B_ = 8;
constexpr int S_ = 2048;
constexpr int D_ = 768;
constexpr int N_ = 196;     // image spatial
constexpr int NF_ = 99;     // image freq bins
constexpr int NFREQ_ = 257;
constexpr int NSEG_ = 9;
constexpr int NBINS_ = NFREQ_ * NSEG_;  // 2313
constexpr float TWOPI_ = 6.28318530717958647692f;

using bf16x8 = __attribute__((ext_vector_type(8))) short;
using f32x4  = __attribute__((ext_vector_type(4))) float;

__device__ __forceinline__ int rev9(int x) { return (int)(__brev((unsigned)x) >> 23); }
__device__ __forceinline__ int padidx(int i) { return i + (i >> 4); }

__device__ __forceinline__ unsigned short f2bf(float x) {
  unsigned u = __float_as_uint(x);
  u = (u + 0x7FFFu + ((u >> 16) & 1u)) >> 16;
  return (unsigned short)u;
}
__device__ __forceinline__ float bf2f(unsigned short h) {
  return __uint_as_float(((unsigned)h) << 16);
}

__device__ __forceinline__ void gload16(const void* g, void* l) {
  __builtin_amdgcn_global_load_lds((const __attribute__((address_space(1))) void*)g,
                                   (__attribute__((address_space(3))) void*)l, 16, 0, 0);
}

// ---------------- generic batched transpose (B,R,C) -> (B,C,R) ----------------
__global__ __launch_bounds__(256) void k_transpose_g(const float* __restrict__ src,
                                                     float* __restrict__ dst,
                                                     int R, int C) {
  __shared__ float tile[32][33];
  const int b = blockIdx.z;
  const int c0 = blockIdx.x * 32;
  const int r0 = blockIdx.y * 32;
  const int tx = threadIdx.x, ty = threadIdx.y;
  for (int i = ty; i < 32; i += 8)
    tile[i][tx] = src[((size_t)b * R + r0 + i) * C + c0 + tx];
  __syncthreads();
  for (int i = ty; i < 32; i += 8)
    dst[((size_t)b * C + c0 + i) * R + r0 + tx] = tile[tx][i];
}

// ---- filter bank: FcT[d][f][k] = -(e0[k*9+f][d] + e1[k*9+f][d]) ----
__global__ __launch_bounds__(256) void k_fc_make(const float2* __restrict__ e2,
                                                 float2* __restrict__ FcT) {
  const int o = blockIdx.x * 256 + threadIdx.x;
  if (o >= NBINS_ * D_) return;
  const int d = o / NBINS_;
  const int r = o - d * NBINS_;
  const int f = r / NFREQ_;
  const int k = r - f * NFREQ_;
  const int s = k * 9 + f;
  const float2 a = e2[(size_t)s * D_ + d];
  const float2 b = e2[(size_t)(NBINS_ + s) * D_ + d];
  FcT[o] = make_float2(-(a.x + b.x), -(a.y + b.y));
}

// ---- weights fp32 -> bf16 (4 matrices concatenated) ----
__global__ __launch_bounds__(256) void k_wconv(const float* __restrict__ w1,
                                               const float* __restrict__ w2,
                                               const float* __restrict__ w3,
                                               const float* __restrict__ w4,
                                               unsigned short* __restrict__ o) {
  const int Nw = D_ * D_;
  const int i = blockIdx.x * 256 + threadIdx.x;
  if (i >= 4 * Nw) return;
  const float* src = (i < Nw) ? w1 : (i < 2 * Nw) ? w2 : (i < 3 * Nw) ? w3 : w4;
  o[i] = f2bf(src[i & (Nw - 1)]);  // Nw = 589824 not pow2! use mod
}

// (Nw not power of two — fix: dedicated index)
__global__ __launch_bounds__(256) void k_wconv2(const float* __restrict__ w,
                                                unsigned short* __restrict__ o, int n) {
  const int i = blockIdx.x * 256 + threadIdx.x;
  if (i < n) o[i] = f2bf(w[i]);
}

// ------------- image rfft (ortho) + filter -> imgF (complex) -------------
__global__ __launch_bounds__(256) void k_img_rfft_filter(
    const float* __restrict__ image, const float2* __restrict__ bank2,
    float2* __restrict__ imgF) {
  const int f = blockIdx.x;  // 0..98
  const int b = blockIdx.y;
  const int tid = threadIdx.x;
  __shared__ float ct[N_], st[N_];
  if (tid < N_) {
    const int r = (f * tid) % N_;
    float s, c;
    sincosf(TWOPI_ * (float)r / (float)N_, &s, &c);
    ct[tid] = c; st[tid] = s;
  }
  __syncthreads();
  for (int d = tid; d < D_; d += 256) {
    float re = 0.f, im = 0.f;
    const float* ip = image + (size_t)b * N_ * D_ + d;
    for (int t = 0; t < N_; ++t) {
      const float v = ip[(size_t)t * D_];
      re = fmaf(v, ct[t], re);
      im = fmaf(-v, st[t], im);
    }
    const float sc = 1.0f / (196.0f * 99.0f);
    const float pr = (re * re - im * im) * sc;
    const float pi2 = (2.f * re * im) * sc;
    const size_t fd = (size_t)f * D_ + d;
    const float2 c0 = bank2[fd];
    const float2 c1 = bank2[(size_t)NF_ * D_ + fd];
    const float fcr = -(c0.x + c1.x), fci = -(c0.y + c1.y);
    imgF[(size_t)(b * NF_ + f) * D_ + d] =
        make_float2(pr * fcr - pi2 * fci, pr * fci + pi2 * fcr);
  }
}

// ---------------- gate pooling + tiny GEMM ----------------
__global__ __launch_bounds__(256) void k_gate_pool(const float2* __restrict__ imgF,
                                                   const float2* __restrict__ gsel2,
                                                   float* __restrict__ gate0) {
  const int b = blockIdx.x;
  for (int d = threadIdx.x; d < D_; d += 256) {
    float acc = 0.f;
    for (int f = 0; f < NF_; ++f) {
      const float2 z = imgF[(size_t)(b * NF_ + f) * D_ + d];
      const float2 w = gsel2[(size_t)f * D_ + d];
      acc += z.x * w.x - z.y * w.y;
    }
    gate0[b * D_ + d] = acc * (1.0f / 99.0f);
  }
}

__global__ __launch_bounds__(256) void k_gate_mm(const float* __restrict__ gate0,
                                                 const float* __restrict__ W,
                                                 const float* __restrict__ bias,
                                                 float* __restrict__ gate) {
  const int b = blockIdx.x;
  __shared__ float row[D_];
  for (int e = threadIdx.x; e < D_; e += 256) row[e] = gate0[b * D_ + e];
  __syncthreads();
  for (int d = threadIdx.x; d < D_; d += 256) {
    float acc = bias[d];
    const float* w = W + (size_t)d * D_;
    for (int e = 0; e < D_; e += 4) {
      const float4 wv = *reinterpret_cast<const float4*>(w + e);
      acc = fmaf(row[e], wv.x, acc);
      acc = fmaf(row[e + 1], wv.y, acc);
      acc = fmaf(row[e + 2], wv.z, acc);
      acc = fmaf(row[e + 3], wv.w, acc);
    }
    gate[b * D_ + d] = acc;
  }
}

// -------- image irfft (ortho) + residual --------
__global__ __launch_bounds__(256) void k_img_irfft_add(const float2* __restrict__ imgF,
                                                       const float* __restrict__ image,
                                                       float* __restrict__ ximg) {
  const int t = blockIdx.x;
  const int b = blockIdx.y;
  const int tid = threadIdx.x;
  __shared__ float cf[NF_], sf[NF_];
  if (tid < NF_) {
    const int r = (t * tid) % N_;
    float s, c;
    sincosf(TWOPI_ * (float)r / (float)N_, &s, &c);
    cf[tid] = c; sf[tid] = s;
  }
  __syncthreads();
  const float sgn_ny = (t & 1) ? -1.f : 1.f;
  for (int d = tid; d < D_; d += 256) {
    const float2* zp = imgF + (size_t)b * NF_ * D_ + d;
    float acc = zp[0].x;
    for (int f = 1; f < NF_ - 1; ++f) {
      const float2 z = zp[(size_t)f * D_];
      acc += 2.f * (z.x * cf[f] - z.y * sf[f]);
    }
    acc += zp[(size_t)(NF_ - 1) * D_].x * sgn_ny;
    const size_t idx = (size_t)(b * N_ + t) * D_ + d;
    ximg[idx] = acc * (1.0f / 14.0f) + image[idx];
  }
}

// ================= ecg fused FFT pipeline =================
template <int DIR>  // -1 fwd, +1 inv
__device__ __forceinline__ void fft512(float* zr, float* zi, const float2* tw, int tid) {
#pragma unroll
  for (int s = 0; s < 9; ++s) {
    if (s >= 7) __syncthreads();
    else asm volatile("s_waitcnt lgkmcnt(0)" ::: "memory");
    const int h = 1 << s;
    const int j = tid & (h - 1);
    const int i0 = ((tid >> s) << (s + 1)) | j;
    const int i1 = i0 + h;
    const float2 w = tw[h - 1 + j];
    const float wc = w.x;
    const float ws = (DIR < 0) ? -w.y : w.y;
    const int a0 = padidx(i0), a1 = padidx(i1);
    const float xr = zr[a0], xi = zi[a0];
    const float yr = zr[a1], yi = zi[a1];
    const float tr = yr * wc - yi * ws;
    const float ti = yr * ws + yi * wc;
    zr[a0] = xr + tr; zi[a0] = xi + ti;
    zr[a1] = xr - tr; zi[a1] = xi - ti;
  }
}

template <int FA, int FB, bool HASB>
__device__ __forceinline__ void ecg_unit(const int tid, const float g,
                                         const float2* __restrict__ fc,
                                         float* sig, float2* tw, float* zr, float* zi,
                                         float* Yar, float* Yai, float* Ybr, float* Ybi,
                                         float* accr) {
  const float c0 = tw[255 + tid].x;
  const float wlo = 0.5f - 0.5f * c0;
  const float whi = 0.5f + 0.5f * c0;
  // ---- scatter windowed frames (bit-reversed) ----
  {
    const float va_lo = (FA == 0) ? 0.f : sig[FA * 256 - 256 + tid] * wlo;
    const float va_hi = (FA == 8) ? 0.f : sig[FA * 256 + tid] * whi;
    float vb_lo = 0.f, vb_hi = 0.f;
    if (HASB) {
      vb_lo = (FB == 0) ? 0.f : sig[FB * 256 - 256 + tid] * wlo;
      vb_hi = (FB == 8) ? 0.f : sig[FB * 256 + tid] * whi;
    }
    const int rlo = padidx(rev9(tid)), rhi = padidx(rev9(tid + 256));
    zr[rlo] = va_lo; zi[rlo] = vb_lo;
    zr[rhi] = va_hi; zi[rhi] = vb_hi;
  }
  __syncthreads();
  fft512<-1>(zr, zi, tw, tid);
  __syncthreads();
  // ---- unpack two real spectra + power + filter + gate ----
  {
    const int niter = (tid == 0) ? 2 : 1;
    for (int it = 0; it < niter; ++it) {
      const int k = (it == 0) ? tid : 256;
      const int q = (512 - k) & 511;
      const float Zrk = zr[padidx(k)], Zik = zi[padidx(k)];
      const float Zrq = zr[padidx(q)], Ziq = zi[padidx(q)];
      const float sc = 0.5f / 256.f;
      const float ar = (Zrk + Zrq) * sc, ai = (Zik - Ziq) * sc;
      {
        const float pr = (ar * ar - ai * ai) * (1.f / 2313.f);
        const float pi = (2.f * ar * ai) * (1.f / 2313.f);
        const float2 cc = fc[FA * 257 + k];
        Yar[k] = (pr * cc.x - pi * cc.y) * g;
        Yai[k] = (pr * cc.y + pi * cc.x) * g;
      }
      if (HASB) {
        const float br = (Zik + Ziq) * sc, bi = (Zrq - Zrk) * sc;
        const float pr = (br * br - bi * bi) * (1.f / 2313.f);
        const float pi = (2.f * br * bi) * (1.f / 2313.f);
        const float2 cc = fc[FB * 257 + k];
        Ybr[k] = (pr * cc.x - pi * cc.y) * g;
        Ybi[k] = (pr * cc.y + pi * cc.x) * g;
      }
    }
  }
  __syncthreads();
  // ---- build packed inverse spectrum C = Ya' + i*Yb' (c2r drops DC/Ny imag) ----
  {
#pragma unroll
    for (int half = 0; half < 2; ++half) {
      const int m = tid + half * 256;
      float Cr, Ci;
      if (m == 0)        { Cr = Yar[0];   Ci = HASB ? Ybr[0]   : 0.f; }
      else if (m == 256) { Cr = Yar[256]; Ci = HASB ? Ybr[256] : 0.f; }
      else if (m < 256) {
        Cr = Yar[m] - (HASB ? Ybi[m] : 0.f);
        Ci = Yai[m] + (HASB ? Ybr[m] : 0.f);
      } else {
        const int mm = 512 - m;
        Cr = Yar[mm] + (HASB ? Ybi[mm] : 0.f);
        Ci = (HASB ? Ybr[mm] : 0.f) - Yai[mm];
      }
      const int rm = padidx(rev9(m));
      zr[rm] = Cr; zi[rm] = Ci;
    }
  }
  __syncthreads();
  fft512<1>(zr, zi, tw, tid);
  // stage-8 wrote z[tid], z[tid+256] from this very thread -> safe to read
  {
    const float xa_lo = zr[padidx(tid)], xa_hi = zr[padidx(tid + 256)];
    accr[FA]     += 0.5f * wlo * xa_lo;
    accr[FA + 1] += 0.5f * whi * xa_hi;
    if (HASB) {
      const float xb_lo = zi[padidx(tid)], xb_hi = zi[padidx(tid + 256)];
      accr[FB]     += 0.5f * wlo * xb_lo;
      accr[FB + 1] += 0.5f * whi * xb_hi;
    }
  }
  __syncthreads();  // protect z before next unit's scatter
}

__global__ __launch_bounds__(256) void k_ecg_fft(
    const float* __restrict__ ecgT, const float2* __restrict__ FcT,
    const float* __restrict__ gate, float* __restrict__ xtT) {
  const int bd = blockIdx.x;
  const int d = bd % D_;
  const int tid = threadIdx.x;

  __shared__ float sig[S_];      // 8 KB
  __shared__ float2 tw[512];     // 4 KB (511 used; per-stage tables)
  __shared__ float zr[544], zi[544];
  __shared__ float Yar[NFREQ_], Yai[NFREQ_], Ybr[NFREQ_], Ybi[NFREQ_];

  const float* src = ecgT + (size_t)bd * S_;
  for (int i = tid; i < S_; i += 256) sig[i] = src[i];
#pragma unroll
  for (int s = 0; s < 9; ++s) {
    const int h = 1 << s;
    for (int j = tid; j < h; j += 256) {
      float sn, cs;
      sincosf((float)j * (TWOPI_ / (2.0f * (float)h)), &sn, &cs);
      tw[h - 1 + j] = make_float2(cs, sn);
    }
  }
  __syncthreads();

  const float g = gate[bd];
  const float2* fc = FcT + (size_t)d * NBINS_;
  float accr[10];
#pragma unroll
  for (int i = 0; i < 10; ++i) accr[i] = 0.f;

  ecg_unit<0, 8, true>(tid, g, fc, sig, tw, zr, zi, Yar, Yai, Ybr, Ybi, accr);
  ecg_unit<1, 2, true>(tid, g, fc, sig, tw, zr, zi, Yar, Yai, Ybr, Ybi, accr);
  ecg_unit<3, 4, true>(tid, g, fc, sig, tw, zr, zi, Yar, Yai, Ybr, Ybi, accr);
  ecg_unit<5, 6, true>(tid, g, fc, sig, tw, zr, zi, Yar, Yai, Ybr, Ybi, accr);
  ecg_unit<7, 0, false>(tid, g, fc, sig, tw, zr, zi, Yar, Yai, Ybr, Ybi, accr);

  const float c0 = tw[255 + tid].x;
  const float nrm = 0.5f + 0.5f * c0 * c0;  // win(t)^2 + win(t+256)^2
  float* dst = xtT + (size_t)bd * S_;
#pragma unroll
  for (int i2 = 0; i2 < 8; ++i2)
    dst[i2 * 256 + tid] = accr[i2 + 1] / nrm + sig[i2 * 256 + tid];
}

// ---------------- LayerNorm over D=768; OUT: 0=f32, 1=bf16 ----------------
template <int BF16OUT>
__global__ __launch_bounds__(256) void k_layernorm(const float* __restrict__ x,
                                                   const float* __restrict__ g,
                                                   const float* __restrict__ b,
                                                   void* __restrict__ outv) {
  const int row = blockIdx.x;
  const int tid = threadIdx.x;
  const float* xr = x + (size_t)row * D_;
  const float v0 = xr[tid], v1 = xr[tid + 256], v2 = xr[tid + 512];
  float s = v0 + v1 + v2;
  float q = v0 * v0 + v1 * v1 + v2 * v2;
  __shared__ float red[8];
  for (int off = 32; off > 0; off >>= 1) {
    s += __shfl_down(s, off);
    q += __shfl_down(q, off);
  }
  if ((tid & 63) == 0) { red[tid >> 6] = s; red[4 + (tid >> 6)] = q; }
  __syncthreads();
  s = red[0] + red[1] + red[2] + red[3];
  q = red[4] + red[5] + red[6] + red[7];
  const float mean = s * (1.0f / 768.0f);
  const float var = q * (1.0f / 768.0f) - mean * mean;
  const float inv = rsqrtf(var + 1e-5f);
  const float o0 = (v0 - mean) * inv * g[tid] + b[tid];
  const float o1 = (v1 - mean) * inv * g[tid + 256] + b[tid + 256];
  const float o2 = (v2 - mean) * inv * g[tid + 512] + b[tid + 512];
  if (BF16OUT) {
    unsigned short* orow = (unsigned short*)outv + (size_t)row * D_;
    orow[tid] = f2bf(o0); orow[tid + 256] = f2bf(o1); orow[tid + 512] = f2bf(o2);
  } else {
    float* orow = (float*)outv + (size_t)row * D_;
    orow[tid] = o0; orow[tid + 256] = o1; orow[tid + 512] = o2;
  }
}

// ---------- MFMA GEMM: out = act(A @ W^T + bias [+resid]) ----------
// A (M,768) bf16 row-major, W (768,768) bf16 row-major (out-feature rows)
// MODE 0: exact GELU -> bf16 out ; MODE 1: +resid(bf16) -> f32 out
template <int MODE>
__global__ __launch_bounds__(256) void k_gemm_mfma(
    const unsigned short* __restrict__ Abf, const unsigned short* __restrict__ Wbf,
    const float* __restrict__ bias, const unsigned short* __restrict__ resid,
    void* __restrict__ outv, int M) {
  __shared__ unsigned short Asm[128 * 64];  // 16 KB, row=128B, slot-swizzled
  __shared__ unsigned short Bsm[128 * 64];
  const int tid = threadIdx.x;
  const int lane = tid & 63, wid = tid >> 6;
  const int wr = wid >> 1, wc = wid & 1;
  const int n0 = blockIdx.x * 128, m0 = blockIdx.y * 128;
  f32x4 acc[4][4] = {};
  for (int kt = 0; kt < 12; ++kt) {
    const int k0 = kt * 64;
#pragma unroll
    for (int i = 0; i < 4; ++i) {
      const int c = tid + 256 * i;         // 16B chunk id, 0..1023
      const int row = c >> 3, sl = c & 7;
      const int gsl = sl ^ (row & 7);      // pre-swizzled global source (T21)
      gload16(Abf + (size_t)(m0 + row) * 768 + k0 + gsl * 8, &Asm[c * 8]);
      gload16(Wbf + (size_t)(n0 + row) * 768 + k0 + gsl * 8, &Bsm[c * 8]);
    }
    __syncthreads();  // drains vmcnt before barrier
#pragma unroll
    for (int ks = 0; ks < 2; ++ks) {
      bf16x8 af[4], bfv[4];
#pragma unroll
      for (int mi = 0; mi < 4; ++mi) {
        const int row = wr * 64 + mi * 16 + (lane & 15);
        const int sl = (ks * 4 + (lane >> 4)) ^ (row & 7);
        af[mi] = *(const bf16x8*)((const char*)Asm + row * 128 + sl * 16);
      }
#pragma unroll
      for (int ni = 0; ni < 4; ++ni) {
        const int row = wc * 64 + ni * 16 + (lane & 15);
        const int sl = (ks * 4 + (lane >> 4)) ^ (row & 7);
        bfv[ni] = *(const bf16x8*)((const char*)Bsm + row * 128 + sl * 16);
      }
#pragma unroll
      for (int mi = 0; mi < 4; ++mi)
#pragma unroll
        for (int ni = 0; ni < 4; ++ni)
          acc[mi][ni] = __builtin_amdgcn_mfma_f32_16x16x32_bf16(af[mi], bfv[ni],
                                                                acc[mi][ni], 0, 0, 0);
    }
    __syncthreads();
  }
#pragma unroll
  for (int mi = 0; mi < 4; ++mi) {
#pragma unroll
    for (int ni = 0; ni < 4; ++ni) {
      const int col = n0 + wc * 64 + ni * 16 + (lane & 15);
#pragma unroll
      for (int e = 0; e < 4; ++e) {
        const int row = m0 + wr * 64 + mi * 16 + (lane >> 4) * 4 + e;
        if (row >= M) continue;
        float v = acc[mi][ni][e] + bias[col];
        if (MODE == 0) {
          v = 0.5f * v * (1.0f + erff(v * 0.70710678118654752440f));
          ((unsigned short*)outv)[(size_t)row * 768 + col] = f2bf(v);
        } else {
          v += bf2f(resid[(size_t)row * 768 + col]);
          ((float*)outv)[(size_t)row * 768 + col] = v;
        }
      }
    }
  }
}

}  // namespace

extern "C" void kernel_launch(void* const* d_in, const int* in_sizes, int n_in,
                              void* d_out, int out_size, void* d_ws, size_t ws_size,
                              hipStream_t stream) {
  (void)in_sizes; (void)n_in; (void)out_size; (void)ws_size;
  const float* ecg     = (const float*)d_in[0];
  const float* image   = (const float*)d_in[1];
  const float* ebank   = (const float*)d_in[2];
  const float* cbank   = (const float*)d_in[3];
  const float* gsel    = (const float*)d_in[4];
  const float* gw      = (const float*)d_in[5];
  const float* gb      = (const float*)d_in[6];
  const float* e_ln1_g = (const float*)d_in[7];
  const float* e_ln1_b = (const float*)d_in[8];
  const float* e_w1    = (const float*)d_in[9];
  const float* e_b1    = (const float*)d_in[10];
  const float* e_w2    = (const float*)d_in[11];
  const float* e_b2    = (const float*)d_in[12];
  const float* e_ln2_g = (const float*)d_in[13];
  const float* e_ln2_b = (const float*)d_in[14];
  const float* c_ln1_g = (const float*)d_in[15];
  const float* c_ln1_b = (const float*)d_in[16];
  const float* c_w1    = (const float*)d_in[17];
  const float* c_b1    = (const float*)d_in[18];
  const float* c_w2    = (const float*)d_in[19];
  const float* c_b2    = (const float*)d_in[20];
  const float* c_ln2_g = (const float*)d_in[21];
  const float* c_ln2_b = (const float*)d_in[22];

  float* out = (float*)d_out;
  float* ws = (float*)d_ws;

  constexpr size_t TXT = (size_t)8 * 2048 * 768;   // 12,582,912
  constexpr size_t IMG = (size_t)8 * 196 * 768;    // 1,204,224
  constexpr int NW = 768 * 768;                    // 589,824

  // ws: A (TXT) | Bb (TXT) | wbf (4*NW ushort = NW f32-eq *2) | gates  ~105.5 MB
  float* A  = ws;
  float* Bb = A + TXT;
  unsigned short* wbf = (unsigned short*)(Bb + TXT);
  unsigned short* ew1b = wbf;
  unsigned short* ew2b = wbf + NW;
  unsigned short* cw1b = wbf + 2 * NW;
  unsigned short* cw2b = wbf + 3 * NW;
  float* gate0 = (float*)(wbf + 4 * NW);
  float* gatev = gate0 + 8 * 768;

  // FcT (2313*768 float2 = 14.2 MB) parked in d_out[0:TXT] (overwritten at final LN)
  float2* FcT = (float2*)out;

  // image-path scratch inside A (fully consumed before ecg transpose overwrites A)
  float* ximg = A;                                        // fp32 (B,196,768)
  unsigned short* xh_i = (unsigned short*)(A + IMG);      // bf16
  unsigned short* h_i  = (unsigned short*)(A + IMG + IMG / 2);
  float* y_i = A + 2 * IMG;                               // fp32

  // text buffers
  unsigned short* xhat = (unsigned short*)(Bb + TXT / 2);  // bf16 LN1 out / resid
  unsigned short* h_t  = (unsigned short*)Bb;              // bf16 GELU act

  // ---- one-time prep ----
  k_fc_make<<<(int)((NBINS_ * D_ + 255) / 256), 256, 0, stream>>>((const float2*)ebank, FcT);
  k_wconv2<<<(NW + 255) / 256, 256, 0, stream>>>(e_w1, ew1b, NW);
  k_wconv2<<<(NW + 255) / 256, 256, 0, stream>>>(e_w2, ew2b, NW);
  k_wconv2<<<(NW + 255) / 256, 256, 0, stream>>>(c_w1, cw1b, NW);
  k_wconv2<<<(NW + 255) / 256, 256, 0, stream>>>(c_w2, cw2b, NW);

  // ---- image path (produces gate; all scratch in A/Bb before ecg path) ----
  k_img_rfft_filter<<<dim3(99, 8), 256, 0, stream>>>(image, (const float2*)cbank,
                                                     (float2*)Bb);
  k_gate_pool<<<8, 256, 0, stream>>>((const float2*)Bb, (const float2*)gsel, gate0);
  k_gate_mm<<<8, 256, 0, stream>>>(gate0, gw, gb, gatev);
  k_img_irfft_add<<<dim3(196, 8), 256, 0, stream>>>((const float2*)Bb, image, ximg);

  k_layernorm<1><<<1568, 256, 0, stream>>>(ximg, c_ln1_g, c_ln1_b, xh_i);
  k_gemm_mfma<0><<<dim3(6, 13), 256, 0, stream>>>(xh_i, cw1b, c_b1, nullptr, h_i, 1568);
  k_gemm_mfma<1><<<dim3(6, 13), 256, 0, stream>>>(h_i, cw2b, c_b2, xh_i, y_i, 1568);
  k_layernorm<0><<<1568, 256, 0, stream>>>(y_i, c_ln2_g, c_ln2_b, out + TXT);

  // ---- ecg path ----
  k_transpose_g<<<dim3(24, 64, 8), dim3(32, 8), 0, stream>>>(ecg, A, 2048, 768);
  k_ecg_fft<<<8 * 768, 256, 0, stream>>>(A, FcT, gatev, Bb);
  k_transpose_g<<<dim3(64, 24, 8), dim3(32, 8), 0, stream>>>(Bb, A, 768, 2048);

  // ---- text AddNorm (bf16 MFMA FFN) ----
  k_layernorm<1><<<16384, 256, 0, stream>>>(A, e_ln1_g, e_ln1_b, xhat);
  k_gemm_mfma<0><<<dim3(6, 128), 256, 0, stream>>>(xhat, ew1b, e_b1, nullptr, h_t, 16384);
  k_gemm_mfma<1><<<dim3(6, 128), 256, 0, stream>>>(h_t, ew2b, e_b2, xhat, A, 16384);
  k_layernorm<0><<<16384, 256, 0, stream>>>(A, e_ln2_g, e_ln2_b, out);
}

// Round 4
// 661.466 us; speedup vs baseline: 4.7967x; 1.0061x over previous
//
#include <hip/hip_runtime.h>
#include <math.h>

namespace {

constexpr int B_ = 8;
constexpr int S_ = 2048;
constexpr int D_ = 768;
constexpr int N_ = 196;     // image spatial
constexpr int NF_ = 99;     // image freq bins
constexpr int NFREQ_ = 257;
constexpr int NSEG_ = 9;
constexpr int NBINS_ = NFREQ_ * NSEG_;  // 2313
constexpr float TWOPI_ = 6.28318530717958647692f;

using bf16x8 = __attribute__((ext_vector_type(8))) short;
using f32x4  = __attribute__((ext_vector_type(4))) float;

__device__ __forceinline__ int rev9(int x) { return (int)(__brev((unsigned)x) >> 23); }
__device__ __forceinline__ int padz(int i) { return i + (i >> 3); }  // float2 elements

__device__ __forceinline__ unsigned short f2bf(float x) {
  unsigned u = __float_as_uint(x);
  u = (u + 0x7FFFu + ((u >> 16) & 1u)) >> 16;
  return (unsigned short)u;
}
__device__ __forceinline__ float bf2f(unsigned short h) {
  return __uint_as_float(((unsigned)h) << 16);
}

__device__ __forceinline__ void gload16(const void* g, void* l) {
  __builtin_amdgcn_global_load_lds((const __attribute__((address_space(1))) void*)g,
                                   (__attribute__((address_space(3))) void*)l, 16, 0, 0);
}

// ---------------- batched transpose (B,R,C) -> (B,C,R) ----------------
__global__ __launch_bounds__(256) void k_transpose_g(const float* __restrict__ src,
                                                     float* __restrict__ dst,
                                                     int R, int C) {
  __shared__ float tile[32][33];
  const int b = blockIdx.z;
  const int c0 = blockIdx.x * 32;
  const int r0 = blockIdx.y * 32;
  const int tx = threadIdx.x & 31, ty = threadIdx.x >> 5;
  for (int i = ty; i < 32; i += 8)
    tile[i][tx] = src[((size_t)b * R + r0 + i) * C + c0 + tx];
  __syncthreads();
  for (int i = ty; i < 32; i += 8)
    dst[((size_t)b * C + c0 + i) * R + r0 + tx] = tile[tx][i];
}

// ---- filter bank: FcT[d][f][k] = -(e0[k*9+f][d] + e1[k*9+f][d]) ----
__global__ __launch_bounds__(256) void k_fc_make(const float2* __restrict__ e2,
                                                 float2* __restrict__ FcT) {
  const int o = blockIdx.x * 256 + threadIdx.x;
  if (o >= NBINS_ * D_) return;
  const int d = o / NBINS_;
  const int r = o - d * NBINS_;
  const int f = r / NFREQ_;
  const int k = r - f * NFREQ_;
  const int s = k * 9 + f;
  const float2 a = e2[(size_t)s * D_ + d];
  const float2 b = e2[(size_t)(NBINS_ + s) * D_ + d];
  FcT[o] = make_float2(-(a.x + b.x), -(a.y + b.y));
}

// ---- 4 weight matrices fp32 -> bf16, one launch ----
__global__ __launch_bounds__(256) void k_wconv4(const float* __restrict__ w0,
                                                const float* __restrict__ w1,
                                                const float* __restrict__ w2,
                                                const float* __restrict__ w3,
                                                unsigned short* __restrict__ o) {
  constexpr int NW = D_ * D_;
  const int i = blockIdx.x * 256 + threadIdx.x;
  if (i >= NW) return;
  const int m = blockIdx.y;
  const float* src = (m == 0) ? w0 : (m == 1) ? w1 : (m == 2) ? w2 : w3;
  o[(size_t)m * NW + i] = f2bf(src[i]);
}

// ------------- image rfft (ortho) + filter -> imgF (complex) -------------
__global__ __launch_bounds__(256) void k_img_rfft_filter(
    const float* __restrict__ image, const float2* __restrict__ bank2,
    float2* __restrict__ imgF) {
  const int f = blockIdx.x;  // 0..98
  const int b = blockIdx.y;
  const int tid = threadIdx.x;
  __shared__ float ct[N_], st[N_];
  if (tid < N_) {
    const int r = (f * tid) % N_;
    float s, c;
    sincosf(TWOPI_ * (float)r / (float)N_, &s, &c);
    ct[tid] = c; st[tid] = s;
  }
  __syncthreads();
  for (int d = tid; d < D_; d += 256) {
    float re = 0.f, im = 0.f;
    const float* ip = image + (size_t)b * N_ * D_ + d;
    for (int t = 0; t < N_; ++t) {
      const float v = ip[(size_t)t * D_];
      re = fmaf(v, ct[t], re);
      im = fmaf(-v, st[t], im);
    }
    const float sc = 1.0f / (196.0f * 99.0f);
    const float pr = (re * re - im * im) * sc;
    const float pi2 = (2.f * re * im) * sc;
    const size_t fd = (size_t)f * D_ + d;
    const float2 c0 = bank2[fd];
    const float2 c1 = bank2[(size_t)NF_ * D_ + fd];
    const float fcr = -(c0.x + c1.x), fci = -(c0.y + c1.y);
    imgF[(size_t)(b * NF_ + f) * D_ + d] =
        make_float2(pr * fcr - pi2 * fci, pr * fci + pi2 * fcr);
  }
}

// ---------------- gate: pooling + 1x1 conv fused ----------------
__global__ __launch_bounds__(256) void k_gate(const float2* __restrict__ imgF,
                                              const float2* __restrict__ gsel2,
                                              const float* __restrict__ W,
                                              const float* __restrict__ bias,
                                              float* __restrict__ gate) {
  const int b = blockIdx.x;
  __shared__ float row[D_];
  for (int d = threadIdx.x; d < D_; d += 256) {
    float acc = 0.f;
    for (int f = 0; f < NF_; ++f) {
      const float2 z = imgF[(size_t)(b * NF_ + f) * D_ + d];
      const float2 w = gsel2[(size_t)f * D_ + d];
      acc += z.x * w.x - z.y * w.y;
    }
    row[d] = acc * (1.0f / 99.0f);
  }
  __syncthreads();
  for (int d = threadIdx.x; d < D_; d += 256) {
    float acc = bias[d];
    const float* w = W + (size_t)d * D_;
    for (int e = 0; e < D_; e += 4) {
      const float4 wv = *reinterpret_cast<const float4*>(w + e);
      acc = fmaf(row[e], wv.x, acc);
      acc = fmaf(row[e + 1], wv.y, acc);
      acc = fmaf(row[e + 2], wv.z, acc);
      acc = fmaf(row[e + 3], wv.w, acc);
    }
    gate[b * D_ + d] = acc;
  }
}

// -------- image irfft (ortho) + residual --------
__global__ __launch_bounds__(256) void k_img_irfft_add(const float2* __restrict__ imgF,
                                                       const float* __restrict__ image,
                                                       float* __restrict__ ximg) {
  const int t = blockIdx.x;
  const int b = blockIdx.y;
  const int tid = threadIdx.x;
  __shared__ float cf[NF_], sf[NF_];
  if (tid < NF_) {
    const int r = (t * tid) % N_;
    float s, c;
    sincosf(TWOPI_ * (float)r / (float)N_, &s, &c);
    cf[tid] = c; sf[tid] = s;
  }
  __syncthreads();
  const float sgn_ny = (t & 1) ? -1.f : 1.f;
  for (int d = tid; d < D_; d += 256) {
    const float2* zp = imgF + (size_t)b * NF_ * D_ + d;
    float acc = zp[0].x;
    for (int f = 1; f < NF_ - 1; ++f) {
      const float2 z = zp[(size_t)f * D_];
      acc += 2.f * (z.x * cf[f] - z.y * sf[f]);
    }
    acc += zp[(size_t)(NF_ - 1) * D_].x * sgn_ny;
    const size_t idx = (size_t)(b * N_ + t) * D_ + d;
    ximg[idx] = acc * (1.0f / 14.0f) + image[idx];
  }
}

// ================= ecg fused FFT pipeline (quad double-stages) =================
// tw[h-1+j] = (cos(2*pi*j/(2h)), sin(2*pi*j/(2h)))

// two radix-2 stages (bits SS, SS+1) fused in registers; wave-local for SS<=6
template <int SS, int DIR>
__device__ __forceinline__ void dblpass(float2* z, const float2* tw, int q) {
  asm volatile("s_waitcnt lgkmcnt(0)" ::: "memory");
  const int h = 1 << SS;
  const int j = q & (h - 1);
  const int base = ((q >> SS) << (SS + 2)) | j;
  const int e0 = padz(base), e1 = padz(base + h);
  const int e2 = padz(base + 2 * h), e3 = padz(base + 3 * h);
  const float2 x0 = z[e0], x1 = z[e1], x2 = z[e2], x3 = z[e3];
  const float2 tw1 = tw[h - 1 + j];
  const float2 tw2 = tw[2 * h - 1 + j];
  const float sg = (DIR < 0) ? -1.f : 1.f;
  const float w1c = tw1.x, w1s = sg * tw1.y;
  const float w2c = tw2.x, w2s = sg * tw2.y;
  // stage SS: pairs (x0,x1), (x2,x3), twiddle w1
  const float t1r = x1.x * w1c - x1.y * w1s, t1i = x1.x * w1s + x1.y * w1c;
  const float t3r = x3.x * w1c - x3.y * w1s, t3i = x3.x * w1s + x3.y * w1c;
  const float a0r = x0.x + t1r, a0i = x0.y + t1i;
  const float a1r = x0.x - t1r, a1i = x0.y - t1i;
  const float a2r = x2.x + t3r, a2i = x2.y + t3i;
  const float a3r = x2.x - t3r, a3i = x2.y - t3i;
  // stage SS+1: (a0,a2) w2 ; (a1,a3) w2*(sg*i)
  const float u2r = a2r * w2c - a2i * w2s, u2i = a2r * w2s + a2i * w2c;
  const float v3r = a3r * w2c - a3i * w2s, v3i = a3r * w2s + a3i * w2c;
  const float u3r = -sg * v3i, u3i = sg * v3r;
  z[e0] = make_float2(a0r + u2r, a0i + u2i);
  z[e2] = make_float2(a0r - u2r, a0i - u2i);
  z[e1] = make_float2(a1r + u3r, a1i + u3i);
  z[e3] = make_float2(a1r - u3r, a1i - u3i);
}

template <int DIR>
__device__ __forceinline__ void stage8(float2* z, const float2* tw, int t) {
  const float2 w = tw[255 + t];
  const float wc = w.x, ws = (DIR < 0) ? -w.y : w.y;
  const int a0 = padz(t), a1 = padz(t + 256);
  const float2 x = z[a0], y = z[a1];
  const float tr = y.x * wc - y.y * ws, ti = y.x * ws + y.y * wc;
  z[a0] = make_float2(x.x + tr, x.y + ti);
  z[a1] = make_float2(x.x - tr, x.y - ti);
}

// filter+pack for one unit at bin k: reads Z[k],Z[512-k], outputs C at k and 512-k
template <int FA, int FB>
__device__ __forceinline__ void filt_pack(const float2* z, int k, float g,
                                          float2 cA, float2 cB,
                                          float2& Ck, float2& Cm) {
  const int q = (512 - k) & 511;
  const float2 Zk = z[padz(k)], Zq = z[padz(q)];
  const float sc = 0.5f / 256.f;
  const float ar = (Zk.x + Zq.x) * sc, ai = (Zk.y - Zq.y) * sc;
  float yar, yai, ybr = 0.f, ybi = 0.f;
  {
    const float pr = (ar * ar - ai * ai) * (1.f / 2313.f);
    const float pi = (2.f * ar * ai) * (1.f / 2313.f);
    yar = (pr * cA.x - pi * cA.y) * g;
    yai = (pr * cA.y + pi * cA.x) * g;
  }
  if (FB >= 0) {
    const float br = (Zk.y + Zq.y) * sc, bi = (Zq.x - Zk.x) * sc;
    const float pr = (br * br - bi * bi) * (1.f / 2313.f);
    const float pi = (2.f * br * bi) * (1.f / 2313.f);
    ybr = (pr * cB.x - pi * cB.y) * g;
    ybi = (pr * cB.y + pi * cB.x) * g;
  }
  if (k == 0 || k == 256) {  // c2r drops imag at DC/Nyquist
    Ck = make_float2(yar, ybr);
    Cm = Ck;  // unused for these k (same slot)
  } else {
    Ck = make_float2(yar - ybi, yai + ybr);
    Cm = make_float2(yar + ybi, ybr - yai);
  }
}

// one super-pass: unit A = frames (FA0 re, FB0 im) in zA; unit B in zB
template <int FA0, int FB0, int FA1, int FB1, bool DUAL>
__device__ __forceinline__ void ecg_super(int tid, float g, const float2* __restrict__ fc,
                                          const float* sig, const float2* tw,
                                          float2* zA, float2* zB, float* accr) {
  const float c0 = tw[255 + tid].x;
  const float wlo = 0.5f - 0.5f * c0;
  const float whi = 0.5f + 0.5f * c0;
  // prefetch filter coefs (global; consumed after fwd FFT)
  const float2 cA0 = fc[FA0 * 257 + tid];
  float2 cB0 = make_float2(0.f, 0.f), cA1 = cB0, cB1 = cB0;
  if (FB0 >= 0) cB0 = fc[FB0 * 257 + tid];
  if (DUAL) { cA1 = fc[FA1 * 257 + tid]; cB1 = fc[FB1 * 257 + tid]; }
  float2 nA0 = make_float2(0.f, 0.f), nB0 = nA0, nA1 = nA0, nB1 = nA0;
  if (tid == 0) {
    nA0 = fc[FA0 * 257 + 256];
    if (FB0 >= 0) nB0 = fc[FB0 * 257 + 256];
    if (DUAL) { nA1 = fc[FA1 * 257 + 256]; nB1 = fc[FB1 * 257 + 256]; }
  }
  __syncthreads();  // z buffers free (prior OA reads done)
  // ---- scatter windowed frames, bit-reversed ----
  {
    const int rlo = padz(rev9(tid)), rhi = padz(rev9(tid + 256));
    const float aLo = (FA0 == 0) ? 0.f : sig[FA0 * 256 - 256 + tid] * wlo;
    const float aHi = (FA0 == 8) ? 0.f : sig[FA0 * 256 + tid] * whi;
    const float bLo = (FB0 <= 0) ? 0.f : sig[FB0 * 256 - 256 + tid] * wlo;
    const float bHi = (FB0 < 0 || FB0 == 8) ? 0.f : sig[FB0 * 256 + tid] * whi;
    zA[rlo] = make_float2(aLo, bLo);
    zA[rhi] = make_float2(aHi, bHi);
    if (DUAL) {
      const float eLo = (FA1 == 0) ? 0.f : sig[FA1 * 256 - 256 + tid] * wlo;
      const float eHi = (FA1 == 8) ? 0.f : sig[FA1 * 256 + tid] * whi;
      const float fLo = (FB1 == 0) ? 0.f : sig[FB1 * 256 - 256 + tid] * wlo;
      const float fHi = (FB1 == 8) ? 0.f : sig[FB1 * 256 + tid] * whi;
      zB[rlo] = make_float2(eLo, fLo);
      zB[rhi] = make_float2(eHi, fHi);
    }
  }
  __syncthreads();
  // ---- forward: 4 wave-local double-stages ----
  if (DUAL || tid < 128) {
    float2* zz = (tid < 128) ? zA : zB;
    const int q = tid & 127;
    dblpass<0, -1>(zz, tw, q);
    dblpass<2, -1>(zz, tw, q);
    dblpass<4, -1>(zz, tw, q);
    dblpass<6, -1>(zz, tw, q);
  }
  __syncthreads();
  stage8<-1>(zA, tw, tid);
  if (DUAL) stage8<-1>(zB, tw, tid);
  __syncthreads();
  // ---- filter + conjugate pack (registers) ----
  float2 CAk, CAm, CBk, CBm;
  filt_pack<FA0, FB0>(zA, tid, g, cA0, cB0, CAk, CAm);
  float2 CAn, CBn, dum;
  if (tid == 0) filt_pack<FA0, FB0>(zA, 256, g, nA0, nB0, CAn, dum);
  if (DUAL) {
    filt_pack<FA1, FB1>(zB, tid, g, cA1, cB1, CBk, CBm);
    if (tid == 0) filt_pack<FA1, FB1>(zB, 256, g, nA1, nB1, CBn, dum);
  }
  __syncthreads();  // all reads of Z done before scatter
  {
    const int rk = padz(rev9(tid));
    zA[rk] = CAk;
    if (DUAL) zB[rk] = CBk;
    if (tid == 0) {
      zA[padz(1)] = CAn;               // rev9(256) = 1
      if (DUAL) zB[padz(1)] = CBn;
    } else {
      const int rm = padz(rev9(512 - tid));
      zA[rm] = CAm;
      if (DUAL) zB[rm] = CBm;
    }
  }
  __syncthreads();
  // ---- inverse ----
  if (DUAL || tid < 128) {
    float2* zz = (tid < 128) ? zA : zB;
    const int q = tid & 127;
    dblpass<0, 1>(zz, tw, q);
    dblpass<2, 1>(zz, tw, q);
    dblpass<4, 1>(zz, tw, q);
    dblpass<6, 1>(zz, tw, q);
  }
  __syncthreads();
  stage8<1>(zA, tw, tid);
  if (DUAL) stage8<1>(zB, tw, tid);
  // ---- overlap-add (own stage-8 outputs; xs = 0.5*win*Re/Im) ----
  {
    const float2 vLo = zA[padz(tid)], vHi = zA[padz(tid + 256)];
    accr[FA0] += 0.5f * wlo * vLo.x;
    accr[FA0 + 1] += 0.5f * whi * vHi.x;
    if (FB0 >= 0) {
      accr[FB0] += 0.5f * wlo * vLo.y;
      accr[FB0 + 1] += 0.5f * whi * vHi.y;
    }
    if (DUAL) {
      const float2 uLo = zB[padz(tid)], uHi = zB[padz(tid + 256)];
      accr[FA1] += 0.5f * wlo * uLo.x;
      accr[FA1 + 1] += 0.5f * whi * uHi.x;
      accr[FB1] += 0.5f * wlo * uLo.y;
      accr[FB1 + 1] += 0.5f * whi * uHi.y;
    }
  }
}

__global__ __launch_bounds__(256) void k_ecg_fft(
    const float* __restrict__ ecgT, const float2* __restrict__ FcT,
    const float* __restrict__ gate, float* __restrict__ xtT) {
  const int bd = blockIdx.x;
  const int d = bd % D_;
  const int tid = threadIdx.x;

  __shared__ float sig[S_];            // 8 KB
  __shared__ float2 tw[511];           // 4 KB
  __shared__ float2 zA[576], zB[576];  // 9 KB

  const float* src = ecgT + (size_t)bd * S_;
  for (int i = tid; i < S_; i += 256) sig[i] = src[i];
#pragma unroll
  for (int s = 0; s < 9; ++s) {
    const int h = 1 << s;
    for (int j = tid; j < h; j += 256) {
      float sn, cs;
      sincosf((float)j * (TWOPI_ / (2.0f * (float)h)), &sn, &cs);
      tw[h - 1 + j] = make_float2(cs, sn);
    }
  }
  __syncthreads();

  const float g = gate[bd];
  const float2* fc = FcT + (size_t)d * NBINS_;
  float accr[10];
#pragma unroll
  for (int i = 0; i < 10; ++i) accr[i] = 0.f;

  ecg_super<0, 8, 1, 2, true>(tid, g, fc, sig, tw, zA, zB, accr);
  ecg_super<3, 4, 5, 6, true>(tid, g, fc, sig, tw, zA, zB, accr);
  ecg_super<7, -1, 0, 0, false>(tid, g, fc, sig, tw, zA, zB, accr);

  const float c0 = tw[255 + tid].x;
  const float nrm = 0.5f + 0.5f * c0 * c0;  // win(n)^2 + win(n+256)^2
  float* dst = xtT + (size_t)bd * S_;
#pragma unroll
  for (int i2 = 0; i2 < 8; ++i2)
    dst[i2 * 256 + tid] = accr[i2 + 1] / nrm + sig[i2 * 256 + tid];
}

// ---- per-(b,t) LN stats over d, reading xtT[b][d][t] coalesced ----
__global__ __launch_bounds__(256) void k_colstats(const float* __restrict__ xtT,
                                                  float2* __restrict__ stats) {
  const int b = blockIdx.y;
  const int t0 = blockIdx.x * 64;
  const int tx = threadIdx.x & 63;
  const int ty = threadIdx.x >> 6;
  float s = 0.f, q = 0.f;
  const float* base = xtT + (size_t)b * D_ * S_ + t0 + tx;
  for (int dd = ty; dd < D_; dd += 4) {
    const float v = base[(size_t)dd * S_];
    s += v;
    q = fmaf(v, v, q);
  }
  __shared__ float sh_s[4][64], sh_q[4][64];
  sh_s[ty][tx] = s; sh_q[ty][tx] = q;
  __syncthreads();
  if (ty == 0) {
    s = sh_s[0][tx] + sh_s[1][tx] + sh_s[2][tx] + sh_s[3][tx];
    q = sh_q[0][tx] + sh_q[1][tx] + sh_q[2][tx] + sh_q[3][tx];
    stats[(size_t)b * S_ + t0 + tx] = make_float2(s, q);
  }
}

// ---- transpose + LN apply + bf16: xhat[b][t][d] = LN(xtT[b][d][t]) ----
__global__ __launch_bounds__(256) void k_transpose_ln(
    const float* __restrict__ xtT, const float2* __restrict__ stats,
    const float* __restrict__ g, const float* __restrict__ bia,
    unsigned short* __restrict__ xhat) {
  __shared__ float tile[32][33];
  const int b = blockIdx.z;
  const int t0 = blockIdx.x * 32;
  const int d0 = blockIdx.y * 32;
  const int tx = threadIdx.x & 31, ty = threadIdx.x >> 5;
  for (int i = ty; i < 32; i += 8)
    tile[i][tx] = xtT[((size_t)b * D_ + d0 + i) * S_ + t0 + tx];
  __syncthreads();
  const float gv = g[d0 + tx], bv = bia[d0 + tx];
  for (int i = ty; i < 32; i += 8) {
    const float2 st = stats[(size_t)b * S_ + t0 + i];
    const float mean = st.x * (1.0f / 768.0f);
    const float var = st.y * (1.0f / 768.0f) - mean * mean;
    const float inv = rsqrtf(var + 1e-5f);
    xhat[((size_t)b * S_ + t0 + i) * D_ + d0 + tx] =
        f2bf((tile[tx][i] - mean) * inv * gv + bv);
  }
}

// ---------------- LayerNorm over D=768; OUT: 0=f32, 1=bf16 ----------------
template <int BF16OUT>
__global__ __launch_bounds__(256) void k_layernorm(const float* __restrict__ x,
                                                   const float* __restrict__ g,
                                                   const float* __restrict__ b,
                                                   void* __restrict__ outv) {
  const int row = blockIdx.x;
  const int tid = threadIdx.x;
  const float* xr = x + (size_t)row * D_;
  const float v0 = xr[tid], v1 = xr[tid + 256], v2 = xr[tid + 512];
  float s = v0 + v1 + v2;
  float q = v0 * v0 + v1 * v1 + v2 * v2;
  __shared__ float red[8];
  for (int off = 32; off > 0; off >>= 1) {
    s += __shfl_down(s, off);
    q += __shfl_down(q, off);
  }
  if ((tid & 63) == 0) { red[tid >> 6] = s; red[4 + (tid >> 6)] = q; }
  __syncthreads();
  s = red[0] + red[1] + red[2] + red[3];
  q = red[4] + red[5] + red[6] + red[7];
  const float mean = s * (1.0f / 768.0f);
  const float var = q * (1.0f / 768.0f) - mean * mean;
  const float inv = rsqrtf(var + 1e-5f);
  const float o0 = (v0 - mean) * inv * g[tid] + b[tid];
  const float o1 = (v1 - mean) * inv * g[tid + 256] + b[tid + 256];
  const float o2 = (v2 - mean) * inv * g[tid + 512] + b[tid + 512];
  if (BF16OUT) {
    unsigned short* orow = (unsigned short*)outv + (size_t)row * D_;
    orow[tid] = f2bf(o0); orow[tid + 256] = f2bf(o1); orow[tid + 512] = f2bf(o2);
  } else {
    float* orow = (float*)outv + (size_t)row * D_;
    orow[tid] = o0; orow[tid + 256] = o1; orow[tid + 512] = o2;
  }
}

// ---------- MFMA GEMM: out = act(A @ W^T + bias [+resid]) ----------
template <int MODE>  // 0: exact GELU -> bf16 ; 1: +resid(bf16) -> f32
__global__ __launch_bounds__(256) void k_gemm_mfma(
    const unsigned short* __restrict__ Abf, const unsigned short* __restrict__ Wbf,
    const float* __restrict__ bias, const unsigned short* __restrict__ resid,
    void* __restrict__ outv, int M) {
  __shared__ unsigned short Asm[128 * 64];
  __shared__ unsigned short Bsm[128 * 64];
  const int tid = threadIdx.x;
  const int lane = tid & 63, wid = tid >> 6;
  const int wr = wid >> 1, wc = wid & 1;
  const int n0 = blockIdx.x * 128, m0 = blockIdx.y * 128;
  f32x4 acc[4][4] = {};
  for (int kt = 0; kt < 12; ++kt) {
    const int k0 = kt * 64;
#pragma unroll
    for (int i = 0; i < 4; ++i) {
      const int c = tid + 256 * i;
      const int row = c >> 3, sl = c & 7;
      const int gsl = sl ^ (row & 7);
      gload16(Abf + (size_t)(m0 + row) * 768 + k0 + gsl * 8, &Asm[c * 8]);
      gload16(Wbf + (size_t)(n0 + row) * 768 + k0 + gsl * 8, &Bsm[c * 8]);
    }
    __syncthreads();
#pragma unroll
    for (int ks = 0; ks < 2; ++ks) {
      bf16x8 af[4], bfv[4];
#pragma unroll
      for (int mi = 0; mi < 4; ++mi) {
        const int row = wr * 64 + mi * 16 + (lane & 15);
        const int sl = (ks * 4 + (lane >> 4)) ^ (row & 7);
        af[mi] = *(const bf16x8*)((const char*)Asm + row * 128 + sl * 16);
      }
#pragma unroll
      for (int ni = 0; ni < 4; ++ni) {
        const int row = wc * 64 + ni * 16 + (lane & 15);
        const int sl = (ks * 4 + (lane >> 4)) ^ (row & 7);
        bfv[ni] = *(const bf16x8*)((const char*)Bsm + row * 128 + sl * 16);
      }
#pragma unroll
      for (int mi = 0; mi < 4; ++mi)
#pragma unroll
        for (int ni = 0; ni < 4; ++ni)
          acc[mi][ni] = __builtin_amdgcn_mfma_f32_16x16x32_bf16(af[mi], bfv[ni],
                                                                acc[mi][ni], 0, 0, 0);
    }
    __syncthreads();
  }
#pragma unroll
  for (int mi = 0; mi < 4; ++mi) {
#pragma unroll
    for (int ni = 0; ni < 4; ++ni) {
      const int col = n0 + wc * 64 + ni * 16 + (lane & 15);
#pragma unroll
      for (int e = 0; e < 4; ++e) {
        const int row = m0 + wr * 64 + mi * 16 + (lane >> 4) * 4 + e;
        if (row >= M) continue;
        float v = acc[mi][ni][e] + bias[col];
        if (MODE == 0) {
          v = 0.5f * v * (1.0f + erff(v * 0.70710678118654752440f));
          ((unsigned short*)outv)[(size_t)row * 768 + col] = f2bf(v);
        } else {
          v += bf2f(resid[(size_t)row * 768 + col]);
          ((float*)outv)[(size_t)row * 768 + col] = v;
        }
      }
    }
  }
}

}  // namespace

extern "C" void kernel_launch(void* const* d_in, const int* in_sizes, int n_in,
                              void* d_out, int out_size, void* d_ws, size_t ws_size,
                              hipStream_t stream) {
  (void)in_sizes; (void)n_in; (void)out_size; (void)ws_size;
  const float* ecg     = (const float*)d_in[0];
  const float* image   = (const float*)d_in[1];
  const float* ebank   = (const float*)d_in[2];
  const float* cbank   = (const float*)d_in[3];
  const float* gsel    = (const float*)d_in[4];
  const float* gw      = (const float*)d_in[5];
  const float* gb      = (const float*)d_in[6];
  const float* e_ln1_g = (const float*)d_in[7];
  const float* e_ln1_b = (const float*)d_in[8];
  const float* e_w1    = (const float*)d_in[9];
  const float* e_b1    = (const float*)d_in[10];
  const float* e_w2    = (const float*)d_in[11];
  const float* e_b2    = (const float*)d_in[12];
  const float* e_ln2_g = (const float*)d_in[13];
  const float* e_ln2_b = (const float*)d_in[14];
  const float* c_ln1_g = (const float*)d_in[15];
  const float* c_ln1_b = (const float*)d_in[16];
  const float* c_w1    = (const float*)d_in[17];
  const float* c_b1    = (const float*)d_in[18];
  const float* c_w2    = (const float*)d_in[19];
  const float* c_b2    = (const float*)d_in[20];
  const float* c_ln2_g = (const float*)d_in[21];
  const float* c_ln2_b = (const float*)d_in[22];

  float* out = (float*)d_out;
  float* ws = (float*)d_ws;

  constexpr size_t TXT = (size_t)8 * 2048 * 768;   // 12,582,912 floats
  constexpr size_t IMG = (size_t)8 * 196 * 768;    // 1,204,224 floats
  constexpr int NW = 768 * 768;                    // 589,824

  // ws layout: A (TXT) | Bb (TXT) | wbf (4*NW ushort) | gatev | stats  ~105.8 MB
  float* A  = ws;
  float* Bb = A + TXT;
  unsigned short* wbf = (unsigned short*)(Bb + TXT);
  unsigned short* ew1b = wbf;
  unsigned short* ew2b = wbf + NW;
  unsigned short* cw1b = wbf + 2 * NW;
  unsigned short* cw2b = wbf + 3 * NW;
  float* gatev = (float*)(wbf + 4 * (size_t)NW);
  float2* stats = (float2*)(gatev + 8 * 768);

  // FcT (2313*768 float2 = 14.2 MB) parked in d_out[0:TXT] (dead before final LN)
  float2* FcT = (float2*)out;

  // image-path scratch inside A (fully consumed before ecg transpose overwrites A)
  float* ximg = A;
  unsigned short* xh_i = (unsigned short*)(A + IMG);
  unsigned short* h_i  = (unsigned short*)(A + IMG + IMG / 2);
  float* y_i = A + 2 * IMG;

  // text buffers
  unsigned short* xhat = (unsigned short*)A;             // bf16 LN1 out / resid
  unsigned short* h_t  = (unsigned short*)(A + TXT / 2); // bf16 GELU act
  float* y_t = Bb;                                       // f32 pre-LN2

  // ---- one-time prep ----
  k_fc_make<<<(NBINS_ * D_ + 255) / 256, 256, 0, stream>>>((const float2*)ebank, FcT);
  k_wconv4<<<dim3((NW + 255) / 256, 4), 256, 0, stream>>>(e_w1, e_w2, c_w1, c_w2, wbf);

  // ---- image path (produces gate) ----
  k_img_rfft_filter<<<dim3(99, 8), 256, 0, stream>>>(image, (const float2*)cbank,
                                                     (float2*)Bb);
  k_gate<<<8, 256, 0, stream>>>((const float2*)Bb, (const float2*)gsel, gw, gb, gatev);
  k_img_irfft_add<<<dim3(196, 8), 256, 0, stream>>>((const float2*)Bb, image, ximg);

  k_layernorm<1><<<1568, 256, 0, stream>>>(ximg, c_ln1_g, c_ln1_b, xh_i);
  k_gemm_mfma<0><<<dim3(6, 13), 256, 0, stream>>>(xh_i, cw1b, c_b1, nullptr, h_i, 1568);
  k_gemm_mfma<1><<<dim3(6, 13), 256, 0, stream>>>(h_i, cw2b, c_b2, xh_i, y_i, 1568);
  k_layernorm<0><<<1568, 256, 0, stream>>>(y_i, c_ln2_g, c_ln2_b, out + TXT);

  // ---- ecg path ----
  k_transpose_g<<<dim3(24, 64, 8), 256, 0, stream>>>(ecg, A, 2048, 768);
  k_ecg_fft<<<8 * 768, 256, 0, stream>>>(A, FcT, gatev, Bb);
  k_colstats<<<dim3(32, 8), 256, 0, stream>>>(Bb, stats);
  k_transpose_ln<<<dim3(64, 24, 8), 256, 0, stream>>>(Bb, stats, e_ln1_g, e_ln1_b, xhat);

  // ---- text FFN (bf16 MFMA) ----
  k_gemm_mfma<0><<<dim3(6, 128), 256, 0, stream>>>(xhat, ew1b, e_b1, nullptr, h_t, 16384);
  k_gemm_mfma<1><<<dim3(6, 128), 256, 0, stream>>>(h_t, ew2b, e_b2, xhat, y_t, 16384);
  k_layernorm<0><<<16384, 256, 0, stream>>>(y_t, e_ln2_g, e_ln2_b, out);
}

// Round 5
// 594.498 us; speedup vs baseline: 5.3370x; 1.1126x over previous
//
#include <hip/hip_runtime.h>
#include <math.h>

namespace {

constexpr int B_ = 8;
constexpr int S_ = 2048;
constexpr int D_ = 768;
constexpr int N_ = 196;     // image spatial
constexpr int NF_ = 99;     // image freq bins
constexpr int NFREQ_ = 257;
constexpr int NSEG_ = 9;
constexpr int NBINS_ = NFREQ_ * NSEG_;  // 2313
constexpr float TWOPI_ = 6.28318530717958647692f;

using bf16x8 = __attribute__((ext_vector_type(8))) short;
using f32x4  = __attribute__((ext_vector_type(4))) float;

__device__ __forceinline__ int rev9(int x) { return (int)(__brev((unsigned)x) >> 23); }
__device__ __forceinline__ int padz(int i) { return i + (i >> 3); }  // float2 elements

__device__ __forceinline__ unsigned short f2bf(float x) {
  unsigned u = __float_as_uint(x);
  u = (u + 0x7FFFu + ((u >> 16) & 1u)) >> 16;
  return (unsigned short)u;
}
__device__ __forceinline__ float bf2f(unsigned short h) {
  return __uint_as_float(((unsigned)h) << 16);
}

__device__ __forceinline__ void gload16(const void* g, void* l) {
  __builtin_amdgcn_global_load_lds((const __attribute__((address_space(1))) void*)g,
                                   (__attribute__((address_space(3))) void*)l, 16, 0, 0);
}

// ---------------- batched transpose (B,R,C) -> (B,C,R) ----------------
__global__ __launch_bounds__(256) void k_transpose_g(const float* __restrict__ src,
                                                     float* __restrict__ dst,
                                                     int R, int C) {
  __shared__ float tile[32][33];
  const int b = blockIdx.z;
  const int c0 = blockIdx.x * 32;
  const int r0 = blockIdx.y * 32;
  const int tx = threadIdx.x & 31, ty = threadIdx.x >> 5;
  for (int i = ty; i < 32; i += 8)
    tile[i][tx] = src[((size_t)b * R + r0 + i) * C + c0 + tx];
  __syncthreads();
  for (int i = ty; i < 32; i += 8)
    dst[((size_t)b * C + c0 + i) * R + r0 + tx] = tile[tx][i];
}

// ---- filter bank: FcT[d][f][k] = -(e0[k*9+f][d] + e1[k*9+f][d]) ----
__global__ __launch_bounds__(256) void k_fc_make(const float2* __restrict__ e2,
                                                 float2* __restrict__ FcT) {
  const int o = blockIdx.x * 256 + threadIdx.x;
  if (o >= NBINS_ * D_) return;
  const int d = o / NBINS_;
  const int r = o - d * NBINS_;
  const int f = r / NFREQ_;
  const int k = r - f * NFREQ_;
  const int s = k * 9 + f;
  const float2 a = e2[(size_t)s * D_ + d];
  const float2 b = e2[(size_t)(NBINS_ + s) * D_ + d];
  FcT[o] = make_float2(-(a.x + b.x), -(a.y + b.y));
}

// ---- 4 weight matrices fp32 -> bf16, one launch ----
__global__ __launch_bounds__(256) void k_wconv4(const float* __restrict__ w0,
                                                const float* __restrict__ w1,
                                                const float* __restrict__ w2,
                                                const float* __restrict__ w3,
                                                unsigned short* __restrict__ o) {
  constexpr int NW = D_ * D_;
  const int i = blockIdx.x * 256 + threadIdx.x;
  if (i >= NW) return;
  const int m = blockIdx.y;
  const float* src = (m == 0) ? w0 : (m == 1) ? w1 : (m == 2) ? w2 : w3;
  o[(size_t)m * NW + i] = f2bf(src[i]);
}

// ------------- image rfft (ortho) + filter -> imgF (complex) -------------
__global__ __launch_bounds__(256) void k_img_rfft_filter(
    const float* __restrict__ image, const float2* __restrict__ bank2,
    float2* __restrict__ imgF) {
  const int f = blockIdx.x;  // 0..98
  const int b = blockIdx.y;
  const int tid = threadIdx.x;
  __shared__ float ct[N_], st[N_];
  if (tid < N_) {
    const int r = (f * tid) % N_;
    float s, c;
    sincosf(TWOPI_ * (float)r / (float)N_, &s, &c);
    ct[tid] = c; st[tid] = s;
  }
  __syncthreads();
  for (int d = tid; d < D_; d += 256) {
    float re = 0.f, im = 0.f;
    const float* ip = image + (size_t)b * N_ * D_ + d;
    for (int t = 0; t < N_; ++t) {
      const float v = ip[(size_t)t * D_];
      re = fmaf(v, ct[t], re);
      im = fmaf(-v, st[t], im);
    }
    const float sc = 1.0f / (196.0f * 99.0f);
    const float pr = (re * re - im * im) * sc;
    const float pi2 = (2.f * re * im) * sc;
    const size_t fd = (size_t)f * D_ + d;
    const float2 c0 = bank2[fd];
    const float2 c1 = bank2[(size_t)NF_ * D_ + fd];
    const float fcr = -(c0.x + c1.x), fci = -(c0.y + c1.y);
    imgF[(size_t)(b * NF_ + f) * D_ + d] =
        make_float2(pr * fcr - pi2 * fci, pr * fci + pi2 * fcr);
  }
}

// ---- gate pooling, partials over freq chunks: part[b][p][d] ----
__global__ __launch_bounds__(256) void k_gate_pool(const float2* __restrict__ imgF,
                                                   const float2* __restrict__ gsel2,
                                                   float* __restrict__ part) {
  const int b = blockIdx.x;
  const int p = blockIdx.y;           // 0..3
  const int f0 = p * 25;
  const int f1 = (p == 3) ? NF_ : f0 + 25;
  for (int d = threadIdx.x; d < D_; d += 256) {
    float acc = 0.f;
    for (int f = f0; f < f1; ++f) {
      const float2 z = imgF[(size_t)(b * NF_ + f) * D_ + d];
      const float2 w = gsel2[(size_t)f * D_ + d];
      acc += z.x * w.x - z.y * w.y;
    }
    part[((size_t)b * 4 + p) * D_ + d] = acc;
  }
}

// ---- gate matvec, all batches per block: gate[b][d0..d0+16) ----
__global__ __launch_bounds__(256) void k_gate_mm2(const float* __restrict__ part,
                                                  const float* __restrict__ W,
                                                  const float* __restrict__ bias,
                                                  float* __restrict__ gate) {
  __shared__ float row[8][D_];      // pooled rows, 24 KB
  __shared__ float red[16][16][8];  // partial sums, 8 KB
  const int tid = threadIdx.x;
  const int d0 = blockIdx.x * 16;
  // fold partials: row[b][e] = (p0+p1+p2+p3)/99
  for (int i = tid; i < 8 * D_; i += 256) {
    const int b = i / D_, e = i - b * D_;
    const float s = part[((size_t)b * 4 + 0) * D_ + e] + part[((size_t)b * 4 + 1) * D_ + e] +
                    part[((size_t)b * 4 + 2) * D_ + e] + part[((size_t)b * 4 + 3) * D_ + e];
    row[b][e] = s * (1.0f / 99.0f);
  }
  __syncthreads();
  const int dl = tid >> 4;          // 0..15
  const int ec = tid & 15;          // 0..15, 48 e each
  const float* w = W + (size_t)(d0 + dl) * D_ + ec * 48;
  float acc[8] = {};
  for (int e = 0; e < 48; e += 4) {
    const float4 wv = *reinterpret_cast<const float4*>(w + e);
    const int eg = ec * 48 + e;
#pragma unroll
    for (int b = 0; b < 8; ++b) {
      acc[b] = fmaf(row[b][eg], wv.x, acc[b]);
      acc[b] = fmaf(row[b][eg + 1], wv.y, acc[b]);
      acc[b] = fmaf(row[b][eg + 2], wv.z, acc[b]);
      acc[b] = fmaf(row[b][eg + 3], wv.w, acc[b]);
    }
  }
#pragma unroll
  for (int b = 0; b < 8; ++b) red[dl][ec][b] = acc[b];
  __syncthreads();
  if (tid < 128) {
    const int dl2 = tid >> 3, b = tid & 7;
    float s = bias[d0 + dl2];
    for (int c = 0; c < 16; ++c) s += red[dl2][c][b];
    gate[b * D_ + d0 + dl2] = s;
  }
}

// -------- image irfft (ortho) + residual --------
__global__ __launch_bounds__(256) void k_img_irfft_add(const float2* __restrict__ imgF,
                                                       const float* __restrict__ image,
                                                       float* __restrict__ ximg) {
  const int t = blockIdx.x;
  const int b = blockIdx.y;
  const int tid = threadIdx.x;
  __shared__ float cf[NF_], sf[NF_];
  if (tid < NF_) {
    const int r = (t * tid) % N_;
    float s, c;
    sincosf(TWOPI_ * (float)r / (float)N_, &s, &c);
    cf[tid] = c; sf[tid] = s;
  }
  __syncthreads();
  const float sgn_ny = (t & 1) ? -1.f : 1.f;
  for (int d = tid; d < D_; d += 256) {
    const float2* zp = imgF + (size_t)b * NF_ * D_ + d;
    float acc = zp[0].x;
    for (int f = 1; f < NF_ - 1; ++f) {
      const float2 z = zp[(size_t)f * D_];
      acc += 2.f * (z.x * cf[f] - z.y * sf[f]);
    }
    acc += zp[(size_t)(NF_ - 1) * D_].x * sgn_ny;
    const size_t idx = (size_t)(b * N_ + t) * D_ + d;
    ximg[idx] = acc * (1.0f / 14.0f) + image[idx];
  }
}

// ================= ecg fused FFT pipeline (quad double-stages) =================
template <int SS, int DIR>
__device__ __forceinline__ void dblpass(float2* z, const float2* tw, int q) {
  asm volatile("s_waitcnt lgkmcnt(0)" ::: "memory");
  const int h = 1 << SS;
  const int j = q & (h - 1);
  const int base = ((q >> SS) << (SS + 2)) | j;
  const int e0 = padz(base), e1 = padz(base + h);
  const int e2 = padz(base + 2 * h), e3 = padz(base + 3 * h);
  const float2 x0 = z[e0], x1 = z[e1], x2 = z[e2], x3 = z[e3];
  const float2 tw1 = tw[h - 1 + j];
  const float2 tw2 = tw[2 * h - 1 + j];
  const float sg = (DIR < 0) ? -1.f : 1.f;
  const float w1c = tw1.x, w1s = sg * tw1.y;
  const float w2c = tw2.x, w2s = sg * tw2.y;
  const float t1r = x1.x * w1c - x1.y * w1s, t1i = x1.x * w1s + x1.y * w1c;
  const float t3r = x3.x * w1c - x3.y * w1s, t3i = x3.x * w1s + x3.y * w1c;
  const float a0r = x0.x + t1r, a0i = x0.y + t1i;
  const float a1r = x0.x - t1r, a1i = x0.y - t1i;
  const float a2r = x2.x + t3r, a2i = x2.y + t3i;
  const float a3r = x2.x - t3r, a3i = x2.y - t3i;
  const float u2r = a2r * w2c - a2i * w2s, u2i = a2r * w2s + a2i * w2c;
  const float v3r = a3r * w2c - a3i * w2s, v3i = a3r * w2s + a3i * w2c;
  const float u3r = -sg * v3i, u3i = sg * v3r;
  z[e0] = make_float2(a0r + u2r, a0i + u2i);
  z[e2] = make_float2(a0r - u2r, a0i - u2i);
  z[e1] = make_float2(a1r + u3r, a1i + u3i);
  z[e3] = make_float2(a1r - u3r, a1i - u3i);
}

template <int DIR>
__device__ __forceinline__ void stage8(float2* z, const float2* tw, int t) {
  const float2 w = tw[255 + t];
  const float wc = w.x, ws = (DIR < 0) ? -w.y : w.y;
  const int a0 = padz(t), a1 = padz(t + 256);
  const float2 x = z[a0], y = z[a1];
  const float tr = y.x * wc - y.y * ws, ti = y.x * ws + y.y * wc;
  z[a0] = make_float2(x.x + tr, x.y + ti);
  z[a1] = make_float2(x.x - tr, x.y - ti);
}

template <int FA, int FB>
__device__ __forceinline__ void filt_pack(const float2* z, int k, float g,
                                          float2 cA, float2 cB,
                                          float2& Ck, float2& Cm) {
  const int q = (512 - k) & 511;
  const float2 Zk = z[padz(k)], Zq = z[padz(q)];
  const float sc = 0.5f / 256.f;
  const float ar = (Zk.x + Zq.x) * sc, ai = (Zk.y - Zq.y) * sc;
  float yar, yai, ybr = 0.f, ybi = 0.f;
  {
    const float pr = (ar * ar - ai * ai) * (1.f / 2313.f);
    const float pi = (2.f * ar * ai) * (1.f / 2313.f);
    yar = (pr * cA.x - pi * cA.y) * g;
    yai = (pr * cA.y + pi * cA.x) * g;
  }
  if (FB >= 0) {
    const float br = (Zk.y + Zq.y) * sc, bi = (Zq.x - Zk.x) * sc;
    const float pr = (br * br - bi * bi) * (1.f / 2313.f);
    const float pi = (2.f * br * bi) * (1.f / 2313.f);
    ybr = (pr * cB.x - pi * cB.y) * g;
    ybi = (pr * cB.y + pi * cB.x) * g;
  }
  if (k == 0 || k == 256) {
    Ck = make_float2(yar, ybr);
    Cm = Ck;
  } else {
    Ck = make_float2(yar - ybi, yai + ybr);
    Cm = make_float2(yar + ybi, ybr - yai);
  }
}

template <int FA0, int FB0, int FA1, int FB1, bool DUAL>
__device__ __forceinline__ void ecg_super(int tid, float g, const float2* __restrict__ fc,
                                          const float* sig, const float2* tw,
                                          float2* zA, float2* zB, float* accr) {
  const float c0 = tw[255 + tid].x;
  const float wlo = 0.5f - 0.5f * c0;
  const float whi = 0.5f + 0.5f * c0;
  const float2 cA0 = fc[FA0 * 257 + tid];
  float2 cB0 = make_float2(0.f, 0.f), cA1 = cB0, cB1 = cB0;
  if (FB0 >= 0) cB0 = fc[FB0 * 257 + tid];
  if (DUAL) { cA1 = fc[FA1 * 257 + tid]; cB1 = fc[FB1 * 257 + tid]; }
  float2 nA0 = make_float2(0.f, 0.f), nB0 = nA0, nA1 = nA0, nB1 = nA0;
  if (tid == 0) {
    nA0 = fc[FA0 * 257 + 256];
    if (FB0 >= 0) nB0 = fc[FB0 * 257 + 256];
    if (DUAL) { nA1 = fc[FA1 * 257 + 256]; nB1 = fc[FB1 * 257 + 256]; }
  }
  __syncthreads();
  {
    const int rlo = padz(rev9(tid)), rhi = padz(rev9(tid + 256));
    const float aLo = (FA0 == 0) ? 0.f : sig[FA0 * 256 - 256 + tid] * wlo;
    const float aHi = (FA0 == 8) ? 0.f : sig[FA0 * 256 + tid] * whi;
    const float bLo = (FB0 <= 0) ? 0.f : sig[FB0 * 256 - 256 + tid] * wlo;
    const float bHi = (FB0 < 0 || FB0 == 8) ? 0.f : sig[FB0 * 256 + tid] * whi;
    zA[rlo] = make_float2(aLo, bLo);
    zA[rhi] = make_float2(aHi, bHi);
    if (DUAL) {
      const float eLo = (FA1 == 0) ? 0.f : sig[FA1 * 256 - 256 + tid] * wlo;
      const float eHi = (FA1 == 8) ? 0.f : sig[FA1 * 256 + tid] * whi;
      const float fLo = (FB1 == 0) ? 0.f : sig[FB1 * 256 - 256 + tid] * wlo;
      const float fHi = (FB1 == 8) ? 0.f : sig[FB1 * 256 + tid] * whi;
      zB[rlo] = make_float2(eLo, fLo);
      zB[rhi] = make_float2(eHi, fHi);
    }
  }
  __syncthreads();
  if (DUAL || tid < 128) {
    float2* zz = (tid < 128) ? zA : zB;
    const int q = tid & 127;
    dblpass<0, -1>(zz, tw, q);
    dblpass<2, -1>(zz, tw, q);
    dblpass<4, -1>(zz, tw, q);
    dblpass<6, -1>(zz, tw, q);
  }
  __syncthreads();
  stage8<-1>(zA, tw, tid);
  if (DUAL) stage8<-1>(zB, tw, tid);
  __syncthreads();
  float2 CAk, CAm, CBk, CBm;
  filt_pack<FA0, FB0>(zA, tid, g, cA0, cB0, CAk, CAm);
  float2 CAn, CBn, dum;
  if (tid == 0) filt_pack<FA0, FB0>(zA, 256, g, nA0, nB0, CAn, dum);
  if (DUAL) {
    filt_pack<FA1, FB1>(zB, tid, g, cA1, cB1, CBk, CBm);
    if (tid == 0) filt_pack<FA1, FB1>(zB, 256, g, nA1, nB1, CBn, dum);
  }
  __syncthreads();
  {
    const int rk = padz(rev9(tid));
    zA[rk] = CAk;
    if (DUAL) zB[rk] = CBk;
    if (tid == 0) {
      zA[padz(1)] = CAn;
      if (DUAL) zB[padz(1)] = CBn;
    } else {
      const int rm = padz(rev9(512 - tid));
      zA[rm] = CAm;
      if (DUAL) zB[rm] = CBm;
    }
  }
  __syncthreads();
  if (DUAL || tid < 128) {
    float2* zz = (tid < 128) ? zA : zB;
    const int q = tid & 127;
    dblpass<0, 1>(zz, tw, q);
    dblpass<2, 1>(zz, tw, q);
    dblpass<4, 1>(zz, tw, q);
    dblpass<6, 1>(zz, tw, q);
  }
  __syncthreads();
  stage8<1>(zA, tw, tid);
  if (DUAL) stage8<1>(zB, tw, tid);
  {
    const float2 vLo = zA[padz(tid)], vHi = zA[padz(tid + 256)];
    accr[FA0] += 0.5f * wlo * vLo.x;
    accr[FA0 + 1] += 0.5f * whi * vHi.x;
    if (FB0 >= 0) {
      accr[FB0] += 0.5f * wlo * vLo.y;
      accr[FB0 + 1] += 0.5f * whi * vHi.y;
    }
    if (DUAL) {
      const float2 uLo = zB[padz(tid)], uHi = zB[padz(tid + 256)];
      accr[FA1] += 0.5f * wlo * uLo.x;
      accr[FA1 + 1] += 0.5f * whi * uHi.x;
      accr[FB1] += 0.5f * wlo * uLo.y;
      accr[FB1 + 1] += 0.5f * whi * uHi.y;
    }
  }
}

__global__ __launch_bounds__(256) void k_ecg_fft(
    const float* __restrict__ ecgT, const float2* __restrict__ FcT,
    const float* __restrict__ gate, float* __restrict__ xtT) {
  const int bd = blockIdx.x;
  const int d = bd % D_;
  const int tid = threadIdx.x;

  __shared__ float sig[S_];
  __shared__ float2 tw[511];
  __shared__ float2 zA[576], zB[576];

  const float* src = ecgT + (size_t)bd * S_;
  for (int i = tid; i < S_; i += 256) sig[i] = src[i];
#pragma unroll
  for (int s = 0; s < 9; ++s) {
    const int h = 1 << s;
    for (int j = tid; j < h; j += 256) {
      float sn, cs;
      sincosf((float)j * (TWOPI_ / (2.0f * (float)h)), &sn, &cs);
      tw[h - 1 + j] = make_float2(cs, sn);
    }
  }
  __syncthreads();

  const float g = gate[bd];
  const float2* fc = FcT + (size_t)d * NBINS_;
  float accr[10];
#pragma unroll
  for (int i = 0; i < 10; ++i) accr[i] = 0.f;

  ecg_super<0, 8, 1, 2, true>(tid, g, fc, sig, tw, zA, zB, accr);
  ecg_super<3, 4, 5, 6, true>(tid, g, fc, sig, tw, zA, zB, accr);
  ecg_super<7, -1, 0, 0, false>(tid, g, fc, sig, tw, zA, zB, accr);

  const float c0 = tw[255 + tid].x;
  const float nrm = 0.5f + 0.5f * c0 * c0;
  float* dst = xtT + (size_t)bd * S_;
#pragma unroll
  for (int i2 = 0; i2 < 8; ++i2)
    dst[i2 * 256 + tid] = accr[i2 + 1] / nrm + sig[i2 * 256 + tid];
}

// ---- per-(b,t) LN stats over d, reading xtT[b][d][t] coalesced ----
__global__ __launch_bounds__(256) void k_colstats(const float* __restrict__ xtT,
                                                  float2* __restrict__ stats) {
  const int b = blockIdx.y;
  const int t0 = blockIdx.x * 64;
  const int tx = threadIdx.x & 63;
  const int ty = threadIdx.x >> 6;
  float s = 0.f, q = 0.f;
  const float* base = xtT + (size_t)b * D_ * S_ + t0 + tx;
  for (int dd = ty; dd < D_; dd += 4) {
    const float v = base[(size_t)dd * S_];
    s += v;
    q = fmaf(v, v, q);
  }
  __shared__ float sh_s[4][64], sh_q[4][64];
  sh_s[ty][tx] = s; sh_q[ty][tx] = q;
  __syncthreads();
  if (ty == 0) {
    s = sh_s[0][tx] + sh_s[1][tx] + sh_s[2][tx] + sh_s[3][tx];
    q = sh_q[0][tx] + sh_q[1][tx] + sh_q[2][tx] + sh_q[3][tx];
    stats[(size_t)b * S_ + t0 + tx] = make_float2(s, q);
  }
}

// ---- transpose + LN apply + bf16 ----
__global__ __launch_bounds__(256) void k_transpose_ln(
    const float* __restrict__ xtT, const float2* __restrict__ stats,
    const float* __restrict__ g, const float* __restrict__ bia,
    unsigned short* __restrict__ xhat) {
  __shared__ float tile[32][33];
  const int b = blockIdx.z;
  const int t0 = blockIdx.x * 32;
  const int d0 = blockIdx.y * 32;
  const int tx = threadIdx.x & 31, ty = threadIdx.x >> 5;
  for (int i = ty; i < 32; i += 8)
    tile[i][tx] = xtT[((size_t)b * D_ + d0 + i) * S_ + t0 + tx];
  __syncthreads();
  const float gv = g[d0 + tx], bv = bia[d0 + tx];
  for (int i = ty; i < 32; i += 8) {
    const float2 st = stats[(size_t)b * S_ + t0 + i];
    const float mean = st.x * (1.0f / 768.0f);
    const float var = st.y * (1.0f / 768.0f) - mean * mean;
    const float inv = rsqrtf(var + 1e-5f);
    xhat[((size_t)b * S_ + t0 + i) * D_ + d0 + tx] =
        f2bf((tile[tx][i] - mean) * inv * gv + bv);
  }
}

// ---------------- LayerNorm over D=768; OUT: 0=f32, 1=bf16 ----------------
template <int BF16OUT>
__global__ __launch_bounds__(256) void k_layernorm(const float* __restrict__ x,
                                                   const float* __restrict__ g,
                                                   const float* __restrict__ b,
                                                   void* __restrict__ outv) {
  const int row = blockIdx.x;
  const int tid = threadIdx.x;
  const float* xr = x + (size_t)row * D_;
  const float v0 = xr[tid], v1 = xr[tid + 256], v2 = xr[tid + 512];
  float s = v0 + v1 + v2;
  float q = v0 * v0 + v1 * v1 + v2 * v2;
  __shared__ float red[8];
  for (int off = 32; off > 0; off >>= 1) {
    s += __shfl_down(s, off);
    q += __shfl_down(q, off);
  }
  if ((tid & 63) == 0) { red[tid >> 6] = s; red[4 + (tid >> 6)] = q; }
  __syncthreads();
  s = red[0] + red[1] + red[2] + red[3];
  q = red[4] + red[5] + red[6] + red[7];
  const float mean = s * (1.0f / 768.0f);
  const float var = q * (1.0f / 768.0f) - mean * mean;
  const float inv = rsqrtf(var + 1e-5f);
  const float o0 = (v0 - mean) * inv * g[tid] + b[tid];
  const float o1 = (v1 - mean) * inv * g[tid + 256] + b[tid + 256];
  const float o2 = (v2 - mean) * inv * g[tid + 512] + b[tid + 512];
  if (BF16OUT) {
    unsigned short* orow = (unsigned short*)outv + (size_t)row * D_;
    orow[tid] = f2bf(o0); orow[tid + 256] = f2bf(o1); orow[tid + 512] = f2bf(o2);
  } else {
    float* orow = (float*)outv + (size_t)row * D_;
    orow[tid] = o0; orow[tid + 256] = o1; orow[tid + 512] = o2;
  }
}

// ---------- MFMA GEMM: out = act(A @ W^T + bias [+resid]) ----------
template <int MODE>  // 0: exact GELU -> bf16 ; 1: +resid(bf16) -> f32
__global__ __launch_bounds__(256) void k_gemm_mfma(
    const unsigned short* __restrict__ Abf, const unsigned short* __restrict__ Wbf,
    const float* __restrict__ bias, const unsigned short* __restrict__ resid,
    void* __restrict__ outv, int M) {
  __shared__ unsigned short Asm[128 * 64];
  __shared__ unsigned short Bsm[128 * 64];
  const int tid = threadIdx.x;
  const int lane = tid & 63, wid = tid >> 6;
  const int wr = wid >> 1, wc = wid & 1;
  const int n0 = blockIdx.x * 128, m0 = blockIdx.y * 128;
  f32x4 acc[4][4] = {};
  for (int kt = 0; kt < 12; ++kt) {
    const int k0 = kt * 64;
#pragma unroll
    for (int i = 0; i < 4; ++i) {
      const int c = tid + 256 * i;
      const int row = c >> 3, sl = c & 7;
      const int gsl = sl ^ (row & 7);
      gload16(Abf + (size_t)(m0 + row) * 768 + k0 + gsl * 8, &Asm[c * 8]);
      gload16(Wbf + (size_t)(n0 + row) * 768 + k0 + gsl * 8, &Bsm[c * 8]);
    }
    __syncthreads();
#pragma unroll
    for (int ks = 0; ks < 2; ++ks) {
      bf16x8 af[4], bfv[4];
#pragma unroll
      for (int mi = 0; mi < 4; ++mi) {
        const int row = wr * 64 + mi * 16 + (lane & 15);
        const int sl = (ks * 4 + (lane >> 4)) ^ (row & 7);
        af[mi] = *(const bf16x8*)((const char*)Asm + row * 128 + sl * 16);
      }
#pragma unroll
      for (int ni = 0; ni < 4; ++ni) {
        const int row = wc * 64 + ni * 16 + (lane & 15);
        const int sl = (ks * 4 + (lane >> 4)) ^ (row & 7);
        bfv[ni] = *(const bf16x8*)((const char*)Bsm + row * 128 + sl * 16);
      }
#pragma unroll
      for (int mi = 0; mi < 4; ++mi)
#pragma unroll
        for (int ni = 0; ni < 4; ++ni)
          acc[mi][ni] = __builtin_amdgcn_mfma_f32_16x16x32_bf16(af[mi], bfv[ni],
                                                                acc[mi][ni], 0, 0, 0);
    }
    __syncthreads();
  }
#pragma unroll
  for (int mi = 0; mi < 4; ++mi) {
#pragma unroll
    for (int ni = 0; ni < 4; ++ni) {
      const int col = n0 + wc * 64 + ni * 16 + (lane & 15);
#pragma unroll
      for (int e = 0; e < 4; ++e) {
        const int row = m0 + wr * 64 + mi * 16 + (lane >> 4) * 4 + e;
        if (row >= M) continue;
        float v = acc[mi][ni][e] + bias[col];
        if (MODE == 0) {
          v = 0.5f * v * (1.0f + erff(v * 0.70710678118654752440f));
          ((unsigned short*)outv)[(size_t)row * 768 + col] = f2bf(v);
        } else {
          v += bf2f(resid[(size_t)row * 768 + col]);
          ((float*)outv)[(size_t)row * 768 + col] = v;
        }
      }
    }
  }
}

}  // namespace

extern "C" void kernel_launch(void* const* d_in, const int* in_sizes, int n_in,
                              void* d_out, int out_size, void* d_ws, size_t ws_size,
                              hipStream_t stream) {
  (void)in_sizes; (void)n_in; (void)out_size; (void)ws_size;
  const float* ecg     = (const float*)d_in[0];
  const float* image   = (const float*)d_in[1];
  const float* ebank   = (const float*)d_in[2];
  const float* cbank   = (const float*)d_in[3];
  const float* gsel    = (const float*)d_in[4];
  const float* gw      = (const float*)d_in[5];
  const float* gb      = (const float*)d_in[6];
  const float* e_ln1_g = (const float*)d_in[7];
  const float* e_ln1_b = (const float*)d_in[8];
  const float* e_w1    = (const float*)d_in[9];
  const float* e_b1    = (const float*)d_in[10];
  const float* e_w2    = (const float*)d_in[11];
  const float* e_b2    = (const float*)d_in[12];
  const float* e_ln2_g = (const float*)d_in[13];
  const float* e_ln2_b = (const float*)d_in[14];
  const float* c_ln1_g = (const float*)d_in[15];
  const float* c_ln1_b = (const float*)d_in[16];
  const float* c_w1    = (const float*)d_in[17];
  const float* c_b1    = (const float*)d_in[18];
  const float* c_w2    = (const float*)d_in[19];
  const float* c_b2    = (const float*)d_in[20];
  const float* c_ln2_g = (const float*)d_in[21];
  const float* c_ln2_b = (const float*)d_in[22];

  float* out = (float*)d_out;
  float* ws = (float*)d_ws;

  constexpr size_t TXT = (size_t)8 * 2048 * 768;
  constexpr size_t IMG = (size_t)8 * 196 * 768;
  constexpr int NW = 768 * 768;

  // ws layout: A | Bb | wbf | gatev | stats | gpart   ~105.9 MB
  float* A  = ws;
  float* Bb = A + TXT;
  unsigned short* wbf = (unsigned short*)(Bb + TXT);
  unsigned short* ew1b = wbf;
  unsigned short* ew2b = wbf + NW;
  unsigned short* cw1b = wbf + 2 * NW;
  unsigned short* cw2b = wbf + 3 * NW;
  float* gatev = (float*)(wbf + 4 * (size_t)NW);
  float2* stats = (float2*)(gatev + 8 * 768);
  float* gpart = (float*)(stats + 8 * 2048);   // 8*4*768 floats

  float2* FcT = (float2*)out;  // parked in d_out (dead before final LN)

  float* ximg = A;
  unsigned short* xh_i = (unsigned short*)(A + IMG);
  unsigned short* h_i  = (unsigned short*)(A + IMG + IMG / 2);
  float* y_i = A + 2 * IMG;

  unsigned short* xhat = (unsigned short*)A;
  unsigned short* h_t  = (unsigned short*)(A + TXT / 2);
  float* y_t = Bb;

  // ---- one-time prep ----
  k_fc_make<<<(NBINS_ * D_ + 255) / 256, 256, 0, stream>>>((const float2*)ebank, FcT);
  k_wconv4<<<dim3((NW + 255) / 256, 4), 256, 0, stream>>>(e_w1, e_w2, c_w1, c_w2, wbf);

  // ---- image path (produces gate) ----
  k_img_rfft_filter<<<dim3(99, 8), 256, 0, stream>>>(image, (const float2*)cbank,
                                                     (float2*)Bb);
  k_gate_pool<<<dim3(8, 4), 256, 0, stream>>>((const float2*)Bb, (const float2*)gsel, gpart);
  k_gate_mm2<<<48, 256, 0, stream>>>(gpart, gw, gb, gatev);
  k_img_irfft_add<<<dim3(196, 8), 256, 0, stream>>>((const float2*)Bb, image, ximg);

  k_layernorm<1><<<1568, 256, 0, stream>>>(ximg, c_ln1_g, c_ln1_b, xh_i);
  k_gemm_mfma<0><<<dim3(6, 13), 256, 0, stream>>>(xh_i, cw1b, c_b1, nullptr, h_i, 1568);
  k_gemm_mfma<1><<<dim3(6, 13), 256, 0, stream>>>(h_i, cw2b, c_b2, xh_i, y_i, 1568);
  k_layernorm<0><<<1568, 256, 0, stream>>>(y_i, c_ln2_g, c_ln2_b, out + TXT);

  // ---- ecg path ----
  k_transpose_g<<<dim3(24, 64, 8), 256, 0, stream>>>(ecg, A, 2048, 768);
  k_ecg_fft<<<8 * 768, 256, 0, stream>>>(A, FcT, gatev, Bb);
  k_colstats<<<dim3(32, 8), 256, 0, stream>>>(Bb, stats);
  k_transpose_ln<<<dim3(64, 24, 8), 256, 0, stream>>>(Bb, stats, e_ln1_g, e_ln1_b, xhat);

  // ---- text FFN (bf16 MFMA) ----
  k_gemm_mfma<0><<<dim3(6, 128), 256, 0, stream>>>(xhat, ew1b, e_b1, nullptr, h_t, 16384);
  k_gemm_mfma<1><<<dim3(6, 128), 256, 0, stream>>>(h_t, ew2b, e_b2, xhat, y_t, 16384);
  k_layernorm<0><<<16384, 256, 0, stream>>>(y_t, e_ln2_g, e_ln2_b, out);
}

// Round 6
// 581.463 us; speedup vs baseline: 5.4566x; 1.0224x over previous
//
#include <hip/hip_runtime.h>
#include <math.h>

namespace {

constexpr int B_ = 8;
constexpr int S_ = 2048;
constexpr int D_ = 768;
constexpr int N_ = 196;     // image spatial
constexpr int NF_ = 99;     // image freq bins
constexpr int NFREQ_ = 257;
constexpr int NSEG_ = 9;
constexpr int NBINS_ = NFREQ_ * NSEG_;  // 2313
constexpr float TWOPI_ = 6.28318530717958647692f;

using bf16x8 = __attribute__((ext_vector_type(8))) short;
using f32x4  = __attribute__((ext_vector_type(4))) float;

__device__ __forceinline__ int rev9(int x) { return (int)(__brev((unsigned)x) >> 23); }
__device__ __forceinline__ int padz(int i) { return i + (i >> 2); }  // pad every 4 float2

__device__ __forceinline__ unsigned short f2bf(float x) {
  unsigned u = __float_as_uint(x);
  u = (u + 0x7FFFu + ((u >> 16) & 1u)) >> 16;
  return (unsigned short)u;
}
__device__ __forceinline__ float bf2f(unsigned short h) {
  return __uint_as_float(((unsigned)h) << 16);
}

__device__ __forceinline__ void gload16(const void* g, void* l) {
  __builtin_amdgcn_global_load_lds((const __attribute__((address_space(1))) void*)g,
                                   (__attribute__((address_space(3))) void*)l, 16, 0, 0);
}

// ---------------- batched transpose (B,R,C) -> (B,C,R) ----------------
__global__ __launch_bounds__(256) void k_transpose_g(const float* __restrict__ src,
                                                     float* __restrict__ dst,
                                                     int R, int C) {
  __shared__ float tile[32][33];
  const int b = blockIdx.z;
  const int c0 = blockIdx.x * 32;
  const int r0 = blockIdx.y * 32;
  const int tx = threadIdx.x & 31, ty = threadIdx.x >> 5;
  for (int i = ty; i < 32; i += 8)
    tile[i][tx] = src[((size_t)b * R + r0 + i) * C + c0 + tx];
  __syncthreads();
  for (int i = ty; i < 32; i += 8)
    dst[((size_t)b * C + c0 + i) * R + r0 + tx] = tile[tx][i];
}

// ---- filter bank: FcT[d][f][k] = -(e0[k*9+f][d] + e1[k*9+f][d]) ----
__global__ __launch_bounds__(256) void k_fc_make(const float2* __restrict__ e2,
                                                 float2* __restrict__ FcT) {
  const int o = blockIdx.x * 256 + threadIdx.x;
  if (o >= NBINS_ * D_) return;
  const int d = o / NBINS_;
  const int r = o - d * NBINS_;
  const int f = r / NFREQ_;
  const int k = r - f * NFREQ_;
  const int s = k * 9 + f;
  const float2 a = e2[(size_t)s * D_ + d];
  const float2 b = e2[(size_t)(NBINS_ + s) * D_ + d];
  FcT[o] = make_float2(-(a.x + b.x), -(a.y + b.y));
}

// ---- twiddle table: twg[h-1+j] = (cos, sin)(pi*j/h), h = 1,2,...,256 ----
__global__ __launch_bounds__(256) void k_tw(float2* __restrict__ twg) {
  const int i = blockIdx.x * 256 + threadIdx.x;
  if (i >= 511) return;
  const int v = i + 1;
  const int h = 1 << (31 - __clz(v));
  const int j = v - h;
  float sn, cs;
  sincosf((float)j * ((TWOPI_ * 0.5f) / (float)h), &sn, &cs);
  twg[i] = make_float2(cs, sn);
}

// ---- 4 weight matrices fp32 -> bf16, one launch ----
__global__ __launch_bounds__(256) void k_wconv4(const float* __restrict__ w0,
                                                const float* __restrict__ w1,
                                                const float* __restrict__ w2,
                                                const float* __restrict__ w3,
                                                unsigned short* __restrict__ o) {
  constexpr int NW = D_ * D_;
  const int i = blockIdx.x * 256 + threadIdx.x;
  if (i >= NW) return;
  const int m = blockIdx.y;
  const float* src = (m == 0) ? w0 : (m == 1) ? w1 : (m == 2) ? w2 : w3;
  o[(size_t)m * NW + i] = f2bf(src[i]);
}

// ------------- image rfft (ortho) + filter -> imgF (complex) -------------
__global__ __launch_bounds__(256) void k_img_rfft_filter(
    const float* __restrict__ image, const float2* __restrict__ bank2,
    float2* __restrict__ imgF) {
  const int f = blockIdx.x;  // 0..98
  const int b = blockIdx.y;
  const int tid = threadIdx.x;
  __shared__ float ct[N_], st[N_];
  if (tid < N_) {
    const int r = (f * tid) % N_;
    float s, c;
    sincosf(TWOPI_ * (float)r / (float)N_, &s, &c);
    ct[tid] = c; st[tid] = s;
  }
  __syncthreads();
  for (int d = tid; d < D_; d += 256) {
    float re = 0.f, im = 0.f;
    const float* ip = image + (size_t)b * N_ * D_ + d;
    for (int t = 0; t < N_; ++t) {
      const float v = ip[(size_t)t * D_];
      re = fmaf(v, ct[t], re);
      im = fmaf(-v, st[t], im);
    }
    const float sc = 1.0f / (196.0f * 99.0f);
    const float pr = (re * re - im * im) * sc;
    const float pi2 = (2.f * re * im) * sc;
    const size_t fd = (size_t)f * D_ + d;
    const float2 c0 = bank2[fd];
    const float2 c1 = bank2[(size_t)NF_ * D_ + fd];
    const float fcr = -(c0.x + c1.x), fci = -(c0.y + c1.y);
    imgF[(size_t)(b * NF_ + f) * D_ + d] =
        make_float2(pr * fcr - pi2 * fci, pr * fci + pi2 * fcr);
  }
}

// ---- gate pooling, partials over freq chunks: part[b][p][d] ----
__global__ __launch_bounds__(256) void k_gate_pool(const float2* __restrict__ imgF,
                                                   const float2* __restrict__ gsel2,
                                                   float* __restrict__ part) {
  const int b = blockIdx.x;
  const int p = blockIdx.y;           // 0..3
  const int f0 = p * 25;
  const int f1 = (p == 3) ? NF_ : f0 + 25;
  for (int d = threadIdx.x; d < D_; d += 256) {
    float acc = 0.f;
    for (int f = f0; f < f1; ++f) {
      const float2 z = imgF[(size_t)(b * NF_ + f) * D_ + d];
      const float2 w = gsel2[(size_t)f * D_ + d];
      acc += z.x * w.x - z.y * w.y;
    }
    part[((size_t)b * 4 + p) * D_ + d] = acc;
  }
}

// ---- gate matvec, all batches per block: gate[b][d0..d0+16) ----
__global__ __launch_bounds__(256) void k_gate_mm2(const float* __restrict__ part,
                                                  const float* __restrict__ W,
                                                  const float* __restrict__ bias,
                                                  float* __restrict__ gate) {
  __shared__ float row[8][D_];
  __shared__ float red[16][16][8];
  const int tid = threadIdx.x;
  const int d0 = blockIdx.x * 16;
  for (int i = tid; i < 8 * D_; i += 256) {
    const int b = i / D_, e = i - b * D_;
    const float s = part[((size_t)b * 4 + 0) * D_ + e] + part[((size_t)b * 4 + 1) * D_ + e] +
                    part[((size_t)b * 4 + 2) * D_ + e] + part[((size_t)b * 4 + 3) * D_ + e];
    row[b][e] = s * (1.0f / 99.0f);
  }
  __syncthreads();
  const int dl = tid >> 4;
  const int ec = tid & 15;
  const float* w = W + (size_t)(d0 + dl) * D_ + ec * 48;
  float acc[8] = {};
  for (int e = 0; e < 48; e += 4) {
    const float4 wv = *reinterpret_cast<const float4*>(w + e);
    const int eg = ec * 48 + e;
#pragma unroll
    for (int b = 0; b < 8; ++b) {
      acc[b] = fmaf(row[b][eg], wv.x, acc[b]);
      acc[b] = fmaf(row[b][eg + 1], wv.y, acc[b]);
      acc[b] = fmaf(row[b][eg + 2], wv.z, acc[b]);
      acc[b] = fmaf(row[b][eg + 3], wv.w, acc[b]);
    }
  }
#pragma unroll
  for (int b = 0; b < 8; ++b) red[dl][ec][b] = acc[b];
  __syncthreads();
  if (tid < 128) {
    const int dl2 = tid >> 3, b = tid & 7;
    float s = bias[d0 + dl2];
    for (int c = 0; c < 16; ++c) s += red[dl2][c][b];
    gate[b * D_ + d0 + dl2] = s;
  }
}

// -------- image irfft (ortho) + residual --------
__global__ __launch_bounds__(256) void k_img_irfft_add(const float2* __restrict__ imgF,
                                                       const float* __restrict__ image,
                                                       float* __restrict__ ximg) {
  const int t = blockIdx.x;
  const int b = blockIdx.y;
  const int tid = threadIdx.x;
  __shared__ float cf[NF_], sf[NF_];
  if (tid < NF_) {
    const int r = (t * tid) % N_;
    float s, c;
    sincosf(TWOPI_ * (float)r / (float)N_, &s, &c);
    cf[tid] = c; sf[tid] = s;
  }
  __syncthreads();
  const float sgn_ny = (t & 1) ? -1.f : 1.f;
  for (int d = tid; d < D_; d += 256) {
    const float2* zp = imgF + (size_t)b * NF_ * D_ + d;
    float acc = zp[0].x;
    for (int f = 1; f < NF_ - 1; ++f) {
      const float2 z = zp[(size_t)f * D_];
      acc += 2.f * (z.x * cf[f] - z.y * sf[f]);
    }
    acc += zp[(size_t)(NF_ - 1) * D_].x * sgn_ny;
    const size_t idx = (size_t)(b * N_ + t) * D_ + d;
    ximg[idx] = acc * (1.0f / 14.0f) + image[idx];
  }
}

// ================= ecg fused FFT pipeline (quad double-stages) =================
template <int SS, int DIR>
__device__ __forceinline__ void dblpass(float2* z, const float2* tw, int q) {
  asm volatile("s_waitcnt lgkmcnt(0)" ::: "memory");
  const int h = 1 << SS;
  const int j = q & (h - 1);
  const int base = ((q >> SS) << (SS + 2)) | j;
  const int e0 = padz(base), e1 = padz(base + h);
  const int e2 = padz(base + 2 * h), e3 = padz(base + 3 * h);
  const float2 x0 = z[e0], x1 = z[e1], x2 = z[e2], x3 = z[e3];
  const float2 tw1 = tw[h - 1 + j];
  const float2 tw2 = tw[2 * h - 1 + j];
  const float sg = (DIR < 0) ? -1.f : 1.f;
  const float w1c = tw1.x, w1s = sg * tw1.y;
  const float w2c = tw2.x, w2s = sg * tw2.y;
  const float t1r = x1.x * w1c - x1.y * w1s, t1i = x1.x * w1s + x1.y * w1c;
  const float t3r = x3.x * w1c - x3.y * w1s, t3i = x3.x * w1s + x3.y * w1c;
  const float a0r = x0.x + t1r, a0i = x0.y + t1i;
  const float a1r = x0.x - t1r, a1i = x0.y - t1i;
  const float a2r = x2.x + t3r, a2i = x2.y + t3i;
  const float a3r = x2.x - t3r, a3i = x2.y - t3i;
  const float u2r = a2r * w2c - a2i * w2s, u2i = a2r * w2s + a2i * w2c;
  const float v3r = a3r * w2c - a3i * w2s, v3i = a3r * w2s + a3i * w2c;
  const float u3r = -sg * v3i, u3i = sg * v3r;
  z[e0] = make_float2(a0r + u2r, a0i + u2i);
  z[e2] = make_float2(a0r - u2r, a0i - u2i);
  z[e1] = make_float2(a1r + u3r, a1i + u3i);
  z[e3] = make_float2(a1r - u3r, a1i - u3i);
}

template <int DIR>
__device__ __forceinline__ void stage8(float2* z, const float2* tw, int t) {
  const float2 w = tw[255 + t];
  const float wc = w.x, ws = (DIR < 0) ? -w.y : w.y;
  const int a0 = padz(t), a1 = padz(t + 256);
  const float2 x = z[a0], y = z[a1];
  const float tr = y.x * wc - y.y * ws, ti = y.x * ws + y.y * wc;
  z[a0] = make_float2(x.x + tr, x.y + ti);
  z[a1] = make_float2(x.x - tr, x.y - ti);
}

template <int FA, int FB>
__device__ __forceinline__ void filt_pack(const float2* z, int k, float g,
                                          float2 cA, float2 cB,
                                          float2& Ck, float2& Cm) {
  const int q = (512 - k) & 511;
  const float2 Zk = z[padz(k)], Zq = z[padz(q)];
  const float sc = 0.5f / 256.f;
  const float ar = (Zk.x + Zq.x) * sc, ai = (Zk.y - Zq.y) * sc;
  float yar, yai, ybr = 0.f, ybi = 0.f;
  {
    const float pr = (ar * ar - ai * ai) * (1.f / 2313.f);
    const float pi = (2.f * ar * ai) * (1.f / 2313.f);
    yar = (pr * cA.x - pi * cA.y) * g;
    yai = (pr * cA.y + pi * cA.x) * g;
  }
  if (FB >= 0) {
    const float br = (Zk.y + Zq.y) * sc, bi = (Zq.x - Zk.x) * sc;
    const float pr = (br * br - bi * bi) * (1.f / 2313.f);
    const float pi = (2.f * br * bi) * (1.f / 2313.f);
    ybr = (pr * cB.x - pi * cB.y) * g;
    ybi = (pr * cB.y + pi * cB.x) * g;
  }
  if (k == 0 || k == 256) {
    Ck = make_float2(yar, ybr);
    Cm = Ck;
  } else {
    Ck = make_float2(yar - ybi, yai + ybr);
    Cm = make_float2(yar + ybi, ybr - yai);
  }
}

// one super-pass; sig held in registers s[8] (s[k] = signal[t = k*256 + tid])
template <int FA0, int FB0, int FA1, int FB1, bool DUAL>
__device__ __forceinline__ void ecg_super(int tid, float g, const float2* __restrict__ fc,
                                          const float (&s)[8], const float2* tw,
                                          float2* zA, float2* zB, float* accr) {
  const float c0 = tw[255 + tid].x;
  const float wlo = 0.5f - 0.5f * c0;
  const float whi = 0.5f + 0.5f * c0;
  const float2 cA0 = fc[FA0 * 257 + tid];
  float2 cB0 = make_float2(0.f, 0.f), cA1 = cB0, cB1 = cB0;
  if (FB0 >= 0) cB0 = fc[FB0 * 257 + tid];
  if (DUAL) { cA1 = fc[FA1 * 257 + tid]; cB1 = fc[FB1 * 257 + tid]; }
  float2 nA0 = make_float2(0.f, 0.f), nB0 = nA0, nA1 = nA0, nB1 = nA0;
  if (tid == 0) {
    nA0 = fc[FA0 * 257 + 256];
    if (FB0 >= 0) nB0 = fc[FB0 * 257 + 256];
    if (DUAL) { nA1 = fc[FA1 * 257 + 256]; nB1 = fc[FB1 * 257 + 256]; }
  }
  __syncthreads();
  {
    constexpr int iAlo = (FA0 > 0) ? FA0 - 1 : 0;
    constexpr int iAhi = (FA0 < 8) ? FA0 : 0;
    constexpr int iBlo = (FB0 > 0) ? FB0 - 1 : 0;
    constexpr int iBhi = (FB0 >= 0 && FB0 < 8) ? FB0 : 0;
    const int rlo = padz(rev9(tid)), rhi = padz(rev9(tid + 256));
    const float aLo = (FA0 == 0) ? 0.f : s[iAlo] * wlo;
    const float aHi = (FA0 == 8) ? 0.f : s[iAhi] * whi;
    const float bLo = (FB0 <= 0) ? 0.f : s[iBlo] * wlo;
    const float bHi = (FB0 < 0 || FB0 == 8) ? 0.f : s[iBhi] * whi;
    zA[rlo] = make_float2(aLo, bLo);
    zA[rhi] = make_float2(aHi, bHi);
    if (DUAL) {
      constexpr int jAlo = (FA1 > 0) ? FA1 - 1 : 0;
      constexpr int jAhi = (FA1 < 8) ? FA1 : 0;
      constexpr int jBlo = (FB1 > 0) ? FB1 - 1 : 0;
      constexpr int jBhi = (FB1 < 8) ? FB1 : 0;
      const float eLo = (FA1 == 0) ? 0.f : s[jAlo] * wlo;
      const float eHi = (FA1 == 8) ? 0.f : s[jAhi] * whi;
      const float fLo = (FB1 == 0) ? 0.f : s[jBlo] * wlo;
      const float fHi = (FB1 == 8) ? 0.f : s[jBhi] * whi;
      zB[rlo] = make_float2(eLo, fLo);
      zB[rhi] = make_float2(eHi, fHi);
    }
  }
  __syncthreads();
  if (DUAL || tid < 128) {
    float2* zz = (tid < 128) ? zA : zB;
    const int q = tid & 127;
    dblpass<0, -1>(zz, tw, q);
    dblpass<2, -1>(zz, tw, q);
    dblpass<4, -1>(zz, tw, q);
    dblpass<6, -1>(zz, tw, q);
  }
  __syncthreads();
  stage8<-1>(zA, tw, tid);
  if (DUAL) stage8<-1>(zB, tw, tid);
  __syncthreads();
  float2 CAk, CAm, CBk, CBm;
  filt_pack<FA0, FB0>(zA, tid, g, cA0, cB0, CAk, CAm);
  float2 CAn, CBn, dum;
  if (tid == 0) filt_pack<FA0, FB0>(zA, 256, g, nA0, nB0, CAn, dum);
  if (DUAL) {
    filt_pack<FA1, FB1>(zB, tid, g, cA1, cB1, CBk, CBm);
    if (tid == 0) filt_pack<FA1, FB1>(zB, 256, g, nA1, nB1, CBn, dum);
  }
  __syncthreads();
  {
    const int rk = padz(rev9(tid));
    zA[rk] = CAk;
    if (DUAL) zB[rk] = CBk;
    if (tid == 0) {
      zA[padz(1)] = CAn;
      if (DUAL) zB[padz(1)] = CBn;
    } else {
      const int rm = padz(rev9(512 - tid));
      zA[rm] = CAm;
      if (DUAL) zB[rm] = CBm;
    }
  }
  __syncthreads();
  if (DUAL || tid < 128) {
    float2* zz = (tid < 128) ? zA : zB;
    const int q = tid & 127;
    dblpass<0, 1>(zz, tw, q);
    dblpass<2, 1>(zz, tw, q);
    dblpass<4, 1>(zz, tw, q);
    dblpass<6, 1>(zz, tw, q);
  }
  __syncthreads();
  stage8<1>(zA, tw, tid);
  if (DUAL) stage8<1>(zB, tw, tid);
  {
    const float2 vLo = zA[padz(tid)], vHi = zA[padz(tid + 256)];
    accr[FA0] += 0.5f * wlo * vLo.x;
    accr[FA0 + 1] += 0.5f * whi * vHi.x;
    if (FB0 >= 0) {
      accr[FB0] += 0.5f * wlo * vLo.y;
      accr[FB0 + 1] += 0.5f * whi * vHi.y;
    }
    if (DUAL) {
      const float2 uLo = zB[padz(tid)], uHi = zB[padz(tid + 256)];
      accr[FA1] += 0.5f * wlo * uLo.x;
      accr[FA1 + 1] += 0.5f * whi * uHi.x;
      accr[FB1] += 0.5f * wlo * uLo.y;
      accr[FB1 + 1] += 0.5f * whi * uHi.y;
    }
  }
}

__global__ __launch_bounds__(256) void k_ecg_fft(
    const float* __restrict__ ecgT, const float2* __restrict__ FcT,
    const float* __restrict__ gate, const float2* __restrict__ twg,
    float* __restrict__ xtT) {
  const int bd = blockIdx.x;
  const int d = bd % D_;
  const int tid = threadIdx.x;

  __shared__ float2 tw[511];           // 4 KB
  __shared__ float2 zA[640], zB[640];  // 10.25 KB

  // signal in registers: s[k] = sig[k*256 + tid]
  float s[8];
  const float* src = ecgT + (size_t)bd * S_;
#pragma unroll
  for (int k = 0; k < 8; ++k) s[k] = src[k * 256 + tid];
  for (int i = tid; i < 511; i += 256) tw[i] = twg[i];
  __syncthreads();

  const float g = gate[bd];
  const float2* fc = FcT + (size_t)d * NBINS_;
  float accr[10];
#pragma unroll
  for (int i = 0; i < 10; ++i) accr[i] = 0.f;

  ecg_super<0, 8, 1, 2, true>(tid, g, fc, s, tw, zA, zB, accr);
  ecg_super<3, 4, 5, 6, true>(tid, g, fc, s, tw, zA, zB, accr);
  ecg_super<7, -1, 0, 0, false>(tid, g, fc, s, tw, zA, zB, accr);

  const float c0 = tw[255 + tid].x;
  const float nrm = 0.5f + 0.5f * c0 * c0;
  float* dst = xtT + (size_t)bd * S_;
#pragma unroll
  for (int i2 = 0; i2 < 8; ++i2)
    dst[i2 * 256 + tid] = accr[i2 + 1] / nrm + s[i2];
}

// ---- per-(b,t) LN stats over d, reading xtT[b][d][t] coalesced ----
__global__ __launch_bounds__(256) void k_colstats(const float* __restrict__ xtT,
                                                  float2* __restrict__ stats) {
  const int b = blockIdx.y;
  const int t0 = blockIdx.x * 64;
  const int tx = threadIdx.x & 63;
  const int ty = threadIdx.x >> 6;
  float s = 0.f, q = 0.f;
  const float* base = xtT + (size_t)b * D_ * S_ + t0 + tx;
  for (int dd = ty; dd < D_; dd += 4) {
    const float v = base[(size_t)dd * S_];
    s += v;
    q = fmaf(v, v, q);
  }
  __shared__ float sh_s[4][64], sh_q[4][64];
  sh_s[ty][tx] = s; sh_q[ty][tx] = q;
  __syncthreads();
  if (ty == 0) {
    s = sh_s[0][tx] + sh_s[1][tx] + sh_s[2][tx] + sh_s[3][tx];
    q = sh_q[0][tx] + sh_q[1][tx] + sh_q[2][tx] + sh_q[3][tx];
    stats[(size_t)b * S_ + t0 + tx] = make_float2(s, q);
  }
}

// ---- transpose + LN apply + bf16 ----
__global__ __launch_bounds__(256) void k_transpose_ln(
    const float* __restrict__ xtT, const float2* __restrict__ stats,
    const float* __restrict__ g, const float* __restrict__ bia,
    unsigned short* __restrict__ xhat) {
  __shared__ float tile[32][33];
  const int b = blockIdx.z;
  const int t0 = blockIdx.x * 32;
  const int d0 = blockIdx.y * 32;
  const int tx = threadIdx.x & 31, ty = threadIdx.x >> 5;
  for (int i = ty; i < 32; i += 8)
    tile[i][tx] = xtT[((size_t)b * D_ + d0 + i) * S_ + t0 + tx];
  __syncthreads();
  const float gv = g[d0 + tx], bv = bia[d0 + tx];
  for (int i = ty; i < 32; i += 8) {
    const float2 st = stats[(size_t)b * S_ + t0 + i];
    const float mean = st.x * (1.0f / 768.0f);
    const float var = st.y * (1.0f / 768.0f) - mean * mean;
    const float inv = rsqrtf(var + 1e-5f);
    xhat[((size_t)b * S_ + t0 + i) * D_ + d0 + tx] =
        f2bf((tile[tx][i] - mean) * inv * gv + bv);
  }
}

// ---------------- LayerNorm over D=768; OUT: 0=f32, 1=bf16 ----------------
template <int BF16OUT>
__global__ __launch_bounds__(256) void k_layernorm(const float* __restrict__ x,
                                                   const float* __restrict__ g,
                                                   const float* __restrict__ b,
                                                   void* __restrict__ outv) {
  const int row = blockIdx.x;
  const int tid = threadIdx.x;
  const float* xr = x + (size_t)row * D_;
  const float v0 = xr[tid], v1 = xr[tid + 256], v2 = xr[tid + 512];
  float s = v0 + v1 + v2;
  float q = v0 * v0 + v1 * v1 + v2 * v2;
  __shared__ float red[8];
  for (int off = 32; off > 0; off >>= 1) {
    s += __shfl_down(s, off);
    q += __shfl_down(q, off);
  }
  if ((tid & 63) == 0) { red[tid >> 6] = s; red[4 + (tid >> 6)] = q; }
  __syncthreads();
  s = red[0] + red[1] + red[2] + red[3];
  q = red[4] + red[5] + red[6] + red[7];
  const float mean = s * (1.0f / 768.0f);
  const float var = q * (1.0f / 768.0f) - mean * mean;
  const float inv = rsqrtf(var + 1e-5f);
  const float o0 = (v0 - mean) * inv * g[tid] + b[tid];
  const float o1 = (v1 - mean) * inv * g[tid + 256] + b[tid + 256];
  const float o2 = (v2 - mean) * inv * g[tid + 512] + b[tid + 512];
  if (BF16OUT) {
    unsigned short* orow = (unsigned short*)outv + (size_t)row * D_;
    orow[tid] = f2bf(o0); orow[tid + 256] = f2bf(o1); orow[tid + 512] = f2bf(o2);
  } else {
    float* orow = (float*)outv + (size_t)row * D_;
    orow[tid] = o0; orow[tid + 256] = o1; orow[tid + 512] = o2;
  }
}

// ---------- MFMA GEMM: out = act(A @ W^T + bias [+resid]) ----------
template <int MODE>  // 0: exact GELU -> bf16 ; 1: +resid(bf16) -> f32
__global__ __launch_bounds__(256) void k_gemm_mfma(
    const unsigned short* __restrict__ Abf, const unsigned short* __restrict__ Wbf,
    const float* __restrict__ bias, const unsigned short* __restrict__ resid,
    void* __restrict__ outv, int M) {
  __shared__ unsigned short Asm[128 * 64];
  __shared__ unsigned short Bsm[128 * 64];
  const int tid = threadIdx.x;
  const int lane = tid & 63, wid = tid >> 6;
  const int wr = wid >> 1, wc = wid & 1;
  const int n0 = blockIdx.x * 128, m0 = blockIdx.y * 128;
  f32x4 acc[4][4] = {};
  for (int kt = 0; kt < 12; ++kt) {
    const int k0 = kt * 64;
#pragma unroll
    for (int i = 0; i < 4; ++i) {
      const int c = tid + 256 * i;
      const int row = c >> 3, sl = c & 7;
      const int gsl = sl ^ (row & 7);
      gload16(Abf + (size_t)(m0 + row) * 768 + k0 + gsl * 8, &Asm[c * 8]);
      gload16(Wbf + (size_t)(n0 + row) * 768 + k0 + gsl * 8, &Bsm[c * 8]);
    }
    __syncthreads();
#pragma unroll
    for (int ks = 0; ks < 2; ++ks) {
      bf16x8 af[4], bfv[4];
#pragma unroll
      for (int mi = 0; mi < 4; ++mi) {
        const int row = wr * 64 + mi * 16 + (lane & 15);
        const int sl = (ks * 4 + (lane >> 4)) ^ (row & 7);
        af[mi] = *(const bf16x8*)((const char*)Asm + row * 128 + sl * 16);
      }
#pragma unroll
      for (int ni = 0; ni < 4; ++ni) {
        const int row = wc * 64 + ni * 16 + (lane & 15);
        const int sl = (ks * 4 + (lane >> 4)) ^ (row & 7);
        bfv[ni] = *(const bf16x8*)((const char*)Bsm + row * 128 + sl * 16);
      }
#pragma unroll
      for (int mi = 0; mi < 4; ++mi)
#pragma unroll
        for (int ni = 0; ni < 4; ++ni)
          acc[mi][ni] = __builtin_amdgcn_mfma_f32_16x16x32_bf16(af[mi], bfv[ni],
                                                                acc[mi][ni], 0, 0, 0);
    }
    __syncthreads();
  }
#pragma unroll
  for (int mi = 0; mi < 4; ++mi) {
#pragma unroll
    for (int ni = 0; ni < 4; ++ni) {
      const int col = n0 + wc * 64 + ni * 16 + (lane & 15);
#pragma unroll
      for (int e = 0; e < 4; ++e) {
        const int row = m0 + wr * 64 + mi * 16 + (lane >> 4) * 4 + e;
        if (row >= M) continue;
        float v = acc[mi][ni][e] + bias[col];
        if (MODE == 0) {
          v = 0.5f * v * (1.0f + erff(v * 0.70710678118654752440f));
          ((unsigned short*)outv)[(size_t)row * 768 + col] = f2bf(v);
        } else {
          v += bf2f(resid[(size_t)row * 768 + col]);
          ((float*)outv)[(size_t)row * 768 + col] = v;
        }
      }
    }
  }
}

}  // namespace

extern "C" void kernel_launch(void* const* d_in, const int* in_sizes, int n_in,
                              void* d_out, int out_size, void* d_ws, size_t ws_size,
                              hipStream_t stream) {
  (void)in_sizes; (void)n_in; (void)out_size; (void)ws_size;
  const float* ecg     = (const float*)d_in[0];
  const float* image   = (const float*)d_in[1];
  const float* ebank   = (const float*)d_in[2];
  const float* cbank   = (const float*)d_in[3];
  const float* gsel    = (const float*)d_in[4];
  const float* gw      = (const float*)d_in[5];
  const float* gb      = (const float*)d_in[6];
  const float* e_ln1_g = (const float*)d_in[7];
  const float* e_ln1_b = (const float*)d_in[8];
  const float* e_w1    = (const float*)d_in[9];
  const float* e_b1    = (const float*)d_in[10];
  const float* e_w2    = (const float*)d_in[11];
  const float* e_b2    = (const float*)d_in[12];
  const float* e_ln2_g = (const float*)d_in[13];
  const float* e_ln2_b = (const float*)d_in[14];
  const float* c_ln1_g = (const float*)d_in[15];
  const float* c_ln1_b = (const float*)d_in[16];
  const float* c_w1    = (const float*)d_in[17];
  const float* c_b1    = (const float*)d_in[18];
  const float* c_w2    = (const float*)d_in[19];
  const float* c_b2    = (const float*)d_in[20];
  const float* c_ln2_g = (const float*)d_in[21];
  const float* c_ln2_b = (const float*)d_in[22];

  float* out = (float*)d_out;
  float* ws = (float*)d_ws;

  constexpr size_t TXT = (size_t)8 * 2048 * 768;
  constexpr size_t IMG = (size_t)8 * 196 * 768;
  constexpr int NW = 768 * 768;

  // ws layout: A | Bb | wbf | gatev | stats | gpart | twg   ~105.9 MB
  float* A  = ws;
  float* Bb = A + TXT;
  unsigned short* wbf = (unsigned short*)(Bb + TXT);
  unsigned short* ew1b = wbf;
  unsigned short* ew2b = wbf + NW;
  unsigned short* cw1b = wbf + 2 * NW;
  unsigned short* cw2b = wbf + 3 * NW;
  float* gatev = (float*)(wbf + 4 * (size_t)NW);
  float2* stats = (float2*)(gatev + 8 * 768);
  float* gpart = (float*)(stats + 8 * 2048);   // 8*4*768 floats
  float2* twg = (float2*)(gpart + 8 * 4 * 768);

  float2* FcT = (float2*)out;  // parked in d_out (dead before final LN)

  float* ximg = A;
  unsigned short* xh_i = (unsigned short*)(A + IMG);
  unsigned short* h_i  = (unsigned short*)(A + IMG + IMG / 2);
  float* y_i = A + 2 * IMG;

  unsigned short* xhat = (unsigned short*)A;
  unsigned short* h_t  = (unsigned short*)(A + TXT / 2);
  float* y_t = Bb;

  // ---- one-time prep ----
  k_fc_make<<<(NBINS_ * D_ + 255) / 256, 256, 0, stream>>>((const float2*)ebank, FcT);
  k_tw<<<2, 256, 0, stream>>>(twg);
  k_wconv4<<<dim3((NW + 255) / 256, 4), 256, 0, stream>>>(e_w1, e_w2, c_w1, c_w2, wbf);

  // ---- image path (produces gate) ----
  k_img_rfft_filter<<<dim3(99, 8), 256, 0, stream>>>(image, (const float2*)cbank,
                                                     (float2*)Bb);
  k_gate_pool<<<dim3(8, 4), 256, 0, stream>>>((const float2*)Bb, (const float2*)gsel, gpart);
  k_gate_mm2<<<48, 256, 0, stream>>>(gpart, gw, gb, gatev);
  k_img_irfft_add<<<dim3(196, 8), 256, 0, stream>>>((const float2*)Bb, image, ximg);

  k_layernorm<1><<<1568, 256, 0, stream>>>(ximg, c_ln1_g, c_ln1_b, xh_i);
  k_gemm_mfma<0><<<dim3(6, 13), 256, 0, stream>>>(xh_i, cw1b, c_b1, nullptr, h_i, 1568);
  k_gemm_mfma<1><<<dim3(6, 13), 256, 0, stream>>>(h_i, cw2b, c_b2, xh_i, y_i, 1568);
  k_layernorm<0><<<1568, 256, 0, stream>>>(y_i, c_ln2_g, c_ln2_b, out + TXT);

  // ---- ecg path ----
  k_transpose_g<<<dim3(24, 64, 8), 256, 0, stream>>>(ecg, A, 2048, 768);
  k_ecg_fft<<<8 * 768, 256, 0, stream>>>(A, FcT, gatev, twg, Bb);
  k_colstats<<<dim3(32, 8), 256, 0, stream>>>(Bb, stats);
  k_transpose_ln<<<dim3(64, 24, 8), 256, 0, stream>>>(Bb, stats, e_ln1_g, e_ln1_b, xhat);

  // ---- text FFN (bf16 MFMA) ----
  k_gemm_mfma<0><<<dim3(6, 128), 256, 0, stream>>>(xhat, ew1b, e_b1, nullptr, h_t, 16384);
  k_gemm_mfma<1><<<dim3(6, 128), 256, 0, stream>>>(h_t, ew2b, e_b2, xhat, y_t, 16384);
  k_layernorm<0><<<16384, 256, 0, stream>>>(y_t, e_ln2_g, e_ln2_b, out);
}

// Round 7
// 569.660 us; speedup vs baseline: 5.5697x; 1.0207x over previous
//
#include <hip/hip_runtime.h>
#include <math.h>

namespace {

constexpr int B_ = 8;
constexpr int S_ = 2048;
constexpr int D_ = 768;
constexpr int N_ = 196;     // image spatial
constexpr int NF_ = 99;     // image freq bins
constexpr int NFREQ_ = 257;
constexpr int NSEG_ = 9;
constexpr int NBINS_ = NFREQ_ * NSEG_;  // 2313
constexpr int NW_ = D_ * D_;            // 589824
constexpr float TWOPI_ = 6.28318530717958647692f;

using bf16x8 = __attribute__((ext_vector_type(8))) short;
using f32x4  = __attribute__((ext_vector_type(4))) float;

__device__ __forceinline__ int rev9(int x) { return (int)(__brev((unsigned)x) >> 23); }
__device__ __forceinline__ int padz(int i) { return i + (i >> 2); }  // float2 elements

__device__ __forceinline__ unsigned short f2bf(float x) {
  unsigned u = __float_as_uint(x);
  u = (u + 0x7FFFu + ((u >> 16) & 1u)) >> 16;
  return (unsigned short)u;
}
__device__ __forceinline__ float bf2f(unsigned short h) {
  return __uint_as_float(((unsigned)h) << 16);
}

__device__ __forceinline__ void gload16(const void* g, void* l) {
  __builtin_amdgcn_global_load_lds((const __attribute__((address_space(1))) void*)g,
                                   (__attribute__((address_space(3))) void*)l, 16, 0, 0);
}

// ---------------- batched transpose (B,R,C) -> (B,C,R) ----------------
__global__ __launch_bounds__(256) void k_transpose_g(const float* __restrict__ src,
                                                     float* __restrict__ dst,
                                                     int R, int C) {
  __shared__ float tile[32][33];
  const int b = blockIdx.z;
  const int c0 = blockIdx.x * 32;
  const int r0 = blockIdx.y * 32;
  const int tx = threadIdx.x & 31, ty = threadIdx.x >> 5;
  for (int i = ty; i < 32; i += 8)
    tile[i][tx] = src[((size_t)b * R + r0 + i) * C + c0 + tx];
  __syncthreads();
  for (int i = ty; i < 32; i += 8)
    dst[((size_t)b * C + c0 + i) * R + r0 + tx] = tile[tx][i];
}

// ---- fused prep: weight bf16 conv (4 mats) + filter bank + twiddles ----
constexpr int PREP_W = (NW_ + 255) / 256;          // 2304 blocks per matrix
constexpr int PREP_WALL = 4 * PREP_W;              // 9216
constexpr int PREP_FC = (NBINS_ * D_ + 255) / 256; // 6939
__global__ __launch_bounds__(256) void k_prep(
    const float* __restrict__ w0, const float* __restrict__ w1,
    const float* __restrict__ w2, const float* __restrict__ w3,
    unsigned short* __restrict__ wbf, const float2* __restrict__ e2,
    float2* __restrict__ FcT, float2* __restrict__ twg) {
  const int bid = blockIdx.x;
  if (bid < PREP_WALL) {
    const int m = bid / PREP_W;
    const int i = (bid - m * PREP_W) * 256 + threadIdx.x;
    if (i >= NW_) return;
    const float* src = (m == 0) ? w0 : (m == 1) ? w1 : (m == 2) ? w2 : w3;
    wbf[(size_t)m * NW_ + i] = f2bf(src[i]);
  } else if (bid < PREP_WALL + PREP_FC) {
    const int o = (bid - PREP_WALL) * 256 + threadIdx.x;
    if (o >= NBINS_ * D_) return;
    const int d = o / NBINS_;
    const int r = o - d * NBINS_;
    const int f = r / NFREQ_;
    const int k = r - f * NFREQ_;
    const int s = k * 9 + f;
    const float2 a = e2[(size_t)s * D_ + d];
    const float2 b = e2[(size_t)(NBINS_ + s) * D_ + d];
    FcT[o] = make_float2(-(a.x + b.x), -(a.y + b.y));
  } else {
    const int i = (bid - PREP_WALL - PREP_FC) * 256 + threadIdx.x;
    if (i >= 511) return;
    const int v = i + 1;
    const int h = 1 << (31 - __clz(v));
    const int j = v - h;
    float sn, cs;
    sincosf((float)j * ((TWOPI_ * 0.5f) / (float)h), &sn, &cs);
    twg[i] = make_float2(cs, sn);
  }
}

// ------------- image rfft (ortho) + filter -> imgF (complex) -------------
__global__ __launch_bounds__(256) void k_img_rfft_filter(
    const float* __restrict__ image, const float2* __restrict__ bank2,
    float2* __restrict__ imgF) {
  const int f = blockIdx.x;  // 0..98
  const int b = blockIdx.y;
  const int tid = threadIdx.x;
  __shared__ float ct[N_], st[N_];
  if (tid < N_) {
    const int r = (f * tid) % N_;
    float s, c;
    sincosf(TWOPI_ * (float)r / (float)N_, &s, &c);
    ct[tid] = c; st[tid] = s;
  }
  __syncthreads();
  for (int d = tid; d < D_; d += 256) {
    float re = 0.f, im = 0.f;
    const float* ip = image + (size_t)b * N_ * D_ + d;
    for (int t = 0; t < N_; ++t) {
      const float v = ip[(size_t)t * D_];
      re = fmaf(v, ct[t], re);
      im = fmaf(-v, st[t], im);
    }
    const float sc = 1.0f / (196.0f * 99.0f);
    const float pr = (re * re - im * im) * sc;
    const float pi2 = (2.f * re * im) * sc;
    const size_t fd = (size_t)f * D_ + d;
    const float2 c0 = bank2[fd];
    const float2 c1 = bank2[(size_t)NF_ * D_ + fd];
    const float fcr = -(c0.x + c1.x), fci = -(c0.y + c1.y);
    imgF[(size_t)(b * NF_ + f) * D_ + d] =
        make_float2(pr * fcr - pi2 * fci, pr * fci + pi2 * fcr);
  }
}

// ---- gate pooling, partials over freq chunks: part[b][p][d] ----
__global__ __launch_bounds__(256) void k_gate_pool(const float2* __restrict__ imgF,
                                                   const float2* __restrict__ gsel2,
                                                   float* __restrict__ part) {
  const int b = blockIdx.x;
  const int p = blockIdx.y;           // 0..3
  const int f0 = p * 25;
  const int f1 = (p == 3) ? NF_ : f0 + 25;
  for (int d = threadIdx.x; d < D_; d += 256) {
    float acc = 0.f;
    for (int f = f0; f < f1; ++f) {
      const float2 z = imgF[(size_t)(b * NF_ + f) * D_ + d];
      const float2 w = gsel2[(size_t)f * D_ + d];
      acc += z.x * w.x - z.y * w.y;
    }
    part[((size_t)b * 4 + p) * D_ + d] = acc;
  }
}

// ---- gate matvec, all batches per block: gate[b][d0..d0+16) ----
__global__ __launch_bounds__(256) void k_gate_mm2(const float* __restrict__ part,
                                                  const float* __restrict__ W,
                                                  const float* __restrict__ bias,
                                                  float* __restrict__ gate) {
  __shared__ float row[8][D_];
  __shared__ float red[16][16][8];
  const int tid = threadIdx.x;
  const int d0 = blockIdx.x * 16;
  for (int i = tid; i < 8 * D_; i += 256) {
    const int b = i / D_, e = i - b * D_;
    const float s = part[((size_t)b * 4 + 0) * D_ + e] + part[((size_t)b * 4 + 1) * D_ + e] +
                    part[((size_t)b * 4 + 2) * D_ + e] + part[((size_t)b * 4 + 3) * D_ + e];
    row[b][e] = s * (1.0f / 99.0f);
  }
  __syncthreads();
  const int dl = tid >> 4;
  const int ec = tid & 15;
  const float* w = W + (size_t)(d0 + dl) * D_ + ec * 48;
  float acc[8] = {};
  for (int e = 0; e < 48; e += 4) {
    const float4 wv = *reinterpret_cast<const float4*>(w + e);
    const int eg = ec * 48 + e;
#pragma unroll
    for (int b = 0; b < 8; ++b) {
      acc[b] = fmaf(row[b][eg], wv.x, acc[b]);
      acc[b] = fmaf(row[b][eg + 1], wv.y, acc[b]);
      acc[b] = fmaf(row[b][eg + 2], wv.z, acc[b]);
      acc[b] = fmaf(row[b][eg + 3], wv.w, acc[b]);
    }
  }
#pragma unroll
  for (int b = 0; b < 8; ++b) red[dl][ec][b] = acc[b];
  __syncthreads();
  if (tid < 128) {
    const int dl2 = tid >> 3, b = tid & 7;
    float s = bias[d0 + dl2];
    for (int c = 0; c < 16; ++c) s += red[dl2][c][b];
    gate[b * D_ + d0 + dl2] = s;
  }
}

// -------- fused: image irfft (ortho) + residual + LayerNorm -> bf16 --------
__global__ __launch_bounds__(256) void k_img_irfft_ln(
    const float2* __restrict__ imgF, const float* __restrict__ image,
    const float* __restrict__ g, const float* __restrict__ bia,
    unsigned short* __restrict__ xh) {
  const int t = blockIdx.x;
  const int b = blockIdx.y;
  const int tid = threadIdx.x;
  __shared__ float cf[NF_], sf[NF_];
  if (tid < NF_) {
    const int r = (t * tid) % N_;
    float s, c;
    sincosf(TWOPI_ * (float)r / (float)N_, &s, &c);
    cf[tid] = c; sf[tid] = s;
  }
  __syncthreads();
  const float sgn_ny = (t & 1) ? -1.f : 1.f;
  float v[3];
#pragma unroll
  for (int j = 0; j < 3; ++j) {
    const int d = tid + j * 256;
    const float2* zp = imgF + (size_t)b * NF_ * D_ + d;
    float acc = zp[0].x;
    for (int f = 1; f < NF_ - 1; ++f) {
      const float2 z = zp[(size_t)f * D_];
      acc += 2.f * (z.x * cf[f] - z.y * sf[f]);
    }
    acc += zp[(size_t)(NF_ - 1) * D_].x * sgn_ny;
    v[j] = acc * (1.0f / 14.0f) + image[(size_t)(b * N_ + t) * D_ + d];
  }
  float s = v[0] + v[1] + v[2];
  float q = v[0] * v[0] + v[1] * v[1] + v[2] * v[2];
  __shared__ float red[8];
  for (int off = 32; off > 0; off >>= 1) {
    s += __shfl_down(s, off);
    q += __shfl_down(q, off);
  }
  if ((tid & 63) == 0) { red[tid >> 6] = s; red[4 + (tid >> 6)] = q; }
  __syncthreads();
  s = red[0] + red[1] + red[2] + red[3];
  q = red[4] + red[5] + red[6] + red[7];
  const float mean = s * (1.0f / 768.0f);
  const float var = q * (1.0f / 768.0f) - mean * mean;
  const float inv = rsqrtf(var + 1e-5f);
  unsigned short* orow = xh + (size_t)(b * N_ + t) * D_;
#pragma unroll
  for (int j = 0; j < 3; ++j) {
    const int d = tid + j * 256;
    orow[d] = f2bf((v[j] - mean) * inv * g[d] + bia[d]);
  }
}

// ================= ecg fused FFT pipeline (unchanged structure) =================
template <int SS, int DIR>
__device__ __forceinline__ void dblpass(float2* z, const float2* tw, int q) {
  asm volatile("s_waitcnt lgkmcnt(0)" ::: "memory");
  const int h = 1 << SS;
  const int j = q & (h - 1);
  const int base = ((q >> SS) << (SS + 2)) | j;
  const int e0 = padz(base), e1 = padz(base + h);
  const int e2 = padz(base + 2 * h), e3 = padz(base + 3 * h);
  const float2 x0 = z[e0], x1 = z[e1], x2 = z[e2], x3 = z[e3];
  const float2 tw1 = tw[h - 1 + j];
  const float2 tw2 = tw[2 * h - 1 + j];
  const float sg = (DIR < 0) ? -1.f : 1.f;
  const float w1c = tw1.x, w1s = sg * tw1.y;
  const float w2c = tw2.x, w2s = sg * tw2.y;
  const float t1r = x1.x * w1c - x1.y * w1s, t1i = x1.x * w1s + x1.y * w1c;
  const float t3r = x3.x * w1c - x3.y * w1s, t3i = x3.x * w1s + x3.y * w1c;
  const float a0r = x0.x + t1r, a0i = x0.y + t1i;
  const float a1r = x0.x - t1r, a1i = x0.y - t1i;
  const float a2r = x2.x + t3r, a2i = x2.y + t3i;
  const float a3r = x2.x - t3r, a3i = x2.y - t3i;
  const float u2r = a2r * w2c - a2i * w2s, u2i = a2r * w2s + a2i * w2c;
  const float v3r = a3r * w2c - a3i * w2s, v3i = a3r * w2s + a3i * w2c;
  const float u3r = -sg * v3i, u3i = sg * v3r;
  z[e0] = make_float2(a0r + u2r, a0i + u2i);
  z[e2] = make_float2(a0r - u2r, a0i - u2i);
  z[e1] = make_float2(a1r + u3r, a1i + u3i);
  z[e3] = make_float2(a1r - u3r, a1i - u3i);
}

template <int DIR>
__device__ __forceinline__ void stage8(float2* z, const float2* tw, int t) {
  const float2 w = tw[255 + t];
  const float wc = w.x, ws = (DIR < 0) ? -w.y : w.y;
  const int a0 = padz(t), a1 = padz(t + 256);
  const float2 x = z[a0], y = z[a1];
  const float tr = y.x * wc - y.y * ws, ti = y.x * ws + y.y * wc;
  z[a0] = make_float2(x.x + tr, x.y + ti);
  z[a1] = make_float2(x.x - tr, x.y - ti);
}

template <int FA, int FB>
__device__ __forceinline__ void filt_pack(const float2* z, int k, float g,
                                          float2 cA, float2 cB,
                                          float2& Ck, float2& Cm) {
  const int q = (512 - k) & 511;
  const float2 Zk = z[padz(k)], Zq = z[padz(q)];
  const float sc = 0.5f / 256.f;
  const float ar = (Zk.x + Zq.x) * sc, ai = (Zk.y - Zq.y) * sc;
  float yar, yai, ybr = 0.f, ybi = 0.f;
  {
    const float pr = (ar * ar - ai * ai) * (1.f / 2313.f);
    const float pi = (2.f * ar * ai) * (1.f / 2313.f);
    yar = (pr * cA.x - pi * cA.y) * g;
    yai = (pr * cA.y + pi * cA.x) * g;
  }
  if (FB >= 0) {
    const float br = (Zk.y + Zq.y) * sc, bi = (Zq.x - Zk.x) * sc;
    const float pr = (br * br - bi * bi) * (1.f / 2313.f);
    const float pi = (2.f * br * bi) * (1.f / 2313.f);
    ybr = (pr * cB.x - pi * cB.y) * g;
    ybi = (pr * cB.y + pi * cB.x) * g;
  }
  if (k == 0 || k == 256) {
    Ck = make_float2(yar, ybr);
    Cm = Ck;
  } else {
    Ck = make_float2(yar - ybi, yai + ybr);
    Cm = make_float2(yar + ybi, ybr - yai);
  }
}

template <int FA0, int FB0, int FA1, int FB1, bool DUAL>
__device__ __forceinline__ void ecg_super(int tid, float g, const float2* __restrict__ fc,
                                          const float (&s)[8], const float2* tw,
                                          float2* zA, float2* zB, float* accr) {
  const float c0 = tw[255 + tid].x;
  const float wlo = 0.5f - 0.5f * c0;
  const float whi = 0.5f + 0.5f * c0;
  const float2 cA0 = fc[FA0 * 257 + tid];
  float2 cB0 = make_float2(0.f, 0.f), cA1 = cB0, cB1 = cB0;
  if (FB0 >= 0) cB0 = fc[FB0 * 257 + tid];
  if (DUAL) { cA1 = fc[FA1 * 257 + tid]; cB1 = fc[FB1 * 257 + tid]; }
  float2 nA0 = make_float2(0.f, 0.f), nB0 = nA0, nA1 = nA0, nB1 = nA0;
  if (tid == 0) {
    nA0 = fc[FA0 * 257 + 256];
    if (FB0 >= 0) nB0 = fc[FB0 * 257 + 256];
    if (DUAL) { nA1 = fc[FA1 * 257 + 256]; nB1 = fc[FB1 * 257 + 256]; }
  }
  __syncthreads();
  {
    constexpr int iAlo = (FA0 > 0) ? FA0 - 1 : 0;
    constexpr int iAhi = (FA0 < 8) ? FA0 : 0;
    constexpr int iBlo = (FB0 > 0) ? FB0 - 1 : 0;
    constexpr int iBhi = (FB0 >= 0 && FB0 < 8) ? FB0 : 0;
    const int rlo = padz(rev9(tid)), rhi = padz(rev9(tid + 256));
    const float aLo = (FA0 == 0) ? 0.f : s[iAlo] * wlo;
    const float aHi = (FA0 == 8) ? 0.f : s[iAhi] * whi;
    const float bLo = (FB0 <= 0) ? 0.f : s[iBlo] * wlo;
    const float bHi = (FB0 < 0 || FB0 == 8) ? 0.f : s[iBhi] * whi;
    zA[rlo] = make_float2(aLo, bLo);
    zA[rhi] = make_float2(aHi, bHi);
    if (DUAL) {
      constexpr int jAlo = (FA1 > 0) ? FA1 - 1 : 0;
      constexpr int jAhi = (FA1 < 8) ? FA1 : 0;
      constexpr int jBlo = (FB1 > 0) ? FB1 - 1 : 0;
      constexpr int jBhi = (FB1 < 8) ? FB1 : 0;
      const float eLo = (FA1 == 0) ? 0.f : s[jAlo] * wlo;
      const float eHi = (FA1 == 8) ? 0.f : s[jAhi] * whi;
      const float fLo = (FB1 == 0) ? 0.f : s[jBlo] * wlo;
      const float fHi = (FB1 == 8) ? 0.f : s[jBhi] * whi;
      zB[rlo] = make_float2(eLo, fLo);
      zB[rhi] = make_float2(eHi, fHi);
    }
  }
  __syncthreads();
  if (DUAL || tid < 128) {
    float2* zz = (tid < 128) ? zA : zB;
    const int q = tid & 127;
    dblpass<0, -1>(zz, tw, q);
    dblpass<2, -1>(zz, tw, q);
    dblpass<4, -1>(zz, tw, q);
    dblpass<6, -1>(zz, tw, q);
  }
  __syncthreads();
  stage8<-1>(zA, tw, tid);
  if (DUAL) stage8<-1>(zB, tw, tid);
  __syncthreads();
  float2 CAk, CAm, CBk, CBm;
  filt_pack<FA0, FB0>(zA, tid, g, cA0, cB0, CAk, CAm);
  float2 CAn, CBn, dum;
  if (tid == 0) filt_pack<FA0, FB0>(zA, 256, g, nA0, nB0, CAn, dum);
  if (DUAL) {
    filt_pack<FA1, FB1>(zB, tid, g, cA1, cB1, CBk, CBm);
    if (tid == 0) filt_pack<FA1, FB1>(zB, 256, g, nA1, nB1, CBn, dum);
  }
  __syncthreads();
  {
    const int rk = padz(rev9(tid));
    zA[rk] = CAk;
    if (DUAL) zB[rk] = CBk;
    if (tid == 0) {
      zA[padz(1)] = CAn;
      if (DUAL) zB[padz(1)] = CBn;
    } else {
      const int rm = padz(rev9(512 - tid));
      zA[rm] = CAm;
      if (DUAL) zB[rm] = CBm;
    }
  }
  __syncthreads();
  if (DUAL || tid < 128) {
    float2* zz = (tid < 128) ? zA : zB;
    const int q = tid & 127;
    dblpass<0, 1>(zz, tw, q);
    dblpass<2, 1>(zz, tw, q);
    dblpass<4, 1>(zz, tw, q);
    dblpass<6, 1>(zz, tw, q);
  }
  __syncthreads();
  stage8<1>(zA, tw, tid);
  if (DUAL) stage8<1>(zB, tw, tid);
  {
    const float2 vLo = zA[padz(tid)], vHi = zA[padz(tid + 256)];
    accr[FA0] += 0.5f * wlo * vLo.x;
    accr[FA0 + 1] += 0.5f * whi * vHi.x;
    if (FB0 >= 0) {
      accr[FB0] += 0.5f * wlo * vLo.y;
      accr[FB0 + 1] += 0.5f * whi * vHi.y;
    }
    if (DUAL) {
      const float2 uLo = zB[padz(tid)], uHi = zB[padz(tid + 256)];
      accr[FA1] += 0.5f * wlo * uLo.x;
      accr[FA1 + 1] += 0.5f * whi * uHi.x;
      accr[FB1] += 0.5f * wlo * uLo.y;
      accr[FB1 + 1] += 0.5f * whi * uHi.y;
    }
  }
}

__global__ __launch_bounds__(256) void k_ecg_fft(
    const float* __restrict__ ecgT, const float2* __restrict__ FcT,
    const float* __restrict__ gate, const float2* __restrict__ twg,
    float* __restrict__ xtT) {
  const int bd = blockIdx.x;
  const int d = bd % D_;
  const int tid = threadIdx.x;

  __shared__ float2 tw[511];
  __shared__ float2 zA[640], zB[640];

  float s[8];
  const float* src = ecgT + (size_t)bd * S_;
#pragma unroll
  for (int k = 0; k < 8; ++k) s[k] = src[k * 256 + tid];
  for (int i = tid; i < 511; i += 256) tw[i] = twg[i];
  __syncthreads();

  const float g = gate[bd];
  const float2* fc = FcT + (size_t)d * NBINS_;
  float accr[10];
#pragma unroll
  for (int i = 0; i < 10; ++i) accr[i] = 0.f;

  ecg_super<0, 8, 1, 2, true>(tid, g, fc, s, tw, zA, zB, accr);
  ecg_super<3, 4, 5, 6, true>(tid, g, fc, s, tw, zA, zB, accr);
  ecg_super<7, -1, 0, 0, false>(tid, g, fc, s, tw, zA, zB, accr);

  const float c0 = tw[255 + tid].x;
  const float nrm = 0.5f + 0.5f * c0 * c0;
  float* dst = xtT + (size_t)bd * S_;
#pragma unroll
  for (int i2 = 0; i2 < 8; ++i2)
    dst[i2 * 256 + tid] = accr[i2 + 1] / nrm + s[i2];
}

// ---- per-(b,t) LN stats over d, reading xtT[b][d][t] coalesced ----
__global__ __launch_bounds__(256) void k_colstats(const float* __restrict__ xtT,
                                                  float2* __restrict__ stats) {
  const int b = blockIdx.y;
  const int t0 = blockIdx.x * 64;
  const int tx = threadIdx.x & 63;
  const int ty = threadIdx.x >> 6;
  float s = 0.f, q = 0.f;
  const float* base = xtT + (size_t)b * D_ * S_ + t0 + tx;
  for (int dd = ty; dd < D_; dd += 4) {
    const float v = base[(size_t)dd * S_];
    s += v;
    q = fmaf(v, v, q);
  }
  __shared__ float sh_s[4][64], sh_q[4][64];
  sh_s[ty][tx] = s; sh_q[ty][tx] = q;
  __syncthreads();
  if (ty == 0) {
    s = sh_s[0][tx] + sh_s[1][tx] + sh_s[2][tx] + sh_s[3][tx];
    q = sh_q[0][tx] + sh_q[1][tx] + sh_q[2][tx] + sh_q[3][tx];
    stats[(size_t)b * S_ + t0 + tx] = make_float2(s, q);
  }
}

// ---- transpose + LN apply + bf16 ----
__global__ __launch_bounds__(256) void k_transpose_ln(
    const float* __restrict__ xtT, const float2* __restrict__ stats,
    const float* __restrict__ g, const float* __restrict__ bia,
    unsigned short* __restrict__ xhat) {
  __shared__ float tile[32][33];
  const int b = blockIdx.z;
  const int t0 = blockIdx.x * 32;
  const int d0 = blockIdx.y * 32;
  const int tx = threadIdx.x & 31, ty = threadIdx.x >> 5;
  for (int i = ty; i < 32; i += 8)
    tile[i][tx] = xtT[((size_t)b * D_ + d0 + i) * S_ + t0 + tx];
  __syncthreads();
  const float gv = g[d0 + tx], bv = bia[d0 + tx];
  for (int i = ty; i < 32; i += 8) {
    const float2 st = stats[(size_t)b * S_ + t0 + i];
    const float mean = st.x * (1.0f / 768.0f);
    const float var = st.y * (1.0f / 768.0f) - mean * mean;
    const float inv = rsqrtf(var + 1e-5f);
    xhat[((size_t)b * S_ + t0 + i) * D_ + d0 + tx] =
        f2bf((tile[tx][i] - mean) * inv * gv + bv);
  }
}

// ---------------- LayerNorm over D=768, bf16 in -> f32 out ----------------
__global__ __launch_bounds__(256) void k_layernorm_bf(const unsigned short* __restrict__ x,
                                                      const float* __restrict__ g,
                                                      const float* __restrict__ b,
                                                      float* __restrict__ out) {
  const int row = blockIdx.x;
  const int tid = threadIdx.x;
  const unsigned short* xr = x + (size_t)row * D_;
  const float v0 = bf2f(xr[tid]), v1 = bf2f(xr[tid + 256]), v2 = bf2f(xr[tid + 512]);
  float s = v0 + v1 + v2;
  float q = v0 * v0 + v1 * v1 + v2 * v2;
  __shared__ float red[8];
  for (int off = 32; off > 0; off >>= 1) {
    s += __shfl_down(s, off);
    q += __shfl_down(q, off);
  }
  if ((tid & 63) == 0) { red[tid >> 6] = s; red[4 + (tid >> 6)] = q; }
  __syncthreads();
  s = red[0] + red[1] + red[2] + red[3];
  q = red[4] + red[5] + red[6] + red[7];
  const float mean = s * (1.0f / 768.0f);
  const float var = q * (1.0f / 768.0f) - mean * mean;
  const float inv = rsqrtf(var + 1e-5f);
  float* orow = out + (size_t)row * D_;
  orow[tid]       = (v0 - mean) * inv * g[tid]       + b[tid];
  orow[tid + 256] = (v1 - mean) * inv * g[tid + 256] + b[tid + 256];
  orow[tid + 512] = (v2 - mean) * inv * g[tid + 512] + b[tid + 512];
}

// ---------- MFMA GEMM, double-buffered pipeline ----------
// MODE 0: exact GELU -> bf16 ; MODE 1: +resid(bf16) -> bf16
template <int MODE>
__global__ __launch_bounds__(256) void k_gemm_mfma(
    const unsigned short* __restrict__ Abf, const unsigned short* __restrict__ Wbf,
    const float* __restrict__ bias, const unsigned short* __restrict__ resid,
    unsigned short* __restrict__ outb, int M) {
  __shared__ unsigned short Asm[2][128 * 64];  // 2 x 16 KB
  __shared__ unsigned short Bsm[2][128 * 64];
  const int tid = threadIdx.x;
  const int lane = tid & 63, wid = tid >> 6;
  const int wr = wid >> 1, wc = wid & 1;
  const int n0 = blockIdx.x * 128, m0 = blockIdx.y * 128;

  auto STAGE = [&](int buf, int kt) {
    const int k0 = kt * 64;
#pragma unroll
    for (int i = 0; i < 4; ++i) {
      const int c = tid + 256 * i;
      const int row = c >> 3, sl = c & 7;
      const int gsl = sl ^ (row & 7);
      gload16(Abf + (size_t)(m0 + row) * 768 + k0 + gsl * 8, &Asm[buf][c * 8]);
      gload16(Wbf + (size_t)(n0 + row) * 768 + k0 + gsl * 8, &Bsm[buf][c * 8]);
    }
  };

  f32x4 acc[4][4] = {};
  STAGE(0, 0);
  for (int kt = 0; kt < 12; ++kt) {
    const int cur = kt & 1;
    if (kt < 11) {
      STAGE(cur ^ 1, kt + 1);
      asm volatile("s_waitcnt vmcnt(8)" ::: "memory");  // drain kt's 8 loads only
    } else {
      asm volatile("s_waitcnt vmcnt(0)" ::: "memory");
    }
    __builtin_amdgcn_sched_barrier(0);
    __builtin_amdgcn_s_barrier();
#pragma unroll
    for (int ks = 0; ks < 2; ++ks) {
      bf16x8 af[4], bfv[4];
#pragma unroll
      for (int mi = 0; mi < 4; ++mi) {
        const int row = wr * 64 + mi * 16 + (lane & 15);
        const int sl = (ks * 4 + (lane >> 4)) ^ (row & 7);
        af[mi] = *(const bf16x8*)((const char*)Asm[cur] + row * 128 + sl * 16);
      }
#pragma unroll
      for (int ni = 0; ni < 4; ++ni) {
        const int row = wc * 64 + ni * 16 + (lane & 15);
        const int sl = (ks * 4 + (lane >> 4)) ^ (row & 7);
        bfv[ni] = *(const bf16x8*)((const char*)Bsm[cur] + row * 128 + sl * 16);
      }
#pragma unroll
      for (int mi = 0; mi < 4; ++mi)
#pragma unroll
        for (int ni = 0; ni < 4; ++ni)
          acc[mi][ni] = __builtin_amdgcn_mfma_f32_16x16x32_bf16(af[mi], bfv[ni],
                                                                acc[mi][ni], 0, 0, 0);
    }
    __builtin_amdgcn_sched_barrier(0);
    __builtin_amdgcn_s_barrier();   // all waves done reading buf cur (MFMA consumed)
  }
#pragma unroll
  for (int mi = 0; mi < 4; ++mi) {
#pragma unroll
    for (int ni = 0; ni < 4; ++ni) {
      const int col = n0 + wc * 64 + ni * 16 + (lane & 15);
#pragma unroll
      for (int e = 0; e < 4; ++e) {
        const int row = m0 + wr * 64 + mi * 16 + (lane >> 4) * 4 + e;
        if (row >= M) continue;
        float v = acc[mi][ni][e] + bias[col];
        if (MODE == 0) {
          v = 0.5f * v * (1.0f + erff(v * 0.70710678118654752440f));
        } else {
          v += bf2f(resid[(size_t)row * 768 + col]);
        }
        outb[(size_t)row * 768 + col] = f2bf(v);
      }
    }
  }
}

}  // namespace

extern "C" void kernel_launch(void* const* d_in, const int* in_sizes, int n_in,
                              void* d_out, int out_size, void* d_ws, size_t ws_size,
                              hipStream_t stream) {
  (void)in_sizes; (void)n_in; (void)out_size; (void)ws_size;
  const float* ecg     = (const float*)d_in[0];
  const float* image   = (const float*)d_in[1];
  const float* ebank   = (const float*)d_in[2];
  const float* cbank   = (const float*)d_in[3];
  const float* gsel    = (const float*)d_in[4];
  const float* gw      = (const float*)d_in[5];
  const float* gb      = (const float*)d_in[6];
  const float* e_ln1_g = (const float*)d_in[7];
  const float* e_ln1_b = (const float*)d_in[8];
  const float* e_w1    = (const float*)d_in[9];
  const float* e_b1    = (const float*)d_in[10];
  const float* e_w2    = (const float*)d_in[11];
  const float* e_b2    = (const float*)d_in[12];
  const float* e_ln2_g = (const float*)d_in[13];
  const float* e_ln2_b = (const float*)d_in[14];
  const float* c_ln1_g = (const float*)d_in[15];
  const float* c_ln1_b = (const float*)d_in[16];
  const float* c_w1    = (const float*)d_in[17];
  const float* c_b1    = (const float*)d_in[18];
  const float* c_w2    = (const float*)d_in[19];
  const float* c_b2    = (const float*)d_in[20];
  const float* c_ln2_g = (const float*)d_in[21];
  const float* c_ln2_b = (const float*)d_in[22];

  float* out = (float*)d_out;
  float* ws = (float*)d_ws;

  constexpr size_t TXT = (size_t)8 * 2048 * 768;
  constexpr size_t IMG = (size_t)8 * 196 * 768;

  // ws layout: A | Bb | wbf | gatev | stats | gpart | twg
  float* A  = ws;
  float* Bb = A + TXT;
  unsigned short* wbf = (unsigned short*)(Bb + TXT);
  unsigned short* ew1b = wbf;
  unsigned short* ew2b = wbf + NW_;
  unsigned short* cw1b = wbf + 2 * NW_;
  unsigned short* cw2b = wbf + 3 * NW_;
  float* gatev = (float*)(wbf + 4 * (size_t)NW_);
  float2* stats = (float2*)(gatev + 8 * 768);
  float* gpart = (float*)(stats + 8 * 2048);
  float2* twg = (float2*)(gpart + 8 * 4 * 768);

  float2* FcT = (float2*)out;  // parked in d_out[0:3.6M] (dead before final LN)

  // image-path scratch inside A (consumed before transpose_g overwrites A)
  unsigned short* xh_i = (unsigned short*)A;       // bf16 LN1 out / resid
  unsigned short* h_i  = xh_i + IMG;               // bf16 GELU act
  unsigned short* y_ib = h_i + IMG;                // bf16 pre-LN2

  // text buffers
  unsigned short* xhat = (unsigned short*)A;           // bf16 LN1 / resid (TXT ushorts)
  unsigned short* y_tb = (unsigned short*)A + TXT;     // bf16 pre-LN2
  unsigned short* h_t  = (unsigned short*)Bb;          // bf16 GELU act (xtT dead)

  // ---- one-time prep (fused) ----
  k_prep<<<PREP_WALL + PREP_FC + 2, 256, 0, stream>>>(
      e_w1, e_w2, c_w1, c_w2, wbf, (const float2*)ebank, FcT, twg);

  // ---- image path (produces gate) ----
  k_img_rfft_filter<<<dim3(99, 8), 256, 0, stream>>>(image, (const float2*)cbank,
                                                     (float2*)Bb);
  k_gate_pool<<<dim3(8, 4), 256, 0, stream>>>((const float2*)Bb, (const float2*)gsel, gpart);
  k_gate_mm2<<<48, 256, 0, stream>>>(gpart, gw, gb, gatev);
  k_img_irfft_ln<<<dim3(196, 8), 256, 0, stream>>>((const float2*)Bb, image,
                                                   c_ln1_g, c_ln1_b, xh_i);
  k_gemm_mfma<0><<<dim3(6, 13), 256, 0, stream>>>(xh_i, cw1b, c_b1, nullptr, h_i, 1568);
  k_gemm_mfma<1><<<dim3(6, 13), 256, 0, stream>>>(h_i, cw2b, c_b2, xh_i, y_ib, 1568);
  k_layernorm_bf<<<1568, 256, 0, stream>>>(y_ib, c_ln2_g, c_ln2_b, out + TXT);

  // ---- ecg path ----
  k_transpose_g<<<dim3(24, 64, 8), 256, 0, stream>>>(ecg, A, 2048, 768);
  k_ecg_fft<<<8 * 768, 256, 0, stream>>>(A, FcT, gatev, twg, Bb);
  k_colstats<<<dim3(32, 8), 256, 0, stream>>>(Bb, stats);
  k_transpose_ln<<<dim3(64, 24, 8), 256, 0, stream>>>(Bb, stats, e_ln1_g, e_ln1_b, xhat);

  // ---- text FFN (bf16 MFMA, pipelined) ----
  k_gemm_mfma<0><<<dim3(6, 128), 256, 0, stream>>>(xhat, ew1b, e_b1, nullptr, h_t, 16384);
  k_gemm_mfma<1><<<dim3(6, 128), 256, 0, stream>>>(h_t, ew2b, e_b2, xhat, y_tb, 16384);
  k_layernorm_bf<<<16384, 256, 0, stream>>>(y_tb, e_ln2_g, e_ln2_b, out);
}

// Round 8
// 525.540 us; speedup vs baseline: 6.0373x; 1.0840x over previous
//
#include <hip/hip_runtime.h>
#include <math.h>

namespace {

constexpr int B_ = 8;
constexpr int S_ = 2048;
constexpr int D_ = 768;
constexpr int N_ = 196;     // image spatial
constexpr int NF_ = 99;     // image freq bins
constexpr int NFREQ_ = 257;
constexpr int NSEG_ = 9;
constexpr int NBINS_ = NFREQ_ * NSEG_;  // 2313
constexpr int NW_ = D_ * D_;            // 589824
constexpr float TWOPI_ = 6.28318530717958647692f;

using bf16x8 = __attribute__((ext_vector_type(8))) short;
using f32x4  = __attribute__((ext_vector_type(4))) float;

__device__ __forceinline__ int rev9(int x) { return (int)(__brev((unsigned)x) >> 23); }
__device__ __forceinline__ int padz(int i) { return i + (i >> 4); }  // float2 elems, 16-pair spread

__device__ __forceinline__ unsigned short f2bf(float x) {
  unsigned u = __float_as_uint(x);
  u = (u + 0x7FFFu + ((u >> 16) & 1u)) >> 16;
  return (unsigned short)u;
}
__device__ __forceinline__ float bf2f(unsigned short h) {
  return __uint_as_float(((unsigned)h) << 16);
}

__device__ __forceinline__ void gload16(const void* g, void* l) {
  __builtin_amdgcn_global_load_lds((const __attribute__((address_space(1))) void*)g,
                                   (__attribute__((address_space(3))) void*)l, 16, 0, 0);
}

// ---------------- batched transpose (B,R,C) -> (B,C,R) ----------------
__global__ __launch_bounds__(256) void k_transpose_g(const float* __restrict__ src,
                                                     float* __restrict__ dst,
                                                     int R, int C) {
  __shared__ float tile[32][33];
  const int b = blockIdx.z;
  const int c0 = blockIdx.x * 32;
  const int r0 = blockIdx.y * 32;
  const int tx = threadIdx.x & 31, ty = threadIdx.x >> 5;
  for (int i = ty; i < 32; i += 8)
    tile[i][tx] = src[((size_t)b * R + r0 + i) * C + c0 + tx];
  __syncthreads();
  for (int i = ty; i < 32; i += 8)
    dst[((size_t)b * C + c0 + i) * R + r0 + tx] = tile[tx][i];
}

// ---- fused prep: weight bf16 conv (4 mats) + filter bank + twiddles ----
constexpr int PREP_W = (NW_ + 255) / 256;          // 2304 blocks per matrix
constexpr int PREP_WALL = 4 * PREP_W;              // 9216
constexpr int PREP_FC = (NBINS_ * D_ + 255) / 256; // 6939
__global__ __launch_bounds__(256) void k_prep(
    const float* __restrict__ w0, const float* __restrict__ w1,
    const float* __restrict__ w2, const float* __restrict__ w3,
    unsigned short* __restrict__ wbf, const float2* __restrict__ e2,
    float2* __restrict__ FcT, float2* __restrict__ twg) {
  const int bid = blockIdx.x;
  if (bid < PREP_WALL) {
    const int m = bid / PREP_W;
    const int i = (bid - m * PREP_W) * 256 + threadIdx.x;
    if (i >= NW_) return;
    const float* src = (m == 0) ? w0 : (m == 1) ? w1 : (m == 2) ? w2 : w3;
    wbf[(size_t)m * NW_ + i] = f2bf(src[i]);
  } else if (bid < PREP_WALL + PREP_FC) {
    const int o = (bid - PREP_WALL) * 256 + threadIdx.x;
    if (o >= NBINS_ * D_) return;
    const int d = o / NBINS_;
    const int r = o - d * NBINS_;
    const int f = r / NFREQ_;
    const int k = r - f * NFREQ_;
    const int s = k * 9 + f;
    const float2 a = e2[(size_t)s * D_ + d];
    const float2 b = e2[(size_t)(NBINS_ + s) * D_ + d];
    FcT[o] = make_float2(-(a.x + b.x), -(a.y + b.y));
  } else {
    const int i = (bid - PREP_WALL - PREP_FC) * 256 + threadIdx.x;
    if (i >= 511) return;
    const int v = i + 1;
    const int h = 1 << (31 - __clz(v));
    const int j = v - h;
    float sn, cs;
    sincosf((float)j * ((TWOPI_ * 0.5f) / (float)h), &sn, &cs);
    twg[i] = make_float2(cs, sn);
  }
}

// ---- image forward DFT + filter: block = (fgroup of 9, dchunk of 256, b) ----
__global__ __launch_bounds__(256) void k_img_dft_f(
    const float* __restrict__ image, const float2* __restrict__ bank2,
    float2* __restrict__ imgF) {
  const int f0 = blockIdx.x * 9;
  const int d = blockIdx.y * 256 + threadIdx.x;
  const int b = blockIdx.z;
  __shared__ float2 tws[9 * N_];  // e^{-i 2pi (f0+fi) t / 196}, 14.1 KB
  for (int idx = threadIdx.x; idx < 9 * N_; idx += 256) {
    const int fi = idx / N_;
    const int t = idx - fi * N_;
    const int r = ((f0 + fi) * t) % N_;
    float sn, cs;
    sincosf(TWOPI_ * (float)r / (float)N_, &sn, &cs);
    tws[idx] = make_float2(cs, sn);
  }
  __syncthreads();
  float re[9] = {}, im[9] = {};
  const float* ip = image + (size_t)b * N_ * D_ + d;
  for (int t = 0; t < N_; ++t) {
    const float v = ip[(size_t)t * D_];
#pragma unroll
    for (int fi = 0; fi < 9; ++fi) {
      const float2 w = tws[fi * N_ + t];   // broadcast, conflict-free
      re[fi] = fmaf(v, w.x, re[fi]);
      im[fi] = fmaf(-v, w.y, im[fi]);
    }
  }
  const float sc = 1.0f / (196.0f * 99.0f);
#pragma unroll
  for (int fi = 0; fi < 9; ++fi) {
    const int f = f0 + fi;
    const float pr = (re[fi] * re[fi] - im[fi] * im[fi]) * sc;
    const float pi2 = (2.f * re[fi] * im[fi]) * sc;
    const size_t fd = (size_t)f * D_ + d;
    const float2 c0 = bank2[fd];
    const float2 c1 = bank2[(size_t)NF_ * D_ + fd];
    const float fcr = -(c0.x + c1.x), fci = -(c0.y + c1.y);
    imgF[(size_t)(b * NF_ + f) * D_ + d] =
        make_float2(pr * fcr - pi2 * fci, pr * fci + pi2 * fcr);
  }
}

// ---- gate pooling, partials over freq chunks: part[b][p][d] ----
__global__ __launch_bounds__(256) void k_gate_pool(const float2* __restrict__ imgF,
                                                   const float2* __restrict__ gsel2,
                                                   float* __restrict__ part) {
  const int b = blockIdx.x;
  const int p = blockIdx.y;           // 0..3
  const int f0 = p * 25;
  const int f1 = (p == 3) ? NF_ : f0 + 25;
  for (int d = threadIdx.x; d < D_; d += 256) {
    float acc = 0.f;
    for (int f = f0; f < f1; ++f) {
      const float2 z = imgF[(size_t)(b * NF_ + f) * D_ + d];
      const float2 w = gsel2[(size_t)f * D_ + d];
      acc += z.x * w.x - z.y * w.y;
    }
    part[((size_t)b * 4 + p) * D_ + d] = acc;
  }
}

// ---- gate matvec, all batches per block: gate[b][d0..d0+16) ----
__global__ __launch_bounds__(256) void k_gate_mm2(const float* __restrict__ part,
                                                  const float* __restrict__ W,
                                                  const float* __restrict__ bias,
                                                  float* __restrict__ gate) {
  __shared__ float row[8][D_];
  __shared__ float red[16][16][8];
  const int tid = threadIdx.x;
  const int d0 = blockIdx.x * 16;
  for (int i = tid; i < 8 * D_; i += 256) {
    const int b = i / D_, e = i - b * D_;
    const float s = part[((size_t)b * 4 + 0) * D_ + e] + part[((size_t)b * 4 + 1) * D_ + e] +
                    part[((size_t)b * 4 + 2) * D_ + e] + part[((size_t)b * 4 + 3) * D_ + e];
    row[b][e] = s * (1.0f / 99.0f);
  }
  __syncthreads();
  const int dl = tid >> 4;
  const int ec = tid & 15;
  const float* w = W + (size_t)(d0 + dl) * D_ + ec * 48;
  float acc[8] = {};
  for (int e = 0; e < 48; e += 4) {
    const float4 wv = *reinterpret_cast<const float4*>(w + e);
    const int eg = ec * 48 + e;
#pragma unroll
    for (int b = 0; b < 8; ++b) {
      acc[b] = fmaf(row[b][eg], wv.x, acc[b]);
      acc[b] = fmaf(row[b][eg + 1], wv.y, acc[b]);
      acc[b] = fmaf(row[b][eg + 2], wv.z, acc[b]);
      acc[b] = fmaf(row[b][eg + 3], wv.w, acc[b]);
    }
  }
#pragma unroll
  for (int b = 0; b < 8; ++b) red[dl][ec][b] = acc[b];
  __syncthreads();
  if (tid < 128) {
    const int dl2 = tid >> 3, b = tid & 7;
    float s = bias[d0 + dl2];
    for (int c = 0; c < 16; ++c) s += red[dl2][c][b];
    gate[b * D_ + d0 + dl2] = s;
  }
}

// ---- image inverse DFT (ortho) + residual: block = (tgroup of 14, dchunk, b) ----
__global__ __launch_bounds__(256) void k_img_idft(
    const float2* __restrict__ imgF, const float* __restrict__ image,
    float* __restrict__ xi) {
  const int t0 = blockIdx.x * 14;
  const int d = blockIdx.y * 256 + threadIdx.x;
  const int b = blockIdx.z;
  __shared__ float2 tws[14 * NF_];  // e^{+i 2pi (t0+ti) f / 196}, 10.8 KB
  for (int idx = threadIdx.x; idx < 14 * NF_; idx += 256) {
    const int ti = idx / NF_;
    const int f = idx - ti * NF_;
    const int r = ((t0 + ti) * f) % N_;
    float sn, cs;
    sincosf(TWOPI_ * (float)r / (float)N_, &sn, &cs);
    tws[idx] = make_float2(cs, sn);
  }
  __syncthreads();
  const float2* zp = imgF + (size_t)b * NF_ * D_ + d;
  const float2 z0 = zp[0];
  const float2 zny = zp[(size_t)(NF_ - 1) * D_];
  float acc[14];
#pragma unroll
  for (int ti = 0; ti < 14; ++ti)
    acc[ti] = z0.x + (((t0 + ti) & 1) ? -zny.x : zny.x);
  for (int f = 1; f < NF_ - 1; ++f) {
    const float2 z = zp[(size_t)f * D_];
#pragma unroll
    for (int ti = 0; ti < 14; ++ti) {
      const float2 w = tws[ti * NF_ + f];   // broadcast
      acc[ti] += 2.f * (z.x * w.x - z.y * w.y);
    }
  }
#pragma unroll
  for (int ti = 0; ti < 14; ++ti) {
    const size_t idx = (size_t)(b * N_ + t0 + ti) * D_ + d;
    xi[idx] = acc[ti] * (1.0f / 14.0f) + image[idx];
  }
}

// ---------------- LayerNorm f32 in -> bf16 out ----------------
__global__ __launch_bounds__(256) void k_layernorm_f2b(const float* __restrict__ x,
                                                       const float* __restrict__ g,
                                                       const float* __restrict__ b,
                                                       unsigned short* __restrict__ out) {
  const int row = blockIdx.x;
  const int tid = threadIdx.x;
  const float* xr = x + (size_t)row * D_;
  const float v0 = xr[tid], v1 = xr[tid + 256], v2 = xr[tid + 512];
  float s = v0 + v1 + v2;
  float q = v0 * v0 + v1 * v1 + v2 * v2;
  __shared__ float red[8];
  for (int off = 32; off > 0; off >>= 1) {
    s += __shfl_down(s, off);
    q += __shfl_down(q, off);
  }
  if ((tid & 63) == 0) { red[tid >> 6] = s; red[4 + (tid >> 6)] = q; }
  __syncthreads();
  s = red[0] + red[1] + red[2] + red[3];
  q = red[4] + red[5] + red[6] + red[7];
  const float mean = s * (1.0f / 768.0f);
  const float var = q * (1.0f / 768.0f) - mean * mean;
  const float inv = rsqrtf(var + 1e-5f);
  unsigned short* orow = out + (size_t)row * D_;
  orow[tid]       = f2bf((v0 - mean) * inv * g[tid]       + b[tid]);
  orow[tid + 256] = f2bf((v1 - mean) * inv * g[tid + 256] + b[tid + 256]);
  orow[tid + 512] = f2bf((v2 - mean) * inv * g[tid + 512] + b[tid + 512]);
}

// ================= ecg fused FFT pipeline (register twiddles) =================
template <int SS, int DIR>
__device__ __forceinline__ void dblpass(float2* z, int q, float2 tw1, float2 tw2) {
  asm volatile("s_waitcnt lgkmcnt(0)" ::: "memory");
  const int h = 1 << SS;
  const int j = q & (h - 1);
  const int base = ((q >> SS) << (SS + 2)) | j;
  const int e0 = padz(base), e1 = padz(base + h);
  const int e2 = padz(base + 2 * h), e3 = padz(base + 3 * h);
  const float2 x0 = z[e0], x1 = z[e1], x2 = z[e2], x3 = z[e3];
  const float sg = (DIR < 0) ? -1.f : 1.f;
  const float w1c = tw1.x, w1s = sg * tw1.y;
  const float w2c = tw2.x, w2s = sg * tw2.y;
  const float t1r = x1.x * w1c - x1.y * w1s, t1i = x1.x * w1s + x1.y * w1c;
  const float t3r = x3.x * w1c - x3.y * w1s, t3i = x3.x * w1s + x3.y * w1c;
  const float a0r = x0.x + t1r, a0i = x0.y + t1i;
  const float a1r = x0.x - t1r, a1i = x0.y - t1i;
  const float a2r = x2.x + t3r, a2i = x2.y + t3i;
  const float a3r = x2.x - t3r, a3i = x2.y - t3i;
  const float u2r = a2r * w2c - a2i * w2s, u2i = a2r * w2s + a2i * w2c;
  const float v3r = a3r * w2c - a3i * w2s, v3i = a3r * w2s + a3i * w2c;
  const float u3r = -sg * v3i, u3i = sg * v3r;
  z[e0] = make_float2(a0r + u2r, a0i + u2i);
  z[e2] = make_float2(a0r - u2r, a0i - u2i);
  z[e1] = make_float2(a1r + u3r, a1i + u3i);
  z[e3] = make_float2(a1r - u3r, a1i - u3i);
}

template <int DIR>
__device__ __forceinline__ void stage8(float2* z, float2 t8, int t) {
  const float wc = t8.x, ws = (DIR < 0) ? -t8.y : t8.y;
  const int a0 = padz(t), a1 = padz(t + 256);
  const float2 x = z[a0], y = z[a1];
  const float tr = y.x * wc - y.y * ws, ti = y.x * ws + y.y * wc;
  z[a0] = make_float2(x.x + tr, x.y + ti);
  z[a1] = make_float2(x.x - tr, x.y - ti);
}

template <int FA, int FB>
__device__ __forceinline__ void filt_pack(const float2* z, int k, float g,
                                          float2 cA, float2 cB,
                                          float2& Ck, float2& Cm) {
  const int q = (512 - k) & 511;
  const float2 Zk = z[padz(k)], Zq = z[padz(q)];
  const float sc = 0.5f / 256.f;
  const float ar = (Zk.x + Zq.x) * sc, ai = (Zk.y - Zq.y) * sc;
  float yar, yai, ybr = 0.f, ybi = 0.f;
  {
    const float pr = (ar * ar - ai * ai) * (1.f / 2313.f);
    const float pi = (2.f * ar * ai) * (1.f / 2313.f);
    yar = (pr * cA.x - pi * cA.y) * g;
    yai = (pr * cA.y + pi * cA.x) * g;
  }
  if (FB >= 0) {
    const float br = (Zk.y + Zq.y) * sc, bi = (Zq.x - Zk.x) * sc;
    const float pr = (br * br - bi * bi) * (1.f / 2313.f);
    const float pi = (2.f * br * bi) * (1.f / 2313.f);
    ybr = (pr * cB.x - pi * cB.y) * g;
    ybi = (pr * cB.y + pi * cB.x) * g;
  }
  if (k == 0 || k == 256) {
    Ck = make_float2(yar, ybr);
    Cm = Ck;
  } else {
    Ck = make_float2(yar - ybi, yai + ybr);
    Cm = make_float2(yar + ybi, ybr - yai);
  }
}

template <int FA0, int FB0, int FA1, int FB1, bool DUAL>
__device__ __forceinline__ void ecg_super(int tid, float g, const float2* __restrict__ fc,
                                          const float (&s)[8], const float2 (&rt)[4][2],
                                          float2 t8, float2* zA, float2* zB, float* accr) {
  const float c0 = t8.x;
  const float wlo = 0.5f - 0.5f * c0;
  const float whi = 0.5f + 0.5f * c0;
  const float2 cA0 = fc[FA0 * 257 + tid];
  float2 cB0 = make_float2(0.f, 0.f), cA1 = cB0, cB1 = cB0;
  if (FB0 >= 0) cB0 = fc[FB0 * 257 + tid];
  if (DUAL) { cA1 = fc[FA1 * 257 + tid]; cB1 = fc[FB1 * 257 + tid]; }
  float2 nA0 = make_float2(0.f, 0.f), nB0 = nA0, nA1 = nA0, nB1 = nA0;
  if (tid == 0) {
    nA0 = fc[FA0 * 257 + 256];
    if (FB0 >= 0) nB0 = fc[FB0 * 257 + 256];
    if (DUAL) { nA1 = fc[FA1 * 257 + 256]; nB1 = fc[FB1 * 257 + 256]; }
  }
  __syncthreads();
  {
    constexpr int iAlo = (FA0 > 0) ? FA0 - 1 : 0;
    constexpr int iAhi = (FA0 < 8) ? FA0 : 0;
    constexpr int iBlo = (FB0 > 0) ? FB0 - 1 : 0;
    constexpr int iBhi = (FB0 >= 0 && FB0 < 8) ? FB0 : 0;
    const int rlo = padz(rev9(tid)), rhi = padz(rev9(tid + 256));
    const float aLo = (FA0 == 0) ? 0.f : s[iAlo] * wlo;
    const float aHi = (FA0 == 8) ? 0.f : s[iAhi] * whi;
    const float bLo = (FB0 <= 0) ? 0.f : s[iBlo] * wlo;
    const float bHi = (FB0 < 0 || FB0 == 8) ? 0.f : s[iBhi] * whi;
    zA[rlo] = make_float2(aLo, bLo);
    zA[rhi] = make_float2(aHi, bHi);
    if (DUAL) {
      constexpr int jAlo = (FA1 > 0) ? FA1 - 1 : 0;
      constexpr int jAhi = (FA1 < 8) ? FA1 : 0;
      constexpr int jBlo = (FB1 > 0) ? FB1 - 1 : 0;
      constexpr int jBhi = (FB1 < 8) ? FB1 : 0;
      const float eLo = (FA1 == 0) ? 0.f : s[jAlo] * wlo;
      const float eHi = (FA1 == 8) ? 0.f : s[jAhi] * whi;
      const float fLo = (FB1 == 0) ? 0.f : s[jBlo] * wlo;
      const float fHi = (FB1 == 8) ? 0.f : s[jBhi] * whi;
      zB[rlo] = make_float2(eLo, fLo);
      zB[rhi] = make_float2(eHi, fHi);
    }
  }
  __syncthreads();
  if (DUAL || tid < 128) {
    float2* zz = (tid < 128) ? zA : zB;
    const int q = tid & 127;
    dblpass<0, -1>(zz, q, rt[0][0], rt[0][1]);
    dblpass<2, -1>(zz, q, rt[1][0], rt[1][1]);
    dblpass<4, -1>(zz, q, rt[2][0], rt[2][1]);
    dblpass<6, -1>(zz, q, rt[3][0], rt[3][1]);
  }
  __syncthreads();
  stage8<-1>(zA, t8, tid);
  if (DUAL) stage8<-1>(zB, t8, tid);
  __syncthreads();
  float2 CAk, CAm, CBk, CBm;
  filt_pack<FA0, FB0>(zA, tid, g, cA0, cB0, CAk, CAm);
  float2 CAn, CBn, dum;
  if (tid == 0) filt_pack<FA0, FB0>(zA, 256, g, nA0, nB0, CAn, dum);
  if (DUAL) {
    filt_pack<FA1, FB1>(zB, tid, g, cA1, cB1, CBk, CBm);
    if (tid == 0) filt_pack<FA1, FB1>(zB, 256, g, nA1, nB1, CBn, dum);
  }
  __syncthreads();
  {
    const int rk = padz(rev9(tid));
    zA[rk] = CAk;
    if (DUAL) zB[rk] = CBk;
    if (tid == 0) {
      zA[padz(1)] = CAn;
      if (DUAL) zB[padz(1)] = CBn;
    } else {
      const int rm = padz(rev9(512 - tid));
      zA[rm] = CAm;
      if (DUAL) zB[rm] = CBm;
    }
  }
  __syncthreads();
  if (DUAL || tid < 128) {
    float2* zz = (tid < 128) ? zA : zB;
    const int q = tid & 127;
    dblpass<0, 1>(zz, q, rt[0][0], rt[0][1]);
    dblpass<2, 1>(zz, q, rt[1][0], rt[1][1]);
    dblpass<4, 1>(zz, q, rt[2][0], rt[2][1]);
    dblpass<6, 1>(zz, q, rt[3][0], rt[3][1]);
  }
  __syncthreads();
  stage8<1>(zA, t8, tid);
  if (DUAL) stage8<1>(zB, t8, tid);
  {
    const float2 vLo = zA[padz(tid)], vHi = zA[padz(tid + 256)];
    accr[FA0] += 0.5f * wlo * vLo.x;
    accr[FA0 + 1] += 0.5f * whi * vHi.x;
    if (FB0 >= 0) {
      accr[FB0] += 0.5f * wlo * vLo.y;
      accr[FB0 + 1] += 0.5f * whi * vHi.y;
    }
    if (DUAL) {
      const float2 uLo = zB[padz(tid)], uHi = zB[padz(tid + 256)];
      accr[FA1] += 0.5f * wlo * uLo.x;
      accr[FA1 + 1] += 0.5f * whi * uHi.x;
      accr[FB1] += 0.5f * wlo * uLo.y;
      accr[FB1 + 1] += 0.5f * whi * uHi.y;
    }
  }
}

__global__ __launch_bounds__(256) void k_ecg_fft(
    const float* __restrict__ ecgT, const float2* __restrict__ FcT,
    const float* __restrict__ gate, const float2* __restrict__ twg,
    float* __restrict__ xtT) {
  const int bd = blockIdx.x;
  const int d = bd % D_;
  const int tid = threadIdx.x;

  __shared__ float2 zA[544], zB[544];  // 8.5 KB total

  float s[8];
  const float* src = ecgT + (size_t)bd * S_;
#pragma unroll
  for (int k = 0; k < 8; ++k) s[k] = src[k * 256 + tid];

  // per-thread twiddles in registers (invariant across all 10 FFT passes)
  float2 rt[4][2];
  const int q = tid & 127;
  rt[0][0] = make_float2(1.f, 0.f);
  rt[0][1] = make_float2(0.f, 1.f);
  rt[1][0] = twg[3 + (q & 3)];
  rt[1][1] = twg[7 + (q & 3)];
  rt[2][0] = twg[15 + (q & 15)];
  rt[2][1] = twg[31 + (q & 15)];
  rt[3][0] = twg[63 + (q & 63)];
  rt[3][1] = twg[127 + (q & 63)];
  const float2 t8 = twg[255 + tid];

  const float g = gate[bd];
  const float2* fc = FcT + (size_t)d * NBINS_;
  float accr[10];
#pragma unroll
  for (int i = 0; i < 10; ++i) accr[i] = 0.f;

  ecg_super<0, 8, 1, 2, true>(tid, g, fc, s, rt, t8, zA, zB, accr);
  ecg_super<3, 4, 5, 6, true>(tid, g, fc, s, rt, t8, zA, zB, accr);
  ecg_super<7, -1, 0, 0, false>(tid, g, fc, s, rt, t8, zA, zB, accr);

  const float c0 = t8.x;
  const float nrm = 0.5f + 0.5f * c0 * c0;
  float* dst = xtT + (size_t)bd * S_;
#pragma unroll
  for (int i2 = 0; i2 < 8; ++i2)
    dst[i2 * 256 + tid] = accr[i2 + 1] / nrm + s[i2];
}

// ---- per-(b,t) LN stats over d, reading xtT[b][d][t] coalesced ----
__global__ __launch_bounds__(256) void k_colstats(const float* __restrict__ xtT,
                                                  float2* __restrict__ stats) {
  const int b = blockIdx.y;
  const int t0 = blockIdx.x * 64;
  const int tx = threadIdx.x & 63;
  const int ty = threadIdx.x >> 6;
  float s = 0.f, q = 0.f;
  const float* base = xtT + (size_t)b * D_ * S_ + t0 + tx;
  for (int dd = ty; dd < D_; dd += 4) {
    const float v = base[(size_t)dd * S_];
    s += v;
    q = fmaf(v, v, q);
  }
  __shared__ float sh_s[4][64], sh_q[4][64];
  sh_s[ty][tx] = s; sh_q[ty][tx] = q;
  __syncthreads();
  if (ty == 0) {
    s = sh_s[0][tx] + sh_s[1][tx] + sh_s[2][tx] + sh_s[3][tx];
    q = sh_q[0][tx] + sh_q[1][tx] + sh_q[2][tx] + sh_q[3][tx];
    stats[(size_t)b * S_ + t0 + tx] = make_float2(s, q);
  }
}

// ---- transpose + LN apply + bf16 ----
__global__ __launch_bounds__(256) void k_transpose_ln(
    const float* __restrict__ xtT, const float2* __restrict__ stats,
    const float* __restrict__ g, const float* __restrict__ bia,
    unsigned short* __restrict__ xhat) {
  __shared__ float tile[32][33];
  const int b = blockIdx.z;
  const int t0 = blockIdx.x * 32;
  const int d0 = blockIdx.y * 32;
  const int tx = threadIdx.x & 31, ty = threadIdx.x >> 5;
  for (int i = ty; i < 32; i += 8)
    tile[i][tx] = xtT[((size_t)b * D_ + d0 + i) * S_ + t0 + tx];
  __syncthreads();
  const float gv = g[d0 + tx], bv = bia[d0 + tx];
  for (int i = ty; i < 32; i += 8) {
    const float2 st = stats[(size_t)b * S_ + t0 + i];
    const float mean = st.x * (1.0f / 768.0f);
    const float var = st.y * (1.0f / 768.0f) - mean * mean;
    const float inv = rsqrtf(var + 1e-5f);
    xhat[((size_t)b * S_ + t0 + i) * D_ + d0 + tx] =
        f2bf((tile[tx][i] - mean) * inv * gv + bv);
  }
}

// ---------------- LayerNorm over D=768, bf16 in -> f32 out ----------------
__global__ __launch_bounds__(256) void k_layernorm_bf(const unsigned short* __restrict__ x,
                                                      const float* __restrict__ g,
                                                      const float* __restrict__ b,
                                                      float* __restrict__ out) {
  const int row = blockIdx.x;
  const int tid = threadIdx.x;
  const unsigned short* xr = x + (size_t)row * D_;
  const float v0 = bf2f(xr[tid]), v1 = bf2f(xr[tid + 256]), v2 = bf2f(xr[tid + 512]);
  float s = v0 + v1 + v2;
  float q = v0 * v0 + v1 * v1 + v2 * v2;
  __shared__ float red[8];
  for (int off = 32; off > 0; off >>= 1) {
    s += __shfl_down(s, off);
    q += __shfl_down(q, off);
  }
  if ((tid & 63) == 0) { red[tid >> 6] = s; red[4 + (tid >> 6)] = q; }
  __syncthreads();
  s = red[0] + red[1] + red[2] + red[3];
  q = red[4] + red[5] + red[6] + red[7];
  const float mean = s * (1.0f / 768.0f);
  const float var = q * (1.0f / 768.0f) - mean * mean;
  const float inv = rsqrtf(var + 1e-5f);
  float* orow = out + (size_t)row * D_;
  orow[tid]       = (v0 - mean) * inv * g[tid]       + b[tid];
  orow[tid + 256] = (v1 - mean) * inv * g[tid + 256] + b[tid + 256];
  orow[tid + 512] = (v2 - mean) * inv * g[tid + 512] + b[tid + 512];
}

// ---------- MFMA GEMM, double-buffered pipeline ----------
// MODE 0: exact GELU -> bf16 ; MODE 1: +resid(bf16) -> bf16
template <int MODE>
__global__ __launch_bounds__(256) void k_gemm_mfma(
    const unsigned short* __restrict__ Abf, const unsigned short* __restrict__ Wbf,
    const float* __restrict__ bias, const unsigned short* __restrict__ resid,
    unsigned short* __restrict__ outb, int M) {
  __shared__ unsigned short Asm[2][128 * 64];
  __shared__ unsigned short Bsm[2][128 * 64];
  const int tid = threadIdx.x;
  const int lane = tid & 63, wid = tid >> 6;
  const int wr = wid >> 1, wc = wid & 1;
  const int n0 = blockIdx.x * 128, m0 = blockIdx.y * 128;

  auto STAGE = [&](int buf, int kt) {
    const int k0 = kt * 64;
#pragma unroll
    for (int i = 0; i < 4; ++i) {
      const int c = tid + 256 * i;
      const int row = c >> 3, sl = c & 7;
      const int gsl = sl ^ (row & 7);
      gload16(Abf + (size_t)(m0 + row) * 768 + k0 + gsl * 8, &Asm[buf][c * 8]);
      gload16(Wbf + (size_t)(n0 + row) * 768 + k0 + gsl * 8, &Bsm[buf][c * 8]);
    }
  };

  f32x4 acc[4][4] = {};
  STAGE(0, 0);
  for (int kt = 0; kt < 12; ++kt) {
    const int cur = kt & 1;
    if (kt < 11) {
      STAGE(cur ^ 1, kt + 1);
      asm volatile("s_waitcnt vmcnt(8)" ::: "memory");
    } else {
      asm volatile("s_waitcnt vmcnt(0)" ::: "memory");
    }
    __builtin_amdgcn_sched_barrier(0);
    __builtin_amdgcn_s_barrier();
#pragma unroll
    for (int ks = 0; ks < 2; ++ks) {
      bf16x8 af[4], bfv[4];
#pragma unroll
      for (int mi = 0; mi < 4; ++mi) {
        const int row = wr * 64 + mi * 16 + (lane & 15);
        const int sl = (ks * 4 + (lane >> 4)) ^ (row & 7);
        af[mi] = *(const bf16x8*)((const char*)Asm[cur] + row * 128 + sl * 16);
      }
#pragma unroll
      for (int ni = 0; ni < 4; ++ni) {
        const int row = wc * 64 + ni * 16 + (lane & 15);
        const int sl = (ks * 4 + (lane >> 4)) ^ (row & 7);
        bfv[ni] = *(const bf16x8*)((const char*)Bsm[cur] + row * 128 + sl * 16);
      }
#pragma unroll
      for (int mi = 0; mi < 4; ++mi)
#pragma unroll
        for (int ni = 0; ni < 4; ++ni)
          acc[mi][ni] = __builtin_amdgcn_mfma_f32_16x16x32_bf16(af[mi], bfv[ni],
                                                                acc[mi][ni], 0, 0, 0);
    }
    __builtin_amdgcn_sched_barrier(0);
    __builtin_amdgcn_s_barrier();
  }
#pragma unroll
  for (int mi = 0; mi < 4; ++mi) {
#pragma unroll
    for (int ni = 0; ni < 4; ++ni) {
      const int col = n0 + wc * 64 + ni * 16 + (lane & 15);
#pragma unroll
      for (int e = 0; e < 4; ++e) {
        const int row = m0 + wr * 64 + mi * 16 + (lane >> 4) * 4 + e;
        if (row >= M) continue;
        float v = acc[mi][ni][e] + bias[col];
        if (MODE == 0) {
          v = 0.5f * v * (1.0f + erff(v * 0.70710678118654752440f));
        } else {
          v += bf2f(resid[(size_t)row * 768 + col]);
        }
        outb[(size_t)row * 768 + col] = f2bf(v);
      }
    }
  }
}

}  // namespace

extern "C" void kernel_launch(void* const* d_in, const int* in_sizes, int n_in,
                              void* d_out, int out_size, void* d_ws, size_t ws_size,
                              hipStream_t stream) {
  (void)in_sizes; (void)n_in; (void)out_size; (void)ws_size;
  const float* ecg     = (const float*)d_in[0];
  const float* image   = (const float*)d_in[1];
  const float* ebank   = (const float*)d_in[2];
  const float* cbank   = (const float*)d_in[3];
  const float* gsel    = (const float*)d_in[4];
  const float* gw      = (const float*)d_in[5];
  const float* gb      = (const float*)d_in[6];
  const float* e_ln1_g = (const float*)d_in[7];
  const float* e_ln1_b = (const float*)d_in[8];
  const float* e_w1    = (const float*)d_in[9];
  const float* e_b1    = (const float*)d_in[10];
  const float* e_w2    = (const float*)d_in[11];
  const float* e_b2    = (const float*)d_in[12];
  const float* e_ln2_g = (const float*)d_in[13];
  const float* e_ln2_b = (const float*)d_in[14];
  const float* c_ln1_g = (const float*)d_in[15];
  const float* c_ln1_b = (const float*)d_in[16];
  const float* c_w1    = (const float*)d_in[17];
  const float* c_b1    = (const float*)d_in[18];
  const float* c_w2    = (const float*)d_in[19];
  const float* c_b2    = (const float*)d_in[20];
  const float* c_ln2_g = (const float*)d_in[21];
  const float* c_ln2_b = (const float*)d_in[22];

  float* out = (float*)d_out;
  float* ws = (float*)d_ws;

  constexpr size_t TXT = (size_t)8 * 2048 * 768;
  constexpr size_t IMG = (size_t)8 * 196 * 768;

  // ws layout: A | Bb | wbf | gatev | stats | gpart | twg
  float* A  = ws;
  float* Bb = A + TXT;
  unsigned short* wbf = (unsigned short*)(Bb + TXT);
  unsigned short* ew1b = wbf;
  unsigned short* ew2b = wbf + NW_;
  unsigned short* cw1b = wbf + 2 * NW_;
  unsigned short* cw2b = wbf + 3 * NW_;
  float* gatev = (float*)(wbf + 4 * (size_t)NW_);
  float2* stats = (float2*)(gatev + 8 * 768);
  float* gpart = (float*)(stats + 8 * 2048);
  float2* twg = (float2*)(gpart + 8 * 4 * 768);

  float2* FcT = (float2*)out;  // parked in d_out[0:3.6M floats] (dead before final LN)

  // image-path scratch inside A (consumed before transpose_g overwrites A)
  float* xi = A;                                   // f32 irfft+resid (IMG)
  unsigned short* xh_i = (unsigned short*)(A + IMG);  // bf16 LN1 out / resid
  unsigned short* h_i  = xh_i + IMG;               // bf16 GELU act
  unsigned short* y_ib = h_i + IMG;                // bf16 pre-LN2

  // text buffers
  unsigned short* xhat = (unsigned short*)A;           // bf16 LN1 / resid
  unsigned short* y_tb = (unsigned short*)A + TXT;     // bf16 pre-LN2
  unsigned short* h_t  = (unsigned short*)Bb;          // bf16 GELU act (xtT dead)

  // ---- one-time prep (fused) ----
  k_prep<<<PREP_WALL + PREP_FC + 2, 256, 0, stream>>>(
      e_w1, e_w2, c_w1, c_w2, wbf, (const float2*)ebank, FcT, twg);

  // ---- image path (produces gate) ----
  k_img_dft_f<<<dim3(11, 3, 8), 256, 0, stream>>>(image, (const float2*)cbank,
                                                  (float2*)Bb);
  k_gate_pool<<<dim3(8, 4), 256, 0, stream>>>((const float2*)Bb, (const float2*)gsel, gpart);
  k_gate_mm2<<<48, 256, 0, stream>>>(gpart, gw, gb, gatev);
  k_img_idft<<<dim3(14, 3, 8), 256, 0, stream>>>((const float2*)Bb, image, xi);
  k_layernorm_f2b<<<1568, 256, 0, stream>>>(xi, c_ln1_g, c_ln1_b, xh_i);
  k_gemm_mfma<0><<<dim3(6, 13), 256, 0, stream>>>(xh_i, cw1b, c_b1, nullptr, h_i, 1568);
  k_gemm_mfma<1><<<dim3(6, 13), 256, 0, stream>>>(h_i, cw2b, c_b2, xh_i, y_ib, 1568);
  k_layernorm_bf<<<1568, 256, 0, stream>>>(y_ib, c_ln2_g, c_ln2_b, out + TXT);

  // ---- ecg path ----
  k_transpose_g<<<dim3(24, 64, 8), 256, 0, stream>>>(ecg, A, 2048, 768);
  k_ecg_fft<<<8 * 768, 256, 0, stream>>>(A, FcT, gatev, twg, Bb);
  k_colstats<<<dim3(32, 8), 256, 0, stream>>>(Bb, stats);
  k_transpose_ln<<<dim3(64, 24, 8), 256, 0, stream>>>(Bb, stats, e_ln1_g, e_ln1_b, xhat);

  // ---- text FFN (bf16 MFMA, pipelined) ----
  k_gemm_mfma<0><<<dim3(6, 128), 256, 0, stream>>>(xhat, ew1b, e_b1, nullptr, h_t, 16384);
  k_gemm_mfma<1><<<dim3(6, 128), 256, 0, stream>>>(h_t, ew2b, e_b2, xhat, y_tb, 16384);
  k_layernorm_bf<<<16384, 256, 0, stream>>>(y_tb, e_ln2_g, e_ln2_b, out);
}

// Round 9
// 483.568 us; speedup vs baseline: 6.5613x; 1.0868x over previous
//
#include <hip/hip_runtime.h>
#include <math.h>

namespace {

constexpr int B_ = 8;
constexpr int S_ = 2048;
constexpr int D_ = 768;
constexpr int N_ = 196;     // image spatial
constexpr int NF_ = 99;     // image freq bins
constexpr int NFREQ_ = 257;
constexpr int NSEG_ = 9;
constexpr int NBINS_ = NFREQ_ * NSEG_;  // 2313
constexpr int NW_ = D_ * D_;            // 589824
constexpr float TWOPI_ = 6.28318530717958647692f;

using bf16x8 = __attribute__((ext_vector_type(8))) short;
using f32x4  = __attribute__((ext_vector_type(4))) float;

__device__ __forceinline__ int rev9(int x) { return (int)(__brev((unsigned)x) >> 23); }
__device__ __forceinline__ int padz(int i) { return i + (i >> 4); }

__device__ __forceinline__ unsigned short f2bf(float x) {
  unsigned u = __float_as_uint(x);
  u = (u + 0x7FFFu + ((u >> 16) & 1u)) >> 16;
  return (unsigned short)u;
}
__device__ __forceinline__ float bf2f(unsigned short h) {
  return __uint_as_float(((unsigned)h) << 16);
}

// exact GELU via Abramowitz-Stegun 7.1.26 erf (|eps| <= 1.5e-7)
__device__ __forceinline__ float gelu_f(float v) {
  const float x = fabsf(v) * 0.70710678118654752440f;
  const float t = 1.0f / fmaf(0.3275911f, x, 1.0f);
  float p = fmaf(fmaf(fmaf(fmaf(1.061405429f, t, -1.453152027f), t, 1.421413741f),
                      t, -0.284496736f), t, 0.254829592f);
  const float e = __expf(-x * x);
  const float er = 1.0f - p * t * e;
  return 0.5f * v * (1.0f + ((v < 0.f) ? -er : er));
}

__device__ __forceinline__ void gload16(const void* g, void* l) {
  __builtin_amdgcn_global_load_lds((const __attribute__((address_space(1))) void*)g,
                                   (__attribute__((address_space(3))) void*)l, 16, 0, 0);
}

// ---------------- batched transpose (B,R,C) -> (B,C,R) ----------------
__global__ __launch_bounds__(256) void k_transpose_g(const float* __restrict__ src,
                                                     float* __restrict__ dst,
                                                     int R, int C) {
  __shared__ float tile[32][33];
  const int b = blockIdx.z;
  const int c0 = blockIdx.x * 32;
  const int r0 = blockIdx.y * 32;
  const int tx = threadIdx.x & 31, ty = threadIdx.x >> 5;
  for (int i = ty; i < 32; i += 8)
    tile[i][tx] = src[((size_t)b * R + r0 + i) * C + c0 + tx];
  __syncthreads();
  for (int i = ty; i < 32; i += 8)
    dst[((size_t)b * C + c0 + i) * R + r0 + tx] = tile[tx][i];
}

// ---- fused prep: weight bf16 conv (4 mats) + filter bank + twiddles ----
constexpr int PREP_W = (NW_ + 255) / 256;
constexpr int PREP_WALL = 4 * PREP_W;
constexpr int PREP_FC = (NBINS_ * D_ + 255) / 256;
__global__ __launch_bounds__(256) void k_prep(
    const float* __restrict__ w0, const float* __restrict__ w1,
    const float* __restrict__ w2, const float* __restrict__ w3,
    unsigned short* __restrict__ wbf, const float2* __restrict__ e2,
    float2* __restrict__ FcT, float2* __restrict__ twg) {
  const int bid = blockIdx.x;
  if (bid < PREP_WALL) {
    const int m = bid / PREP_W;
    const int i = (bid - m * PREP_W) * 256 + threadIdx.x;
    if (i >= NW_) return;
    const float* src = (m == 0) ? w0 : (m == 1) ? w1 : (m == 2) ? w2 : w3;
    wbf[(size_t)m * NW_ + i] = f2bf(src[i]);
  } else if (bid < PREP_WALL + PREP_FC) {
    const int o = (bid - PREP_WALL) * 256 + threadIdx.x;
    if (o >= NBINS_ * D_) return;
    const int d = o / NBINS_;
    const int r = o - d * NBINS_;
    const int f = r / NFREQ_;
    const int k = r - f * NFREQ_;
    const int s = k * 9 + f;
    const float2 a = e2[(size_t)s * D_ + d];
    const float2 b = e2[(size_t)(NBINS_ + s) * D_ + d];
    FcT[o] = make_float2(-(a.x + b.x), -(a.y + b.y));
  } else {
    const int i = (bid - PREP_WALL - PREP_FC) * 256 + threadIdx.x;
    if (i >= 511) return;
    const int v = i + 1;
    const int h = 1 << (31 - __clz(v));
    const int j = v - h;
    float sn, cs;
    sincosf((float)j * ((TWOPI_ * 0.5f) / (float)h), &sn, &cs);
    twg[i] = make_float2(cs, sn);
  }
}

// ---- image forward DFT + filter + gate partials ----
__global__ __launch_bounds__(256) void k_img_dft_f(
    const float* __restrict__ image, const float2* __restrict__ bank2,
    const float2* __restrict__ gsel2, float2* __restrict__ imgF,
    float* __restrict__ part) {
  const int fg = blockIdx.x;
  const int f0 = fg * 9;
  const int d = blockIdx.y * 256 + threadIdx.x;
  const int b = blockIdx.z;
  __shared__ float2 tws[9 * N_];
  for (int idx = threadIdx.x; idx < 9 * N_; idx += 256) {
    const int fi = idx / N_;
    const int t = idx - fi * N_;
    const int r = ((f0 + fi) * t) % N_;
    float sn, cs;
    sincosf(TWOPI_ * (float)r / (float)N_, &sn, &cs);
    tws[idx] = make_float2(cs, sn);
  }
  __syncthreads();
  float re[9] = {}, im[9] = {};
  const float* ip = image + (size_t)b * N_ * D_ + d;
  for (int t = 0; t < N_; ++t) {
    const float v = ip[(size_t)t * D_];
#pragma unroll
    for (int fi = 0; fi < 9; ++fi) {
      const float2 w = tws[fi * N_ + t];
      re[fi] = fmaf(v, w.x, re[fi]);
      im[fi] = fmaf(-v, w.y, im[fi]);
    }
  }
  const float sc = 1.0f / (196.0f * 99.0f);
  float gp = 0.f;
#pragma unroll
  for (int fi = 0; fi < 9; ++fi) {
    const int f = f0 + fi;
    const float pr = (re[fi] * re[fi] - im[fi] * im[fi]) * sc;
    const float pi2 = (2.f * re[fi] * im[fi]) * sc;
    const size_t fd = (size_t)f * D_ + d;
    const float2 c0 = bank2[fd];
    const float2 c1 = bank2[(size_t)NF_ * D_ + fd];
    const float fcr = -(c0.x + c1.x), fci = -(c0.y + c1.y);
    const float zr = pr * fcr - pi2 * fci;
    const float zi = pr * fci + pi2 * fcr;
    imgF[(size_t)(b * NF_ + f) * D_ + d] = make_float2(zr, zi);
    const float2 gw = gsel2[fd];
    gp += zr * gw.x - zi * gw.y;
  }
  part[((size_t)b * 11 + fg) * D_ + d] = gp;
}

// ---- gate matvec, folds 11 partials: gate[b][d0..d0+16) ----
__global__ __launch_bounds__(256) void k_gate_mm2(const float* __restrict__ part,
                                                  const float* __restrict__ W,
                                                  const float* __restrict__ bias,
                                                  float* __restrict__ gate) {
  __shared__ float row[8][D_];
  __shared__ float red[16][16][8];
  const int tid = threadIdx.x;
  const int d0 = blockIdx.x * 16;
  for (int i = tid; i < 8 * D_; i += 256) {
    const int b = i / D_, e = i - b * D_;
    float s = 0.f;
    for (int p = 0; p < 11; ++p) s += part[((size_t)b * 11 + p) * D_ + e];
    row[b][e] = s * (1.0f / 99.0f);
  }
  __syncthreads();
  const int dl = tid >> 4;
  const int ec = tid & 15;
  const float* w = W + (size_t)(d0 + dl) * D_ + ec * 48;
  float acc[8] = {};
  for (int e = 0; e < 48; e += 4) {
    const float4 wv = *reinterpret_cast<const float4*>(w + e);
    const int eg = ec * 48 + e;
#pragma unroll
    for (int b = 0; b < 8; ++b) {
      acc[b] = fmaf(row[b][eg], wv.x, acc[b]);
      acc[b] = fmaf(row[b][eg + 1], wv.y, acc[b]);
      acc[b] = fmaf(row[b][eg + 2], wv.z, acc[b]);
      acc[b] = fmaf(row[b][eg + 3], wv.w, acc[b]);
    }
  }
#pragma unroll
  for (int b = 0; b < 8; ++b) red[dl][ec][b] = acc[b];
  __syncthreads();
  if (tid < 128) {
    const int dl2 = tid >> 3, b = tid & 7;
    float s = bias[d0 + dl2];
    for (int c = 0; c < 16; ++c) s += red[dl2][c][b];
    gate[b * D_ + d0 + dl2] = s;
  }
}

// ---- image inverse DFT (ortho) + residual ----
__global__ __launch_bounds__(256) void k_img_idft(
    const float2* __restrict__ imgF, const float* __restrict__ image,
    float* __restrict__ xi) {
  const int t0 = blockIdx.x * 14;
  const int d = blockIdx.y * 256 + threadIdx.x;
  const int b = blockIdx.z;
  __shared__ float2 tws[14 * NF_];
  for (int idx = threadIdx.x; idx < 14 * NF_; idx += 256) {
    const int ti = idx / NF_;
    const int f = idx - ti * NF_;
    const int r = ((t0 + ti) * f) % N_;
    float sn, cs;
    sincosf(TWOPI_ * (float)r / (float)N_, &sn, &cs);
    tws[idx] = make_float2(cs, sn);
  }
  __syncthreads();
  const float2* zp = imgF + (size_t)b * NF_ * D_ + d;
  const float2 z0 = zp[0];
  const float2 zny = zp[(size_t)(NF_ - 1) * D_];
  float acc[14];
#pragma unroll
  for (int ti = 0; ti < 14; ++ti)
    acc[ti] = z0.x + (((t0 + ti) & 1) ? -zny.x : zny.x);
  for (int f = 1; f < NF_ - 1; ++f) {
    const float2 z = zp[(size_t)f * D_];
#pragma unroll
    for (int ti = 0; ti < 14; ++ti) {
      const float2 w = tws[ti * NF_ + f];
      acc[ti] += 2.f * (z.x * w.x - z.y * w.y);
    }
  }
#pragma unroll
  for (int ti = 0; ti < 14; ++ti) {
    const size_t idx = (size_t)(b * N_ + t0 + ti) * D_ + d;
    xi[idx] = acc[ti] * (1.0f / 14.0f) + image[idx];
  }
}

// ---------------- LayerNorm f32 in -> bf16 out ----------------
__global__ __launch_bounds__(256) void k_layernorm_f2b(const float* __restrict__ x,
                                                       const float* __restrict__ g,
                                                       const float* __restrict__ b,
                                                       unsigned short* __restrict__ out) {
  const int row = blockIdx.x;
  const int tid = threadIdx.x;
  const float* xr = x + (size_t)row * D_;
  const float v0 = xr[tid], v1 = xr[tid + 256], v2 = xr[tid + 512];
  float s = v0 + v1 + v2;
  float q = v0 * v0 + v1 * v1 + v2 * v2;
  __shared__ float red[8];
  for (int off = 32; off > 0; off >>= 1) {
    s += __shfl_down(s, off);
    q += __shfl_down(q, off);
  }
  if ((tid & 63) == 0) { red[tid >> 6] = s; red[4 + (tid >> 6)] = q; }
  __syncthreads();
  s = red[0] + red[1] + red[2] + red[3];
  q = red[4] + red[5] + red[6] + red[7];
  const float mean = s * (1.0f / 768.0f);
  const float var = q * (1.0f / 768.0f) - mean * mean;
  const float inv = rsqrtf(var + 1e-5f);
  unsigned short* orow = out + (size_t)row * D_;
  orow[tid]       = f2bf((v0 - mean) * inv * g[tid]       + b[tid]);
  orow[tid + 256] = f2bf((v1 - mean) * inv * g[tid + 256] + b[tid + 256]);
  orow[tid + 512] = f2bf((v2 - mean) * inv * g[tid + 512] + b[tid + 512]);
}

// ================= ecg fused FFT pipeline (math frozen; bf16 output) ===========
template <int SS, int DIR>
__device__ __forceinline__ void dblpass(float2* z, int q, float2 tw1, float2 tw2) {
  asm volatile("s_waitcnt lgkmcnt(0)" ::: "memory");
  const int h = 1 << SS;
  const int j = q & (h - 1);
  const int base = ((q >> SS) << (SS + 2)) | j;
  const int e0 = padz(base), e1 = padz(base + h);
  const int e2 = padz(base + 2 * h), e3 = padz(base + 3 * h);
  const float2 x0 = z[e0], x1 = z[e1], x2 = z[e2], x3 = z[e3];
  const float sg = (DIR < 0) ? -1.f : 1.f;
  const float w1c = tw1.x, w1s = sg * tw1.y;
  const float w2c = tw2.x, w2s = sg * tw2.y;
  const float t1r = x1.x * w1c - x1.y * w1s, t1i = x1.x * w1s + x1.y * w1c;
  const float t3r = x3.x * w1c - x3.y * w1s, t3i = x3.x * w1s + x3.y * w1c;
  const float a0r = x0.x + t1r, a0i = x0.y + t1i;
  const float a1r = x0.x - t1r, a1i = x0.y - t1i;
  const float a2r = x2.x + t3r, a2i = x2.y + t3i;
  const float a3r = x2.x - t3r, a3i = x2.y - t3i;
  const float u2r = a2r * w2c - a2i * w2s, u2i = a2r * w2s + a2i * w2c;
  const float v3r = a3r * w2c - a3i * w2s, v3i = a3r * w2s + a3i * w2c;
  const float u3r = -sg * v3i, u3i = sg * v3r;
  z[e0] = make_float2(a0r + u2r, a0i + u2i);
  z[e2] = make_float2(a0r - u2r, a0i - u2i);
  z[e1] = make_float2(a1r + u3r, a1i + u3i);
  z[e3] = make_float2(a1r - u3r, a1i - u3i);
}

template <int DIR>
__device__ __forceinline__ void stage8(float2* z, float2 t8, int t) {
  const float wc = t8.x, ws = (DIR < 0) ? -t8.y : t8.y;
  const int a0 = padz(t), a1 = padz(t + 256);
  const float2 x = z[a0], y = z[a1];
  const float tr = y.x * wc - y.y * ws, ti = y.x * ws + y.y * wc;
  z[a0] = make_float2(x.x + tr, x.y + ti);
  z[a1] = make_float2(x.x - tr, x.y - ti);
}

template <int FA, int FB>
__device__ __forceinline__ void filt_pack(const float2* z, int k, float g,
                                          float2 cA, float2 cB,
                                          float2& Ck, float2& Cm) {
  const int q = (512 - k) & 511;
  const float2 Zk = z[padz(k)], Zq = z[padz(q)];
  const float sc = 0.5f / 256.f;
  const float ar = (Zk.x + Zq.x) * sc, ai = (Zk.y - Zq.y) * sc;
  float yar, yai, ybr = 0.f, ybi = 0.f;
  {
    const float pr = (ar * ar - ai * ai) * (1.f / 2313.f);
    const float pi = (2.f * ar * ai) * (1.f / 2313.f);
    yar = (pr * cA.x - pi * cA.y) * g;
    yai = (pr * cA.y + pi * cA.x) * g;
  }
  if (FB >= 0) {
    const float br = (Zk.y + Zq.y) * sc, bi = (Zq.x - Zk.x) * sc;
    const float pr = (br * br - bi * bi) * (1.f / 2313.f);
    const float pi = (2.f * br * bi) * (1.f / 2313.f);
    ybr = (pr * cB.x - pi * cB.y) * g;
    ybi = (pr * cB.y + pi * cB.x) * g;
  }
  if (k == 0 || k == 256) {
    Ck = make_float2(yar, ybr);
    Cm = Ck;
  } else {
    Ck = make_float2(yar - ybi, yai + ybr);
    Cm = make_float2(yar + ybi, ybr - yai);
  }
}

template <int FA0, int FB0, int FA1, int FB1, bool DUAL>
__device__ __forceinline__ void ecg_super(int tid, float g, const float2* __restrict__ fc,
                                          const float (&s)[8], const float2 (&rt)[4][2],
                                          float2 t8, float2* zA, float2* zB, float* accr) {
  const float c0 = t8.x;
  const float wlo = 0.5f - 0.5f * c0;
  const float whi = 0.5f + 0.5f * c0;
  const float2 cA0 = fc[FA0 * 257 + tid];
  float2 cB0 = make_float2(0.f, 0.f), cA1 = cB0, cB1 = cB0;
  if (FB0 >= 0) cB0 = fc[FB0 * 257 + tid];
  if (DUAL) { cA1 = fc[FA1 * 257 + tid]; cB1 = fc[FB1 * 257 + tid]; }
  float2 nA0 = make_float2(0.f, 0.f), nB0 = nA0, nA1 = nA0, nB1 = nA0;
  if (tid == 0) {
    nA0 = fc[FA0 * 257 + 256];
    if (FB0 >= 0) nB0 = fc[FB0 * 257 + 256];
    if (DUAL) { nA1 = fc[FA1 * 257 + 256]; nB1 = fc[FB1 * 257 + 256]; }
  }
  __syncthreads();
  {
    constexpr int iAlo = (FA0 > 0) ? FA0 - 1 : 0;
    constexpr int iAhi = (FA0 < 8) ? FA0 : 0;
    constexpr int iBlo = (FB0 > 0) ? FB0 - 1 : 0;
    constexpr int iBhi = (FB0 >= 0 && FB0 < 8) ? FB0 : 0;
    const int rlo = padz(rev9(tid)), rhi = padz(rev9(tid + 256));
    const float aLo = (FA0 == 0) ? 0.f : s[iAlo] * wlo;
    const float aHi = (FA0 == 8) ? 0.f : s[iAhi] * whi;
    const float bLo = (FB0 <= 0) ? 0.f : s[iBlo] * wlo;
    const float bHi = (FB0 < 0 || FB0 == 8) ? 0.f : s[iBhi] * whi;
    zA[rlo] = make_float2(aLo, bLo);
    zA[rhi] = make_float2(aHi, bHi);
    if (DUAL) {
      constexpr int jAlo = (FA1 > 0) ? FA1 - 1 : 0;
      constexpr int jAhi = (FA1 < 8) ? FA1 : 0;
      constexpr int jBlo = (FB1 > 0) ? FB1 - 1 : 0;
      constexpr int jBhi = (FB1 < 8) ? FB1 : 0;
      const float eLo = (FA1 == 0) ? 0.f : s[jAlo] * wlo;
      const float eHi = (FA1 == 8) ? 0.f : s[jAhi] * whi;
      const float fLo = (FB1 == 0) ? 0.f : s[jBlo] * wlo;
      const float fHi = (FB1 == 8) ? 0.f : s[jBhi] * whi;
      zB[rlo] = make_float2(eLo, fLo);
      zB[rhi] = make_float2(eHi, fHi);
    }
  }
  __syncthreads();
  if (DUAL || tid < 128) {
    float2* zz = (tid < 128) ? zA : zB;
    const int q = tid & 127;
    dblpass<0, -1>(zz, q, rt[0][0], rt[0][1]);
    dblpass<2, -1>(zz, q, rt[1][0], rt[1][1]);
    dblpass<4, -1>(zz, q, rt[2][0], rt[2][1]);
    dblpass<6, -1>(zz, q, rt[3][0], rt[3][1]);
  }
  __syncthreads();
  stage8<-1>(zA, t8, tid);
  if (DUAL) stage8<-1>(zB, t8, tid);
  __syncthreads();
  float2 CAk, CAm, CBk, CBm;
  filt_pack<FA0, FB0>(zA, tid, g, cA0, cB0, CAk, CAm);
  float2 CAn, CBn, dum;
  if (tid == 0) filt_pack<FA0, FB0>(zA, 256, g, nA0, nB0, CAn, dum);
  if (DUAL) {
    filt_pack<FA1, FB1>(zB, tid, g, cA1, cB1, CBk, CBm);
    if (tid == 0) filt_pack<FA1, FB1>(zB, 256, g, nA1, nB1, CBn, dum);
  }
  __syncthreads();
  {
    const int rk = padz(rev9(tid));
    zA[rk] = CAk;
    if (DUAL) zB[rk] = CBk;
    if (tid == 0) {
      zA[padz(1)] = CAn;
      if (DUAL) zB[padz(1)] = CBn;
    } else {
      const int rm = padz(rev9(512 - tid));
      zA[rm] = CAm;
      if (DUAL) zB[rm] = CBm;
    }
  }
  __syncthreads();
  if (DUAL || tid < 128) {
    float2* zz = (tid < 128) ? zA : zB;
    const int q = tid & 127;
    dblpass<0, 1>(zz, q, rt[0][0], rt[0][1]);
    dblpass<2, 1>(zz, q, rt[1][0], rt[1][1]);
    dblpass<4, 1>(zz, q, rt[2][0], rt[2][1]);
    dblpass<6, 1>(zz, q, rt[3][0], rt[3][1]);
  }
  __syncthreads();
  stage8<1>(zA, t8, tid);
  if (DUAL) stage8<1>(zB, t8, tid);
  {
    const float2 vLo = zA[padz(tid)], vHi = zA[padz(tid + 256)];
    accr[FA0] += 0.5f * wlo * vLo.x;
    accr[FA0 + 1] += 0.5f * whi * vHi.x;
    if (FB0 >= 0) {
      accr[FB0] += 0.5f * wlo * vLo.y;
      accr[FB0 + 1] += 0.5f * whi * vHi.y;
    }
    if (DUAL) {
      const float2 uLo = zB[padz(tid)], uHi = zB[padz(tid + 256)];
      accr[FA1] += 0.5f * wlo * uLo.x;
      accr[FA1 + 1] += 0.5f * whi * uHi.x;
      accr[FB1] += 0.5f * wlo * uLo.y;
      accr[FB1 + 1] += 0.5f * whi * uHi.y;
    }
  }
}

__global__ __launch_bounds__(256) void k_ecg_fft(
    const float* __restrict__ ecgT, const float2* __restrict__ FcT,
    const float* __restrict__ gate, const float2* __restrict__ twg,
    unsigned short* __restrict__ xtT) {
  const int bd = blockIdx.x;
  const int d = bd % D_;
  const int tid = threadIdx.x;

  __shared__ float2 zA[544], zB[544];

  float s[8];
  const float* src = ecgT + (size_t)bd * S_;
#pragma unroll
  for (int k = 0; k < 8; ++k) s[k] = src[k * 256 + tid];

  float2 rt[4][2];
  const int q = tid & 127;
  rt[0][0] = make_float2(1.f, 0.f);
  rt[0][1] = make_float2(0.f, 1.f);
  rt[1][0] = twg[3 + (q & 3)];
  rt[1][1] = twg[7 + (q & 3)];
  rt[2][0] = twg[15 + (q & 15)];
  rt[2][1] = twg[31 + (q & 15)];
  rt[3][0] = twg[63 + (q & 63)];
  rt[3][1] = twg[127 + (q & 63)];
  const float2 t8 = twg[255 + tid];

  const float g = gate[bd];
  const float2* fc = FcT + (size_t)d * NBINS_;
  float accr[10];
#pragma unroll
  for (int i = 0; i < 10; ++i) accr[i] = 0.f;

  ecg_super<0, 8, 1, 2, true>(tid, g, fc, s, rt, t8, zA, zB, accr);
  ecg_super<3, 4, 5, 6, true>(tid, g, fc, s, rt, t8, zA, zB, accr);
  ecg_super<7, -1, 0, 0, false>(tid, g, fc, s, rt, t8, zA, zB, accr);

  const float c0 = t8.x;
  const float rinv = 1.0f / (0.5f + 0.5f * c0 * c0);
  unsigned short* dst = xtT + (size_t)bd * S_;
#pragma unroll
  for (int i2 = 0; i2 < 8; ++i2)
    dst[i2 * 256 + tid] = f2bf(accr[i2 + 1] * rinv + s[i2]);
}

// ---- per-(b,t) LN stats over d, reading bf16 xtT[b][d][t] as uint pairs ----
__global__ __launch_bounds__(256) void k_colstats_bf(const unsigned short* __restrict__ xtT,
                                                     float2* __restrict__ stats) {
  const int b = blockIdx.y;
  const int t0 = blockIdx.x * 128;
  const int tx = threadIdx.x & 63;
  const int ty = threadIdx.x >> 6;
  float s0 = 0.f, q0 = 0.f, s1 = 0.f, q1 = 0.f;
  const unsigned int* base = (const unsigned int*)(xtT + (size_t)b * D_ * S_);
  for (int dd = ty; dd < D_; dd += 4) {
    const unsigned int u = base[(size_t)dd * (S_ / 2) + (t0 >> 1) + tx];
    const float v0 = bf2f((unsigned short)(u & 0xffffu));
    const float v1 = bf2f((unsigned short)(u >> 16));
    s0 += v0; q0 = fmaf(v0, v0, q0);
    s1 += v1; q1 = fmaf(v1, v1, q1);
  }
  __shared__ float sh[4][64][4];
  sh[ty][tx][0] = s0; sh[ty][tx][1] = q0; sh[ty][tx][2] = s1; sh[ty][tx][3] = q1;
  __syncthreads();
  if (ty == 0) {
    s0 = sh[0][tx][0] + sh[1][tx][0] + sh[2][tx][0] + sh[3][tx][0];
    q0 = sh[0][tx][1] + sh[1][tx][1] + sh[2][tx][1] + sh[3][tx][1];
    s1 = sh[0][tx][2] + sh[1][tx][2] + sh[2][tx][2] + sh[3][tx][2];
    q1 = sh[0][tx][3] + sh[1][tx][3] + sh[2][tx][3] + sh[3][tx][3];
    stats[(size_t)b * S_ + t0 + 2 * tx]     = make_float2(s0, q0);
    stats[(size_t)b * S_ + t0 + 2 * tx + 1] = make_float2(s1, q1);
  }
}

// ---- transpose + LN apply, bf16 in -> bf16 out ----
__global__ __launch_bounds__(256) void k_transpose_ln(
    const unsigned short* __restrict__ xtT, const float2* __restrict__ stats,
    const float* __restrict__ g, const float* __restrict__ bia,
    unsigned short* __restrict__ xhat) {
  __shared__ float tile[32][33];
  const int b = blockIdx.z;
  const int t0 = blockIdx.x * 32;
  const int d0 = blockIdx.y * 32;
  const int tx = threadIdx.x & 31, ty = threadIdx.x >> 5;
  for (int i = ty; i < 32; i += 8)
    tile[i][tx] = bf2f(xtT[((size_t)b * D_ + d0 + i) * S_ + t0 + tx]);
  __syncthreads();
  const float gv = g[d0 + tx], bv = bia[d0 + tx];
  for (int i = ty; i < 32; i += 8) {
    const float2 st = stats[(size_t)b * S_ + t0 + i];
    const float mean = st.x * (1.0f / 768.0f);
    const float var = st.y * (1.0f / 768.0f) - mean * mean;
    const float inv = rsqrtf(var + 1e-5f);
    xhat[((size_t)b * S_ + t0 + i) * D_ + d0 + tx] =
        f2bf((tile[tx][i] - mean) * inv * gv + bv);
  }
}

// ---------------- LayerNorm over D=768, bf16 in -> f32 out ----------------
__global__ __launch_bounds__(256) void k_layernorm_bf(const unsigned short* __restrict__ x,
                                                      const float* __restrict__ g,
                                                      const float* __restrict__ b,
                                                      float* __restrict__ out) {
  const int row = blockIdx.x;
  const int tid = threadIdx.x;
  const unsigned short* xr = x + (size_t)row * D_;
  const float v0 = bf2f(xr[tid]), v1 = bf2f(xr[tid + 256]), v2 = bf2f(xr[tid + 512]);
  float s = v0 + v1 + v2;
  float q = v0 * v0 + v1 * v1 + v2 * v2;
  __shared__ float red[8];
  for (int off = 32; off > 0; off >>= 1) {
    s += __shfl_down(s, off);
    q += __shfl_down(q, off);
  }
  if ((tid & 63) == 0) { red[tid >> 6] = s; red[4 + (tid >> 6)] = q; }
  __syncthreads();
  s = red[0] + red[1] + red[2] + red[3];
  q = red[4] + red[5] + red[6] + red[7];
  const float mean = s * (1.0f / 768.0f);
  const float var = q * (1.0f / 768.0f) - mean * mean;
  const float inv = rsqrtf(var + 1e-5f);
  float* orow = out + (size_t)row * D_;
  orow[tid]       = (v0 - mean) * inv * g[tid]       + b[tid];
  orow[tid + 256] = (v1 - mean) * inv * g[tid + 256] + b[tid + 256];
  orow[tid + 512] = (v2 - mean) * inv * g[tid + 512] + b[tid + 512];
}

// ---------- MFMA GEMM, double-buffered pipeline ----------
// MODE 0: exact GELU -> bf16 ; MODE 1: +resid(bf16) -> bf16
template <int MODE, bool SWZ>
__global__ __launch_bounds__(256) void k_gemm_mfma(
    const unsigned short* __restrict__ Abf, const unsigned short* __restrict__ Wbf,
    const float* __restrict__ bias, const unsigned short* __restrict__ resid,
    unsigned short* __restrict__ outb, int M) {
  __shared__ unsigned short Asm[2][128 * 64];
  __shared__ unsigned short Bsm[2][128 * 64];
  const int tid = threadIdx.x;
  const int lane = tid & 63, wid = tid >> 6;
  const int wr = wid >> 1, wc = wid & 1;
  int bx = blockIdx.x, by = blockIdx.y;
  if (SWZ) {  // bijective XCD swizzle (nwg % 8 == 0 for the text GEMMs)
    const int nwg = gridDim.x * gridDim.y;
    const int bid = by * gridDim.x + bx;
    const int nbid = (bid % 8) * (nwg >> 3) + (bid >> 3);
    bx = nbid % gridDim.x;
    by = nbid / gridDim.x;
  }
  const int n0 = bx * 128, m0 = by * 128;

  auto STAGE = [&](int buf, int kt) {
    const int k0 = kt * 64;
#pragma unroll
    for (int i = 0; i < 4; ++i) {
      const int c = tid + 256 * i;
      const int row = c >> 3, sl = c & 7;
      const int gsl = sl ^ (row & 7);
      gload16(Abf + (size_t)(m0 + row) * 768 + k0 + gsl * 8, &Asm[buf][c * 8]);
      gload16(Wbf + (size_t)(n0 + row) * 768 + k0 + gsl * 8, &Bsm[buf][c * 8]);
    }
  };

  f32x4 acc[4][4] = {};
  STAGE(0, 0);
  for (int kt = 0; kt < 12; ++kt) {
    const int cur = kt & 1;
    if (kt < 11) {
      STAGE(cur ^ 1, kt + 1);
      asm volatile("s_waitcnt vmcnt(8)" ::: "memory");
    } else {
      asm volatile("s_waitcnt vmcnt(0)" ::: "memory");
    }
    __builtin_amdgcn_sched_barrier(0);
    __builtin_amdgcn_s_barrier();
#pragma unroll
    for (int ks = 0; ks < 2; ++ks) {
      bf16x8 af[4], bfv[4];
#pragma unroll
      for (int mi = 0; mi < 4; ++mi) {
        const int row = wr * 64 + mi * 16 + (lane & 15);
        const int sl = (ks * 4 + (lane >> 4)) ^ (row & 7);
        af[mi] = *(const bf16x8*)((const char*)Asm[cur] + row * 128 + sl * 16);
      }
#pragma unroll
      for (int ni = 0; ni < 4; ++ni) {
        const int row = wc * 64 + ni * 16 + (lane & 15);
        const int sl = (ks * 4 + (lane >> 4)) ^ (row & 7);
        bfv[ni] = *(const bf16x8*)((const char*)Bsm[cur] + row * 128 + sl * 16);
      }
#pragma unroll
      for (int mi = 0; mi < 4; ++mi)
#pragma unroll
        for (int ni = 0; ni < 4; ++ni)
          acc[mi][ni] = __builtin_amdgcn_mfma_f32_16x16x32_bf16(af[mi], bfv[ni],
                                                                acc[mi][ni], 0, 0, 0);
    }
    __builtin_amdgcn_sched_barrier(0);
    __builtin_amdgcn_s_barrier();
  }
#pragma unroll
  for (int mi = 0; mi < 4; ++mi) {
#pragma unroll
    for (int ni = 0; ni < 4; ++ni) {
      const int col = n0 + wc * 64 + ni * 16 + (lane & 15);
#pragma unroll
      for (int e = 0; e < 4; ++e) {
        const int row = m0 + wr * 64 + mi * 16 + (lane >> 4) * 4 + e;
        if (row >= M) continue;
        float v = acc[mi][ni][e] + bias[col];
        if (MODE == 0) {
          v = gelu_f(v);
        } else {
          v += bf2f(resid[(size_t)row * 768 + col]);
        }
        outb[(size_t)row * 768 + col] = f2bf(v);
      }
    }
  }
}

}  // namespace

extern "C" void kernel_launch(void* const* d_in, const int* in_sizes, int n_in,
                              void* d_out, int out_size, void* d_ws, size_t ws_size,
                              hipStream_t stream) {
  (void)in_sizes; (void)n_in; (void)out_size; (void)ws_size;
  const float* ecg     = (const float*)d_in[0];
  const float* image   = (const float*)d_in[1];
  const float* ebank   = (const float*)d_in[2];
  const float* cbank   = (const float*)d_in[3];
  const float* gsel    = (const float*)d_in[4];
  const float* gw      = (const float*)d_in[5];
  const float* gb      = (const float*)d_in[6];
  const float* e_ln1_g = (const float*)d_in[7];
  const float* e_ln1_b = (const float*)d_in[8];
  const float* e_w1    = (const float*)d_in[9];
  const float* e_b1    = (const float*)d_in[10];
  const float* e_w2    = (const float*)d_in[11];
  const float* e_b2    = (const float*)d_in[12];
  const float* e_ln2_g = (const float*)d_in[13];
  const float* e_ln2_b = (const float*)d_in[14];
  const float* c_ln1_g = (const float*)d_in[15];
  const float* c_ln1_b = (const float*)d_in[16];
  const float* c_w1    = (const float*)d_in[17];
  const float* c_b1    = (const float*)d_in[18];
  const float* c_w2    = (const float*)d_in[19];
  const float* c_b2    = (const float*)d_in[20];
  const float* c_ln2_g = (const float*)d_in[21];
  const float* c_ln2_b = (const float*)d_in[22];

  float* out = (float*)d_out;
  float* ws = (float*)d_ws;

  constexpr size_t TXT = (size_t)8 * 2048 * 768;
  constexpr size_t IMG = (size_t)8 * 196 * 768;

  // ws layout: A | Bb | wbf | gatev | stats | gpart | twg
  float* A  = ws;
  float* Bb = A + TXT;
  unsigned short* wbf = (unsigned short*)(Bb + TXT);
  unsigned short* ew1b = wbf;
  unsigned short* ew2b = wbf + NW_;
  unsigned short* cw1b = wbf + 2 * NW_;
  unsigned short* cw2b = wbf + 3 * NW_;
  float* gatev = (float*)(wbf + 4 * (size_t)NW_);
  float2* stats = (float2*)(gatev + 8 * 768);
  float* gpart = (float*)(stats + 8 * 2048);   // 8*11*768 floats
  float2* twg = (float2*)(gpart + 8 * 11 * 768);

  float2* FcT = (float2*)out;  // parked in d_out (dead before final LN)

  // image-path scratch inside A
  float* xi = A;
  unsigned short* xh_i = (unsigned short*)(A + IMG);
  unsigned short* h_i  = xh_i + IMG;
  unsigned short* y_ib = h_i + IMG;

  // text buffers
  unsigned short* xhat = (unsigned short*)A;           // bf16 LN1 / resid
  unsigned short* y_tb = (unsigned short*)A + TXT;     // bf16 pre-LN2
  unsigned short* xtT  = (unsigned short*)Bb;          // bf16 ecg_fft out [b][d][t]
  unsigned short* h_t  = (unsigned short*)Bb;          // bf16 GELU act (after xtT dead)

  // ---- one-time prep (fused) ----
  k_prep<<<PREP_WALL + PREP_FC + 2, 256, 0, stream>>>(
      e_w1, e_w2, c_w1, c_w2, wbf, (const float2*)ebank, FcT, twg);

  // ---- image path (produces gate) ----
  k_img_dft_f<<<dim3(11, 3, 8), 256, 0, stream>>>(image, (const float2*)cbank,
                                                  (const float2*)gsel,
                                                  (float2*)(A + 2 * IMG), gpart);
  k_gate_mm2<<<48, 256, 0, stream>>>(gpart, gw, gb, gatev);
  k_img_idft<<<dim3(14, 3, 8), 256, 0, stream>>>((const float2*)(A + 2 * IMG), image, xi);
  k_layernorm_f2b<<<1568, 256, 0, stream>>>(xi, c_ln1_g, c_ln1_b, xh_i);
  k_gemm_mfma<0, false><<<dim3(6, 13), 256, 0, stream>>>(xh_i, cw1b, c_b1, nullptr, h_i, 1568);
  k_gemm_mfma<1, false><<<dim3(6, 13), 256, 0, stream>>>(h_i, cw2b, c_b2, xh_i, y_ib, 1568);
  k_layernorm_bf<<<1568, 256, 0, stream>>>(y_ib, c_ln2_g, c_ln2_b, out + TXT);

  // ---- ecg path ----
  k_transpose_g<<<dim3(24, 64, 8), 256, 0, stream>>>(ecg, A, 2048, 768);
  k_ecg_fft<<<8 * 768, 256, 0, stream>>>(A, FcT, gatev, twg, xtT);
  k_colstats_bf<<<dim3(16, 8), 256, 0, stream>>>(xtT, stats);
  k_transpose_ln<<<dim3(64, 24, 8), 256, 0, stream>>>(xtT, stats, e_ln1_g, e_ln1_b, xhat);

  // ---- text FFN (bf16 MFMA, pipelined, XCD-swizzled) ----
  k_gemm_mfma<0, true><<<dim3(6, 128), 256, 0, stream>>>(xhat, ew1b, e_b1, nullptr, h_t, 16384);
  k_gemm_mfma<1, true><<<dim3(6, 128), 256, 0, stream>>>(h_t, ew2b, e_b2, xhat, y_tb, 16384);
  k_layernorm_bf<<<16384, 256, 0, stream>>>(y_tb, e_ln2_g, e_ln2_b, out);
}

// Round 10
// 474.568 us; speedup vs baseline: 6.6857x; 1.0190x over previous
//
#include <hip/hip_runtime.h>
#include <math.h>

namespace {

constexpr int B_ = 8;
constexpr int S_ = 2048;
constexpr int D_ = 768;
constexpr int N_ = 196;     // image spatial
constexpr int NF_ = 99;     // image freq bins
constexpr int NFREQ_ = 257;
constexpr int NSEG_ = 9;
constexpr int NBINS_ = NFREQ_ * NSEG_;  // 2313
constexpr int NW_ = D_ * D_;            // 589824
constexpr float TWOPI_ = 6.28318530717958647692f;

using bf16x8 = __attribute__((ext_vector_type(8))) short;
using f32x4  = __attribute__((ext_vector_type(4))) float;

__device__ __forceinline__ int rev9(int x) { return (int)(__brev((unsigned)x) >> 23); }
__device__ __forceinline__ int padz(int i) { return i + (i >> 4); }

__device__ __forceinline__ unsigned short f2bf(float x) {
  unsigned u = __float_as_uint(x);
  u = (u + 0x7FFFu + ((u >> 16) & 1u)) >> 16;
  return (unsigned short)u;
}
__device__ __forceinline__ float bf2f(unsigned short h) {
  return __uint_as_float(((unsigned)h) << 16);
}

// exact GELU via Abramowitz-Stegun 7.1.26 erf (|eps| <= 1.5e-7)
__device__ __forceinline__ float gelu_f(float v) {
  const float x = fabsf(v) * 0.70710678118654752440f;
  const float t = 1.0f / fmaf(0.3275911f, x, 1.0f);
  float p = fmaf(fmaf(fmaf(fmaf(1.061405429f, t, -1.453152027f), t, 1.421413741f),
                      t, -0.284496736f), t, 0.254829592f);
  const float e = __expf(-x * x);
  const float er = 1.0f - p * t * e;
  return 0.5f * v * (1.0f + ((v < 0.f) ? -er : er));
}

__device__ __forceinline__ void gload16(const void* g, void* l) {
  __builtin_amdgcn_global_load_lds((const __attribute__((address_space(1))) void*)g,
                                   (__attribute__((address_space(3))) void*)l, 16, 0, 0);
}

__device__ __forceinline__ float2 cmulf(float2 a, float2 b) {
  return make_float2(a.x * b.x - a.y * b.y, a.x * b.y + a.y * b.x);
}
__device__ __forceinline__ float2 cadd(float2 a, float2 b) {
  return make_float2(a.x + b.x, a.y + b.y);
}
__device__ __forceinline__ float2 csub(float2 a, float2 b) {
  return make_float2(a.x - b.x, a.y - b.y);
}

// ---------------- batched transpose (B,R,C) -> (B,C,R) ----------------
__global__ __launch_bounds__(256) void k_transpose_g(const float* __restrict__ src,
                                                     float* __restrict__ dst,
                                                     int R, int C) {
  __shared__ float tile[32][33];
  const int b = blockIdx.z;
  const int c0 = blockIdx.x * 32;
  const int r0 = blockIdx.y * 32;
  const int tx = threadIdx.x & 31, ty = threadIdx.x >> 5;
  for (int i = ty; i < 32; i += 8)
    tile[i][tx] = src[((size_t)b * R + r0 + i) * C + c0 + tx];
  __syncthreads();
  for (int i = ty; i < 32; i += 8)
    dst[((size_t)b * C + c0 + i) * R + r0 + tx] = tile[tx][i];
}

// ---- fused prep: weight bf16 conv (4 mats) + filter bank + twiddles ----
constexpr int PREP_W = (NW_ + 255) / 256;
constexpr int PREP_WALL = 4 * PREP_W;
constexpr int PREP_FC = (NBINS_ * D_ + 255) / 256;
__global__ __launch_bounds__(256) void k_prep(
    const float* __restrict__ w0, const float* __restrict__ w1,
    const float* __restrict__ w2, const float* __restrict__ w3,
    unsigned short* __restrict__ wbf, const float2* __restrict__ e2,
    float2* __restrict__ FcT, float2* __restrict__ twg) {
  const int bid = blockIdx.x;
  if (bid < PREP_WALL) {
    const int m = bid / PREP_W;
    const int i = (bid - m * PREP_W) * 256 + threadIdx.x;
    if (i >= NW_) return;
    const float* src = (m == 0) ? w0 : (m == 1) ? w1 : (m == 2) ? w2 : w3;
    wbf[(size_t)m * NW_ + i] = f2bf(src[i]);
  } else if (bid < PREP_WALL + PREP_FC) {
    const int o = (bid - PREP_WALL) * 256 + threadIdx.x;
    if (o >= NBINS_ * D_) return;
    const int d = o / NBINS_;
    const int r = o - d * NBINS_;
    const int f = r / NFREQ_;
    const int k = r - f * NFREQ_;
    const int s = k * 9 + f;
    const float2 a = e2[(size_t)s * D_ + d];
    const float2 b = e2[(size_t)(NBINS_ + s) * D_ + d];
    FcT[o] = make_float2(-(a.x + b.x), -(a.y + b.y));
  } else {
    const int i = (bid - PREP_WALL - PREP_FC) * 256 + threadIdx.x;
    if (i >= 511) return;
    const int v = i + 1;
    const int h = 1 << (31 - __clz(v));
    const int j = v - h;
    float sn, cs;
    sincosf((float)j * ((TWOPI_ * 0.5f) / (float)h), &sn, &cs);
    twg[i] = make_float2(cs, sn);
  }
}

// ---- image forward DFT + filter + gate partials ----
__global__ __launch_bounds__(256) void k_img_dft_f(
    const float* __restrict__ image, const float2* __restrict__ bank2,
    const float2* __restrict__ gsel2, float2* __restrict__ imgF,
    float* __restrict__ part) {
  const int fg = blockIdx.x;
  const int f0 = fg * 9;
  const int d = blockIdx.y * 256 + threadIdx.x;
  const int b = blockIdx.z;
  __shared__ float2 tws[9 * N_];
  for (int idx = threadIdx.x; idx < 9 * N_; idx += 256) {
    const int fi = idx / N_;
    const int t = idx - fi * N_;
    const int r = ((f0 + fi) * t) % N_;
    float sn, cs;
    sincosf(TWOPI_ * (float)r / (float)N_, &sn, &cs);
    tws[idx] = make_float2(cs, sn);
  }
  __syncthreads();
  float re[9] = {}, im[9] = {};
  const float* ip = image + (size_t)b * N_ * D_ + d;
  for (int t = 0; t < N_; ++t) {
    const float v = ip[(size_t)t * D_];
#pragma unroll
    for (int fi = 0; fi < 9; ++fi) {
      const float2 w = tws[fi * N_ + t];
      re[fi] = fmaf(v, w.x, re[fi]);
      im[fi] = fmaf(-v, w.y, im[fi]);
    }
  }
  const float sc = 1.0f / (196.0f * 99.0f);
  float gp = 0.f;
#pragma unroll
  for (int fi = 0; fi < 9; ++fi) {
    const int f = f0 + fi;
    const float pr = (re[fi] * re[fi] - im[fi] * im[fi]) * sc;
    const float pi2 = (2.f * re[fi] * im[fi]) * sc;
    const size_t fd = (size_t)f * D_ + d;
    const float2 c0 = bank2[fd];
    const float2 c1 = bank2[(size_t)NF_ * D_ + fd];
    const float fcr = -(c0.x + c1.x), fci = -(c0.y + c1.y);
    const float zr = pr * fcr - pi2 * fci;
    const float zi = pr * fci + pi2 * fcr;
    imgF[(size_t)(b * NF_ + f) * D_ + d] = make_float2(zr, zi);
    const float2 gw = gsel2[fd];
    gp += zr * gw.x - zi * gw.y;
  }
  part[((size_t)b * 11 + fg) * D_ + d] = gp;
}

// ---- gate matvec, folds 11 partials: gate[b][d0..d0+16) ----
__global__ __launch_bounds__(256) void k_gate_mm2(const float* __restrict__ part,
                                                  const float* __restrict__ W,
                                                  const float* __restrict__ bias,
                                                  float* __restrict__ gate) {
  __shared__ float row[8][D_];
  __shared__ float red[16][16][8];
  const int tid = threadIdx.x;
  const int d0 = blockIdx.x * 16;
  for (int i = tid; i < 8 * D_; i += 256) {
    const int b = i / D_, e = i - b * D_;
    float s = 0.f;
    for (int p = 0; p < 11; ++p) s += part[((size_t)b * 11 + p) * D_ + e];
    row[b][e] = s * (1.0f / 99.0f);
  }
  __syncthreads();
  const int dl = tid >> 4;
  const int ec = tid & 15;
  const float* w = W + (size_t)(d0 + dl) * D_ + ec * 48;
  float acc[8] = {};
  for (int e = 0; e < 48; e += 4) {
    const float4 wv = *reinterpret_cast<const float4*>(w + e);
    const int eg = ec * 48 + e;
#pragma unroll
    for (int b = 0; b < 8; ++b) {
      acc[b] = fmaf(row[b][eg], wv.x, acc[b]);
      acc[b] = fmaf(row[b][eg + 1], wv.y, acc[b]);
      acc[b] = fmaf(row[b][eg + 2], wv.z, acc[b]);
      acc[b] = fmaf(row[b][eg + 3], wv.w, acc[b]);
    }
  }
#pragma unroll
  for (int b = 0; b < 8; ++b) red[dl][ec][b] = acc[b];
  __syncthreads();
  if (tid < 128) {
    const int dl2 = tid >> 3, b = tid & 7;
    float s = bias[d0 + dl2];
    for (int c = 0; c < 16; ++c) s += red[dl2][c][b];
    gate[b * D_ + d0 + dl2] = s;
  }
}

// ---- image inverse DFT (ortho) + residual ----
__global__ __launch_bounds__(256) void k_img_idft(
    const float2* __restrict__ imgF, const float* __restrict__ image,
    float* __restrict__ xi) {
  const int t0 = blockIdx.x * 14;
  const int d = blockIdx.y * 256 + threadIdx.x;
  const int b = blockIdx.z;
  __shared__ float2 tws[14 * NF_];
  for (int idx = threadIdx.x; idx < 14 * NF_; idx += 256) {
    const int ti = idx / NF_;
    const int f = idx - ti * NF_;
    const int r = ((t0 + ti) * f) % N_;
    float sn, cs;
    sincosf(TWOPI_ * (float)r / (float)N_, &sn, &cs);
    tws[idx] = make_float2(cs, sn);
  }
  __syncthreads();
  const float2* zp = imgF + (size_t)b * NF_ * D_ + d;
  const float2 z0 = zp[0];
  const float2 zny = zp[(size_t)(NF_ - 1) * D_];
  float acc[14];
#pragma unroll
  for (int ti = 0; ti < 14; ++ti)
    acc[ti] = z0.x + (((t0 + ti) & 1) ? -zny.x : zny.x);
  for (int f = 1; f < NF_ - 1; ++f) {
    const float2 z = zp[(size_t)f * D_];
#pragma unroll
    for (int ti = 0; ti < 14; ++ti) {
      const float2 w = tws[ti * NF_ + f];
      acc[ti] += 2.f * (z.x * w.x - z.y * w.y);
    }
  }
#pragma unroll
  for (int ti = 0; ti < 14; ++ti) {
    const size_t idx = (size_t)(b * N_ + t0 + ti) * D_ + d;
    xi[idx] = acc[ti] * (1.0f / 14.0f) + image[idx];
  }
}

// ---------------- LayerNorm f32 in -> bf16 out ----------------
__global__ __launch_bounds__(256) void k_layernorm_f2b(const float* __restrict__ x,
                                                       const float* __restrict__ g,
                                                       const float* __restrict__ b,
                                                       unsigned short* __restrict__ out) {
  const int row = blockIdx.x;
  const int tid = threadIdx.x;
  const float* xr = x + (size_t)row * D_;
  const float v0 = xr[tid], v1 = xr[tid + 256], v2 = xr[tid + 512];
  float s = v0 + v1 + v2;
  float q = v0 * v0 + v1 * v1 + v2 * v2;
  __shared__ float red[8];
  for (int off = 32; off > 0; off >>= 1) {
    s += __shfl_down(s, off);
    q += __shfl_down(q, off);
  }
  if ((tid & 63) == 0) { red[tid >> 6] = s; red[4 + (tid >> 6)] = q; }
  __syncthreads();
  s = red[0] + red[1] + red[2] + red[3];
  q = red[4] + red[5] + red[6] + red[7];
  const float mean = s * (1.0f / 768.0f);
  const float var = q * (1.0f / 768.0f) - mean * mean;
  const float inv = rsqrtf(var + 1e-5f);
  unsigned short* orow = out + (size_t)row * D_;
  orow[tid]       = f2bf((v0 - mean) * inv * g[tid]       + b[tid]);
  orow[tid + 256] = f2bf((v1 - mean) * inv * g[tid + 256] + b[tid + 256]);
  orow[tid + 512] = f2bf((v2 - mean) * inv * g[tid + 512] + b[tid + 512]);
}

// ================= ecg fused FFT pipeline (radix-8 passes, 1 wave/buffer) ======
// fused 3 radix-2 DIT stages (sub-size H -> 8H) in registers; in-place.
// wa = W_{2H}^j, wb = W_{4H}^j, wc = W_{8H}^j from table (+sin); sg applied here.
template <int H, int DIR, bool TRIV>
__device__ __forceinline__ void pass8(float2* z, int l,
                                      float2 wa, float2 wb, float2 wc) {
  asm volatile("s_waitcnt lgkmcnt(0)" ::: "memory");
  const float sg = (DIR < 0) ? -1.f : 1.f;
  const int base = (H == 1) ? (l << 3)
                 : (H == 8) ? (((l >> 3) << 6) | (l & 7))
                            : l;
  const float2 x0 = z[padz(base)],         x1 = z[padz(base + H)];
  const float2 x2 = z[padz(base + 2 * H)], x3 = z[padz(base + 3 * H)];
  const float2 x4 = z[padz(base + 4 * H)], x5 = z[padz(base + 5 * H)];
  const float2 x6 = z[padz(base + 6 * H)], x7 = z[padz(base + 7 * H)];
  const float2 WA = make_float2(wa.x, sg * wa.y);
  const float2 WB = make_float2(wb.x, sg * wb.y);
  const float2 WC = make_float2(wc.x, sg * wc.y);
  const float2 WBp = make_float2(-sg * WB.y, sg * WB.x);  // WB * W4
  // stage a: pairs (0,1)(2,3)(4,5)(6,7), twiddle WA
  float2 t, u;
  t = TRIV ? x1 : cmulf(x1, WA); const float2 A0 = cadd(x0, t), A1 = csub(x0, t);
  t = TRIV ? x3 : cmulf(x3, WA); const float2 A2 = cadd(x2, t), A3 = csub(x2, t);
  t = TRIV ? x5 : cmulf(x5, WA); const float2 A4 = cadd(x4, t), A5 = csub(x4, t);
  t = TRIV ? x7 : cmulf(x7, WA); const float2 A6 = cadd(x6, t), A7 = csub(x6, t);
  // stage b: (A0,A2)&(A1,A3) with WB, WB*W4 ; same for A4..A7
  t = TRIV ? A2 : cmulf(A2, WB);
  u = TRIV ? make_float2(-sg * A3.y, sg * A3.x) : cmulf(A3, WBp);
  const float2 B0 = cadd(A0, t), B2 = csub(A0, t);
  const float2 B1 = cadd(A1, u), B3 = csub(A1, u);
  t = TRIV ? A6 : cmulf(A6, WB);
  u = TRIV ? make_float2(-sg * A7.y, sg * A7.x) : cmulf(A7, WBp);
  const float2 B4 = cadd(A4, t), B6 = csub(A4, t);
  const float2 B5 = cadd(A5, u), B7 = csub(A5, u);
  // stage c: combine with factors WC * W8^t, W8 = (r, sg*r)
  const float r_ = 0.70710678118654752440f;
  const float2 F1 = TRIV ? make_float2(r_, sg * r_)
                         : cmulf(WC, make_float2(r_, sg * r_));
  const float2 F2 = TRIV ? make_float2(0.f, sg)
                         : make_float2(-sg * WC.y, sg * WC.x);
  const float2 F3 = TRIV ? make_float2(-r_, sg * r_)
                         : cmulf(WC, make_float2(-r_, sg * r_));
  t = TRIV ? B4 : cmulf(B4, WC);
  z[padz(base)]         = cadd(B0, t);
  z[padz(base + 4 * H)] = csub(B0, t);
  t = cmulf(B5, F1);
  z[padz(base + H)]     = cadd(B1, t);
  z[padz(base + 5 * H)] = csub(B1, t);
  t = cmulf(B6, F2);
  z[padz(base + 2 * H)] = cadd(B2, t);
  z[padz(base + 6 * H)] = csub(B2, t);
  t = cmulf(B7, F3);
  z[padz(base + 3 * H)] = cadd(B3, t);
  z[padz(base + 7 * H)] = csub(B3, t);
}

template <int FA, int FB>
__device__ __forceinline__ void filt_pack(const float2* z, int k, float g,
                                          float2 cA, float2 cB,
                                          float2& Ck, float2& Cm) {
  const int q = (512 - k) & 511;
  const float2 Zk = z[padz(k)], Zq = z[padz(q)];
  const float sc = 0.5f / 256.f;
  const float ar = (Zk.x + Zq.x) * sc, ai = (Zk.y - Zq.y) * sc;
  float yar, yai, ybr = 0.f, ybi = 0.f;
  {
    const float pr = (ar * ar - ai * ai) * (1.f / 2313.f);
    const float pi = (2.f * ar * ai) * (1.f / 2313.f);
    yar = (pr * cA.x - pi * cA.y) * g;
    yai = (pr * cA.y + pi * cA.x) * g;
  }
  if (FB >= 0) {
    const float br = (Zk.y + Zq.y) * sc, bi = (Zq.x - Zk.x) * sc;
    const float pr = (br * br - bi * bi) * (1.f / 2313.f);
    const float pi = (2.f * br * bi) * (1.f / 2313.f);
    ybr = (pr * cB.x - pi * cB.y) * g;
    ybi = (pr * cB.y + pi * cB.x) * g;
  }
  if (k == 0 || k == 256) {
    Ck = make_float2(yar, ybr);
    Cm = Ck;
  } else {
    Ck = make_float2(yar - ybi, yai + ybr);
    Cm = make_float2(yar + ybi, ybr - yai);
  }
}

template <int FA0, int FB0, int FA1, int FB1, bool DUAL>
__device__ __forceinline__ void ecg_super(int tid, float g, const float2* __restrict__ fc,
                                          const float (&s)[8], const float2 (&ptw)[6],
                                          float2 t8, float2* zA, float2* zB, float* accr) {
  const float c0 = t8.x;
  const float wlo = 0.5f - 0.5f * c0;
  const float whi = 0.5f + 0.5f * c0;
  const float2 cA0 = fc[FA0 * 257 + tid];
  float2 cB0 = make_float2(0.f, 0.f), cA1 = cB0, cB1 = cB0;
  if (FB0 >= 0) cB0 = fc[FB0 * 257 + tid];
  if (DUAL) { cA1 = fc[FA1 * 257 + tid]; cB1 = fc[FB1 * 257 + tid]; }
  float2 nA0 = make_float2(0.f, 0.f), nB0 = nA0, nA1 = nA0, nB1 = nA0;
  if (tid == 0) {
    nA0 = fc[FA0 * 257 + 256];
    if (FB0 >= 0) nB0 = fc[FB0 * 257 + 256];
    if (DUAL) { nA1 = fc[FA1 * 257 + 256]; nB1 = fc[FB1 * 257 + 256]; }
  }
  __syncthreads();
  {
    constexpr int iAlo = (FA0 > 0) ? FA0 - 1 : 0;
    constexpr int iAhi = (FA0 < 8) ? FA0 : 0;
    constexpr int iBlo = (FB0 > 0) ? FB0 - 1 : 0;
    constexpr int iBhi = (FB0 >= 0 && FB0 < 8) ? FB0 : 0;
    const int rlo = padz(rev9(tid)), rhi = padz(rev9(tid + 256));
    const float aLo = (FA0 == 0) ? 0.f : s[iAlo] * wlo;
    const float aHi = (FA0 == 8) ? 0.f : s[iAhi] * whi;
    const float bLo = (FB0 <= 0) ? 0.f : s[iBlo] * wlo;
    const float bHi = (FB0 < 0 || FB0 == 8) ? 0.f : s[iBhi] * whi;
    zA[rlo] = make_float2(aLo, bLo);
    zA[rhi] = make_float2(aHi, bHi);
    if (DUAL) {
      constexpr int jAlo = (FA1 > 0) ? FA1 - 1 : 0;
      constexpr int jAhi = (FA1 < 8) ? FA1 : 0;
      constexpr int jBlo = (FB1 > 0) ? FB1 - 1 : 0;
      constexpr int jBhi = (FB1 < 8) ? FB1 : 0;
      const float eLo = (FA1 == 0) ? 0.f : s[jAlo] * wlo;
      const float eHi = (FA1 == 8) ? 0.f : s[jAhi] * whi;
      const float fLo = (FB1 == 0) ? 0.f : s[jBlo] * wlo;
      const float fHi = (FB1 == 8) ? 0.f : s[jBhi] * whi;
      zB[rlo] = make_float2(eLo, fLo);
      zB[rhi] = make_float2(eHi, fHi);
    }
  }
  __syncthreads();
  // ---- forward FFT: 3 radix-8 passes, one wave per buffer ----
  if (tid < 64 || (DUAL && tid >= 128 && tid < 192)) {
    float2* zz = (tid < 64) ? zA : zB;
    const int l = tid & 63;
    pass8<1, -1, true>(zz, l, ptw[0], ptw[1], ptw[2]);
    pass8<8, -1, false>(zz, l, ptw[0], ptw[1], ptw[2]);
    pass8<64, -1, false>(zz, l, ptw[3], ptw[4], ptw[5]);
  }
  __syncthreads();
  float2 CAk, CAm, CBk, CBm;
  filt_pack<FA0, FB0>(zA, tid, g, cA0, cB0, CAk, CAm);
  float2 CAn, CBn, dum;
  if (tid == 0) filt_pack<FA0, FB0>(zA, 256, g, nA0, nB0, CAn, dum);
  if (DUAL) {
    filt_pack<FA1, FB1>(zB, tid, g, cA1, cB1, CBk, CBm);
    if (tid == 0) filt_pack<FA1, FB1>(zB, 256, g, nA1, nB1, CBn, dum);
  }
  __syncthreads();
  {
    const int rk = padz(rev9(tid));
    zA[rk] = CAk;
    if (DUAL) zB[rk] = CBk;
    if (tid == 0) {
      zA[padz(1)] = CAn;
      if (DUAL) zB[padz(1)] = CBn;
    } else {
      const int rm = padz(rev9(512 - tid));
      zA[rm] = CAm;
      if (DUAL) zB[rm] = CBm;
    }
  }
  __syncthreads();
  // ---- inverse FFT ----
  if (tid < 64 || (DUAL && tid >= 128 && tid < 192)) {
    float2* zz = (tid < 64) ? zA : zB;
    const int l = tid & 63;
    pass8<1, 1, true>(zz, l, ptw[0], ptw[1], ptw[2]);
    pass8<8, 1, false>(zz, l, ptw[0], ptw[1], ptw[2]);
    pass8<64, 1, false>(zz, l, ptw[3], ptw[4], ptw[5]);
  }
  __syncthreads();
  {
    const float2 vLo = zA[padz(tid)], vHi = zA[padz(tid + 256)];
    accr[FA0] += 0.5f * wlo * vLo.x;
    accr[FA0 + 1] += 0.5f * whi * vHi.x;
    if (FB0 >= 0) {
      accr[FB0] += 0.5f * wlo * vLo.y;
      accr[FB0 + 1] += 0.5f * whi * vHi.y;
    }
    if (DUAL) {
      const float2 uLo = zB[padz(tid)], uHi = zB[padz(tid + 256)];
      accr[FA1] += 0.5f * wlo * uLo.x;
      accr[FA1 + 1] += 0.5f * whi * uHi.x;
      accr[FB1] += 0.5f * wlo * uLo.y;
      accr[FB1 + 1] += 0.5f * whi * uHi.y;
    }
  }
}

__global__ __launch_bounds__(256) void k_ecg_fft(
    const float* __restrict__ ecgT, const float2* __restrict__ FcT,
    const float* __restrict__ gate, const float2* __restrict__ twg,
    unsigned short* __restrict__ xtT) {
  const int bd = blockIdx.x;
  const int d = bd % D_;
  const int tid = threadIdx.x;

  __shared__ float2 zA[544], zB[544];

  float s[8];
  const float* src = ecgT + (size_t)bd * S_;
#pragma unroll
  for (int k = 0; k < 8; ++k) s[k] = src[k * 256 + tid];

  // per-thread radix-8 pass twiddles (l = lane within buffer-wave)
  const int l6 = tid & 63;
  float2 ptw[6];
  ptw[0] = twg[7 + (l6 & 7)];     // H=8:  W_16^j
  ptw[1] = twg[15 + (l6 & 7)];    // H=8:  W_32^j
  ptw[2] = twg[31 + (l6 & 7)];    // H=8:  W_64^j
  ptw[3] = twg[63 + l6];          // H=64: W_128^j
  ptw[4] = twg[127 + l6];         // H=64: W_256^j
  ptw[5] = twg[255 + l6];         // H=64: W_512^j
  const float2 t8 = twg[255 + tid];  // window / norm only

  const float g = gate[bd];
  const float2* fc = FcT + (size_t)d * NBINS_;
  float accr[10];
#pragma unroll
  for (int i = 0; i < 10; ++i) accr[i] = 0.f;

  ecg_super<0, 8, 1, 2, true>(tid, g, fc, s, ptw, t8, zA, zB, accr);
  ecg_super<3, 4, 5, 6, true>(tid, g, fc, s, ptw, t8, zA, zB, accr);
  ecg_super<7, -1, 0, 0, false>(tid, g, fc, s, ptw, t8, zA, zB, accr);

  const float c0 = t8.x;
  const float rinv = 1.0f / (0.5f + 0.5f * c0 * c0);
  unsigned short* dst = xtT + (size_t)bd * S_;
#pragma unroll
  for (int i2 = 0; i2 < 8; ++i2)
    dst[i2 * 256 + tid] = f2bf(accr[i2 + 1] * rinv + s[i2]);
}

// ---- per-(b,t) LN stats over d, reading bf16 xtT[b][d][t] as uint pairs ----
__global__ __launch_bounds__(256) void k_colstats_bf(const unsigned short* __restrict__ xtT,
                                                     float2* __restrict__ stats) {
  const int b = blockIdx.y;
  const int t0 = blockIdx.x * 128;
  const int tx = threadIdx.x & 63;
  const int ty = threadIdx.x >> 6;
  float s0 = 0.f, q0 = 0.f, s1 = 0.f, q1 = 0.f;
  const unsigned int* base = (const unsigned int*)(xtT + (size_t)b * D_ * S_);
  for (int dd = ty; dd < D_; dd += 4) {
    const unsigned int u = base[(size_t)dd * (S_ / 2) + (t0 >> 1) + tx];
    const float v0 = bf2f((unsigned short)(u & 0xffffu));
    const float v1 = bf2f((unsigned short)(u >> 16));
    s0 += v0; q0 = fmaf(v0, v0, q0);
    s1 += v1; q1 = fmaf(v1, v1, q1);
  }
  __shared__ float sh[4][64][4];
  sh[ty][tx][0] = s0; sh[ty][tx][1] = q0; sh[ty][tx][2] = s1; sh[ty][tx][3] = q1;
  __syncthreads();
  if (ty == 0) {
    s0 = sh[0][tx][0] + sh[1][tx][0] + sh[2][tx][0] + sh[3][tx][0];
    q0 = sh[0][tx][1] + sh[1][tx][1] + sh[2][tx][1] + sh[3][tx][1];
    s1 = sh[0][tx][2] + sh[1][tx][2] + sh[2][tx][2] + sh[3][tx][2];
    q1 = sh[0][tx][3] + sh[1][tx][3] + sh[2][tx][3] + sh[3][tx][3];
    stats[(size_t)b * S_ + t0 + 2 * tx]     = make_float2(s0, q0);
    stats[(size_t)b * S_ + t0 + 2 * tx + 1] = make_float2(s1, q1);
  }
}

// ---- transpose + LN apply, bf16 in -> bf16 out ----
__global__ __launch_bounds__(256) void k_transpose_ln(
    const unsigned short* __restrict__ xtT, const float2* __restrict__ stats,
    const float* __restrict__ g, const float* __restrict__ bia,
    unsigned short* __restrict__ xhat) {
  __shared__ float tile[32][33];
  const int b = blockIdx.z;
  const int t0 = blockIdx.x * 32;
  const int d0 = blockIdx.y * 32;
  const int tx = threadIdx.x & 31, ty = threadIdx.x >> 5;
  for (int i = ty; i < 32; i += 8)
    tile[i][tx] = bf2f(xtT[((size_t)b * D_ + d0 + i) * S_ + t0 + tx]);
  __syncthreads();
  const float gv = g[d0 + tx], bv = bia[d0 + tx];
  for (int i = ty; i < 32; i += 8) {
    const float2 st = stats[(size_t)b * S_ + t0 + i];
    const float mean = st.x * (1.0f / 768.0f);
    const float var = st.y * (1.0f / 768.0f) - mean * mean;
    const float inv = rsqrtf(var + 1e-5f);
    xhat[((size_t)b * S_ + t0 + i) * D_ + d0 + tx] =
        f2bf((tile[tx][i] - mean) * inv * gv + bv);
  }
}

// ---------------- LayerNorm over D=768, bf16 in -> f32 out ----------------
__global__ __launch_bounds__(256) void k_layernorm_bf(const unsigned short* __restrict__ x,
                                                      const float* __restrict__ g,
                                                      const float* __restrict__ b,
                                                      float* __restrict__ out) {
  const int row = blockIdx.x;
  const int tid = threadIdx.x;
  const unsigned short* xr = x + (size_t)row * D_;
  const float v0 = bf2f(xr[tid]), v1 = bf2f(xr[tid + 256]), v2 = bf2f(xr[tid + 512]);
  float s = v0 + v1 + v2;
  float q = v0 * v0 + v1 * v1 + v2 * v2;
  __shared__ float red[8];
  for (int off = 32; off > 0; off >>= 1) {
    s += __shfl_down(s, off);
    q += __shfl_down(q, off);
  }
  if ((tid & 63) == 0) { red[tid >> 6] = s; red[4 + (tid >> 6)] = q; }
  __syncthreads();
  s = red[0] + red[1] + red[2] + red[3];
  q = red[4] + red[5] + red[6] + red[7];
  const float mean = s * (1.0f / 768.0f);
  const float var = q * (1.0f / 768.0f) - mean * mean;
  const float inv = rsqrtf(var + 1e-5f);
  float* orow = out + (size_t)row * D_;
  orow[tid]       = (v0 - mean) * inv * g[tid]       + b[tid];
  orow[tid + 256] = (v1 - mean) * inv * g[tid + 256] + b[tid + 256];
  orow[tid + 512] = (v2 - mean) * inv * g[tid + 512] + b[tid + 512];
}

// ---------- MFMA GEMM, double-buffered pipeline ----------
// MODE 0: exact GELU -> bf16 ; MODE 1: +resid(bf16) -> bf16
template <int MODE, bool SWZ>
__global__ __launch_bounds__(256) void k_gemm_mfma(
    const unsigned short* __restrict__ Abf, const unsigned short* __restrict__ Wbf,
    const float* __restrict__ bias, const unsigned short* __restrict__ resid,
    unsigned short* __restrict__ outb, int M) {
  __shared__ unsigned short Asm[2][128 * 64];
  __shared__ unsigned short Bsm[2][128 * 64];
  const int tid = threadIdx.x;
  const int lane = tid & 63, wid = tid >> 6;
  const int wr = wid >> 1, wc = wid & 1;
  int bx = blockIdx.x, by = blockIdx.y;
  if (SWZ) {
    const int nwg = gridDim.x * gridDim.y;
    const int bid = by * gridDim.x + bx;
    const int nbid = (bid % 8) * (nwg >> 3) + (bid >> 3);
    bx = nbid % gridDim.x;
    by = nbid / gridDim.x;
  }
  const int n0 = bx * 128, m0 = by * 128;

  auto STAGE = [&](int buf, int kt) {
    const int k0 = kt * 64;
#pragma unroll
    for (int i = 0; i < 4; ++i) {
      const int c = tid + 256 * i;
      const int row = c >> 3, sl = c & 7;
      const int gsl = sl ^ (row & 7);
      gload16(Abf + (size_t)(m0 + row) * 768 + k0 + gsl * 8, &Asm[buf][c * 8]);
      gload16(Wbf + (size_t)(n0 + row) * 768 + k0 + gsl * 8, &Bsm[buf][c * 8]);
    }
  };

  f32x4 acc[4][4] = {};
  STAGE(0, 0);
  for (int kt = 0; kt < 12; ++kt) {
    const int cur = kt & 1;
    if (kt < 11) {
      STAGE(cur ^ 1, kt + 1);
      asm volatile("s_waitcnt vmcnt(8)" ::: "memory");
    } else {
      asm volatile("s_waitcnt vmcnt(0)" ::: "memory");
    }
    __builtin_amdgcn_sched_barrier(0);
    __builtin_amdgcn_s_barrier();
#pragma unroll
    for (int ks = 0; ks < 2; ++ks) {
      bf16x8 af[4], bfv[4];
#pragma unroll
      for (int mi = 0; mi < 4; ++mi) {
        const int row = wr * 64 + mi * 16 + (lane & 15);
        const int sl = (ks * 4 + (lane >> 4)) ^ (row & 7);
        af[mi] = *(const bf16x8*)((const char*)Asm[cur] + row * 128 + sl * 16);
      }
#pragma unroll
      for (int ni = 0; ni < 4; ++ni) {
        const int row = wc * 64 + ni * 16 + (lane & 15);
        const int sl = (ks * 4 + (lane >> 4)) ^ (row & 7);
        bfv[ni] = *(const bf16x8*)((const char*)Bsm[cur] + row * 128 + sl * 16);
      }
#pragma unroll
      for (int mi = 0; mi < 4; ++mi)
#pragma unroll
        for (int ni = 0; ni < 4; ++ni)
          acc[mi][ni] = __builtin_amdgcn_mfma_f32_16x16x32_bf16(af[mi], bfv[ni],
                                                                acc[mi][ni], 0, 0, 0);
    }
    __builtin_amdgcn_sched_barrier(0);
    __builtin_amdgcn_s_barrier();
  }
#pragma unroll
  for (int mi = 0; mi < 4; ++mi) {
#pragma unroll
    for (int ni = 0; ni < 4; ++ni) {
      const int col = n0 + wc * 64 + ni * 16 + (lane & 15);
#pragma unroll
      for (int e = 0; e < 4; ++e) {
        const int row = m0 + wr * 64 + mi * 16 + (lane >> 4) * 4 + e;
        if (row >= M) continue;
        float v = acc[mi][ni][e] + bias[col];
        if (MODE == 0) {
          v = gelu_f(v);
        } else {
          v += bf2f(resid[(size_t)row * 768 + col]);
        }
        outb[(size_t)row * 768 + col] = f2bf(v);
      }
    }
  }
}

}  // namespace

extern "C" void kernel_launch(void* const* d_in, const int* in_sizes, int n_in,
                              void* d_out, int out_size, void* d_ws, size_t ws_size,
                              hipStream_t stream) {
  (void)in_sizes; (void)n_in; (void)out_size; (void)ws_size;
  const float* ecg     = (const float*)d_in[0];
  const float* image   = (const float*)d_in[1];
  const float* ebank   = (const float*)d_in[2];
  const float* cbank   = (const float*)d_in[3];
  const float* gsel    = (const float*)d_in[4];
  const float* gw      = (const float*)d_in[5];
  const float* gb      = (const float*)d_in[6];
  const float* e_ln1_g = (const float*)d_in[7];
  const float* e_ln1_b = (const float*)d_in[8];
  const float* e_w1    = (const float*)d_in[9];
  const float* e_b1    = (const float*)d_in[10];
  const float* e_w2    = (const float*)d_in[11];
  const float* e_b2    = (const float*)d_in[12];
  const float* e_ln2_g = (const float*)d_in[13];
  const float* e_ln2_b = (const float*)d_in[14];
  const float* c_ln1_g = (const float*)d_in[15];
  const float* c_ln1_b = (const float*)d_in[16];
  const float* c_w1    = (const float*)d_in[17];
  const float* c_b1    = (const float*)d_in[18];
  const float* c_w2    = (const float*)d_in[19];
  const float* c_b2    = (const float*)d_in[20];
  const float* c_ln2_g = (const float*)d_in[21];
  const float* c_ln2_b = (const float*)d_in[22];

  float* out = (float*)d_out;
  float* ws = (float*)d_ws;

  constexpr size_t TXT = (size_t)8 * 2048 * 768;
  constexpr size_t IMG = (size_t)8 * 196 * 768;

  // ws layout: A | Bb | wbf | gatev | stats | gpart | twg
  float* A  = ws;
  float* Bb = A + TXT;
  unsigned short* wbf = (unsigned short*)(Bb + TXT);
  unsigned short* ew1b = wbf;
  unsigned short* ew2b = wbf + NW_;
  unsigned short* cw1b = wbf + 2 * NW_;
  unsigned short* cw2b = wbf + 3 * NW_;
  float* gatev = (float*)(wbf + 4 * (size_t)NW_);
  float2* stats = (float2*)(gatev + 8 * 768);
  float* gpart = (float*)(stats + 8 * 2048);   // 8*11*768 floats
  float2* twg = (float2*)(gpart + 8 * 11 * 768);

  float2* FcT = (float2*)out;  // parked in d_out (dead before final LN)

  // image-path scratch inside A
  float* xi = A;
  unsigned short* xh_i = (unsigned short*)(A + IMG);
  unsigned short* h_i  = xh_i + IMG;
  unsigned short* y_ib = h_i + IMG;

  // text buffers
  unsigned short* xhat = (unsigned short*)A;           // bf16 LN1 / resid
  unsigned short* y_tb = (unsigned short*)A + TXT;     // bf16 pre-LN2
  unsigned short* xtT  = (unsigned short*)Bb;          // bf16 ecg_fft out [b][d][t]
  unsigned short* h_t  = (unsigned short*)Bb;          // bf16 GELU act (after xtT dead)

  // ---- one-time prep (fused) ----
  k_prep<<<PREP_WALL + PREP_FC + 2, 256, 0, stream>>>(
      e_w1, e_w2, c_w1, c_w2, wbf, (const float2*)ebank, FcT, twg);

  // ---- image path (produces gate) ----
  k_img_dft_f<<<dim3(11, 3, 8), 256, 0, stream>>>(image, (const float2*)cbank,
                                                  (const float2*)gsel,
                                                  (float2*)(A + 2 * IMG), gpart);
  k_gate_mm2<<<48, 256, 0, stream>>>(gpart, gw, gb, gatev);
  k_img_idft<<<dim3(14, 3, 8), 256, 0, stream>>>((const float2*)(A + 2 * IMG), image, xi);
  k_layernorm_f2b<<<1568, 256, 0, stream>>>(xi, c_ln1_g, c_ln1_b, xh_i);
  k_gemm_mfma<0, false><<<dim3(6, 13), 256, 0, stream>>>(xh_i, cw1b, c_b1, nullptr, h_i, 1568);
  k_gemm_mfma<1, false><<<dim3(6, 13), 256, 0, stream>>>(h_i, cw2b, c_b2, xh_i, y_ib, 1568);
  k_layernorm_bf<<<1568, 256, 0, stream>>>(y_ib, c_ln2_g, c_ln2_b, out + TXT);

  // ---- ecg path ----
  k_transpose_g<<<dim3(24, 64, 8), 256, 0, stream>>>(ecg, A, 2048, 768);
  k_ecg_fft<<<8 * 768, 256, 0, stream>>>(A, FcT, gatev, twg, xtT);
  k_colstats_bf<<<dim3(16, 8), 256, 0, stream>>>(xtT, stats);
  k_transpose_ln<<<dim3(64, 24, 8), 256, 0, stream>>>(xtT, stats, e_ln1_g, e_ln1_b, xhat);

  // ---- text FFN (bf16 MFMA, pipelined, XCD-swizzled) ----
  k_gemm_mfma<0, true><<<dim3(6, 128), 256, 0, stream>>>(xhat, ew1b, e_b1, nullptr, h_t, 16384);
  k_gemm_mfma<1, true><<<dim3(6, 128), 256, 0, stream>>>(h_t, ew2b, e_b2, xhat, y_tb, 16384);
  k_layernorm_bf<<<16384, 256, 0, stream>>>(y_tb, e_ln2_g, e_ln2_b, out);
}

// Round 11
// 413.512 us; speedup vs baseline: 7.6729x; 1.1477x over previous
//
#include <hip/hip_runtime.h>
#include <math.h>

namespace {

constexpr int B_ = 8;
constexpr int S_ = 2048;
constexpr int D_ = 768;
constexpr int N_ = 196;     // image spatial
constexpr int NF_ = 99;     // image freq bins
constexpr int NFREQ_ = 257;
constexpr int NSEG_ = 9;
constexpr int NBINS_ = NFREQ_ * NSEG_;  // 2313
constexpr int NW_ = D_ * D_;            // 589824
constexpr float TWOPI_ = 6.28318530717958647692f;

using bf16x8 = __attribute__((ext_vector_type(8))) short;
using f32x4  = __attribute__((ext_vector_type(4))) float;

__device__ __forceinline__ int rev9(int x) { return (int)(__brev((unsigned)x) >> 23); }
__device__ __forceinline__ int padz(int i) { return i + (i >> 4); }

__device__ __forceinline__ unsigned short f2bf(float x) {
  unsigned u = __float_as_uint(x);
  u = (u + 0x7FFFu + ((u >> 16) & 1u)) >> 16;
  return (unsigned short)u;
}
__device__ __forceinline__ float bf2f(unsigned short h) {
  return __uint_as_float(((unsigned)h) << 16);
}

// exact GELU via Abramowitz-Stegun 7.1.26 erf (|eps| <= 1.5e-7)
__device__ __forceinline__ float gelu_f(float v) {
  const float x = fabsf(v) * 0.70710678118654752440f;
  const float t = 1.0f / fmaf(0.3275911f, x, 1.0f);
  float p = fmaf(fmaf(fmaf(fmaf(1.061405429f, t, -1.453152027f), t, 1.421413741f),
                      t, -0.284496736f), t, 0.254829592f);
  const float e = __expf(-x * x);
  const float er = 1.0f - p * t * e;
  return 0.5f * v * (1.0f + ((v < 0.f) ? -er : er));
}

__device__ __forceinline__ void gload16(const void* g, void* l) {
  __builtin_amdgcn_global_load_lds((const __attribute__((address_space(1))) void*)g,
                                   (__attribute__((address_space(3))) void*)l, 16, 0, 0);
}

__device__ __forceinline__ float2 cmulf(float2 a, float2 b) {
  return make_float2(a.x * b.x - a.y * b.y, a.x * b.y + a.y * b.x);
}
__device__ __forceinline__ float2 cadd(float2 a, float2 b) {
  return make_float2(a.x + b.x, a.y + b.y);
}
__device__ __forceinline__ float2 csub(float2 a, float2 b) {
  return make_float2(a.x - b.x, a.y - b.y);
}

// ---------------- batched transpose (B,R,C) -> (B,C,R) ----------------
__global__ __launch_bounds__(256) void k_transpose_g(const float* __restrict__ src,
                                                     float* __restrict__ dst,
                                                     int R, int C) {
  __shared__ float tile[32][33];
  const int b = blockIdx.z;
  const int c0 = blockIdx.x * 32;
  const int r0 = blockIdx.y * 32;
  const int tx = threadIdx.x & 31, ty = threadIdx.x >> 5;
  for (int i = ty; i < 32; i += 8)
    tile[i][tx] = src[((size_t)b * R + r0 + i) * C + c0 + tx];
  __syncthreads();
  for (int i = ty; i < 32; i += 8)
    dst[((size_t)b * C + c0 + i) * R + r0 + tx] = tile[tx][i];
}

// ---- fused prep: weight bf16 conv (4 mats) + filter bank + twiddles ----
constexpr int PREP_W = (NW_ + 255) / 256;
constexpr int PREP_WALL = 4 * PREP_W;
constexpr int PREP_FC = (NBINS_ * D_ + 255) / 256;
__global__ __launch_bounds__(256) void k_prep(
    const float* __restrict__ w0, const float* __restrict__ w1,
    const float* __restrict__ w2, const float* __restrict__ w3,
    unsigned short* __restrict__ wbf, const float2* __restrict__ e2,
    float2* __restrict__ FcT, float2* __restrict__ twg) {
  const int bid = blockIdx.x;
  if (bid < PREP_WALL) {
    const int m = bid / PREP_W;
    const int i = (bid - m * PREP_W) * 256 + threadIdx.x;
    if (i >= NW_) return;
    const float* src = (m == 0) ? w0 : (m == 1) ? w1 : (m == 2) ? w2 : w3;
    wbf[(size_t)m * NW_ + i] = f2bf(src[i]);
  } else if (bid < PREP_WALL + PREP_FC) {
    const int o = (bid - PREP_WALL) * 256 + threadIdx.x;
    if (o >= NBINS_ * D_) return;
    const int d = o / NBINS_;
    const int r = o - d * NBINS_;
    const int f = r / NFREQ_;
    const int k = r - f * NFREQ_;
    const int s = k * 9 + f;
    const float2 a = e2[(size_t)s * D_ + d];
    const float2 b = e2[(size_t)(NBINS_ + s) * D_ + d];
    FcT[o] = make_float2(-(a.x + b.x), -(a.y + b.y));
  } else {
    const int i = (bid - PREP_WALL - PREP_FC) * 256 + threadIdx.x;
    if (i >= 511) return;
    const int v = i + 1;
    const int h = 1 << (31 - __clz(v));
    const int j = v - h;
    float sn, cs;
    sincosf((float)j * ((TWOPI_ * 0.5f) / (float)h), &sn, &cs);
    twg[i] = make_float2(cs, sn);
  }
}

// ---- image forward DFT + filter + gate partials ----
__global__ __launch_bounds__(256) void k_img_dft_f(
    const float* __restrict__ image, const float2* __restrict__ bank2,
    const float2* __restrict__ gsel2, float2* __restrict__ imgF,
    float* __restrict__ part) {
  const int fg = blockIdx.x;
  const int f0 = fg * 9;
  const int d = blockIdx.y * 256 + threadIdx.x;
  const int b = blockIdx.z;
  __shared__ float2 tws[9 * N_];
  for (int idx = threadIdx.x; idx < 9 * N_; idx += 256) {
    const int fi = idx / N_;
    const int t = idx - fi * N_;
    const int r = ((f0 + fi) * t) % N_;
    float sn, cs;
    sincosf(TWOPI_ * (float)r / (float)N_, &sn, &cs);
    tws[idx] = make_float2(cs, sn);
  }
  __syncthreads();
  float re[9] = {}, im[9] = {};
  const float* ip = image + (size_t)b * N_ * D_ + d;
  for (int t = 0; t < N_; ++t) {
    const float v = ip[(size_t)t * D_];
#pragma unroll
    for (int fi = 0; fi < 9; ++fi) {
      const float2 w = tws[fi * N_ + t];
      re[fi] = fmaf(v, w.x, re[fi]);
      im[fi] = fmaf(-v, w.y, im[fi]);
    }
  }
  const float sc = 1.0f / (196.0f * 99.0f);
  float gp = 0.f;
#pragma unroll
  for (int fi = 0; fi < 9; ++fi) {
    const int f = f0 + fi;
    const float pr = (re[fi] * re[fi] - im[fi] * im[fi]) * sc;
    const float pi2 = (2.f * re[fi] * im[fi]) * sc;
    const size_t fd = (size_t)f * D_ + d;
    const float2 c0 = bank2[fd];
    const float2 c1 = bank2[(size_t)NF_ * D_ + fd];
    const float fcr = -(c0.x + c1.x), fci = -(c0.y + c1.y);
    const float zr = pr * fcr - pi2 * fci;
    const float zi = pr * fci + pi2 * fcr;
    imgF[(size_t)(b * NF_ + f) * D_ + d] = make_float2(zr, zi);
    const float2 gw = gsel2[fd];
    gp += zr * gw.x - zi * gw.y;
  }
  part[((size_t)b * 11 + fg) * D_ + d] = gp;
}

// ---- gate matvec, folds 11 partials: gate[b][d0..d0+16) ----
__global__ __launch_bounds__(256) void k_gate_mm2(const float* __restrict__ part,
                                                  const float* __restrict__ W,
                                                  const float* __restrict__ bias,
                                                  float* __restrict__ gate) {
  __shared__ float row[8][D_];
  __shared__ float red[16][16][8];
  const int tid = threadIdx.x;
  const int d0 = blockIdx.x * 16;
  for (int i = tid; i < 8 * D_; i += 256) {
    const int b = i / D_, e = i - b * D_;
    float s = 0.f;
    for (int p = 0; p < 11; ++p) s += part[((size_t)b * 11 + p) * D_ + e];
    row[b][e] = s * (1.0f / 99.0f);
  }
  __syncthreads();
  const int dl = tid >> 4;
  const int ec = tid & 15;
  const float* w = W + (size_t)(d0 + dl) * D_ + ec * 48;
  float acc[8] = {};
  for (int e = 0; e < 48; e += 4) {
    const float4 wv = *reinterpret_cast<const float4*>(w + e);
    const int eg = ec * 48 + e;
#pragma unroll
    for (int b = 0; b < 8; ++b) {
      acc[b] = fmaf(row[b][eg], wv.x, acc[b]);
      acc[b] = fmaf(row[b][eg + 1], wv.y, acc[b]);
      acc[b] = fmaf(row[b][eg + 2], wv.z, acc[b]);
      acc[b] = fmaf(row[b][eg + 3], wv.w, acc[b]);
    }
  }
#pragma unroll
  for (int b = 0; b < 8; ++b) red[dl][ec][b] = acc[b];
  __syncthreads();
  if (tid < 128) {
    const int dl2 = tid >> 3, b = tid & 7;
    float s = bias[d0 + dl2];
    for (int c = 0; c < 16; ++c) s += red[dl2][c][b];
    gate[b * D_ + d0 + dl2] = s;
  }
}

// ---- image inverse DFT (ortho) + residual ----
__global__ __launch_bounds__(256) void k_img_idft(
    const float2* __restrict__ imgF, const float* __restrict__ image,
    float* __restrict__ xi) {
  const int t0 = blockIdx.x * 14;
  const int d = blockIdx.y * 256 + threadIdx.x;
  const int b = blockIdx.z;
  __shared__ float2 tws[14 * NF_];
  for (int idx = threadIdx.x; idx < 14 * NF_; idx += 256) {
    const int ti = idx / NF_;
    const int f = idx - ti * NF_;
    const int r = ((t0 + ti) * f) % N_;
    float sn, cs;
    sincosf(TWOPI_ * (float)r / (float)N_, &sn, &cs);
    tws[idx] = make_float2(cs, sn);
  }
  __syncthreads();
  const float2* zp = imgF + (size_t)b * NF_ * D_ + d;
  const float2 z0 = zp[0];
  const float2 zny = zp[(size_t)(NF_ - 1) * D_];
  float acc[14];
#pragma unroll
  for (int ti = 0; ti < 14; ++ti)
    acc[ti] = z0.x + (((t0 + ti) & 1) ? -zny.x : zny.x);
  for (int f = 1; f < NF_ - 1; ++f) {
    const float2 z = zp[(size_t)f * D_];
#pragma unroll
    for (int ti = 0; ti < 14; ++ti) {
      const float2 w = tws[ti * NF_ + f];
      acc[ti] += 2.f * (z.x * w.x - z.y * w.y);
    }
  }
#pragma unroll
  for (int ti = 0; ti < 14; ++ti) {
    const size_t idx = (size_t)(b * N_ + t0 + ti) * D_ + d;
    xi[idx] = acc[ti] * (1.0f / 14.0f) + image[idx];
  }
}

// ---------------- LayerNorm f32 in -> bf16 out ----------------
__global__ __launch_bounds__(256) void k_layernorm_f2b(const float* __restrict__ x,
                                                       const float* __restrict__ g,
                                                       const float* __restrict__ b,
                                                       unsigned short* __restrict__ out) {
  const int row = blockIdx.x;
  const int tid = threadIdx.x;
  const float* xr = x + (size_t)row * D_;
  const float v0 = xr[tid], v1 = xr[tid + 256], v2 = xr[tid + 512];
  float s = v0 + v1 + v2;
  float q = v0 * v0 + v1 * v1 + v2 * v2;
  __shared__ float red[8];
  for (int off = 32; off > 0; off >>= 1) {
    s += __shfl_down(s, off);
    q += __shfl_down(q, off);
  }
  if ((tid & 63) == 0) { red[tid >> 6] = s; red[4 + (tid >> 6)] = q; }
  __syncthreads();
  s = red[0] + red[1] + red[2] + red[3];
  q = red[4] + red[5] + red[6] + red[7];
  const float mean = s * (1.0f / 768.0f);
  const float var = q * (1.0f / 768.0f) - mean * mean;
  const float inv = rsqrtf(var + 1e-5f);
  unsigned short* orow = out + (size_t)row * D_;
  orow[tid]       = f2bf((v0 - mean) * inv * g[tid]       + b[tid]);
  orow[tid + 256] = f2bf((v1 - mean) * inv * g[tid + 256] + b[tid + 256]);
  orow[tid + 512] = f2bf((v2 - mean) * inv * g[tid + 512] + b[tid + 512]);
}

// ================= ecg fused FFT pipeline (radix-8, 4 buffers/block) ===========
template <int H, int DIR, bool TRIV>
__device__ __forceinline__ void pass8(float2* z, int l,
                                      float2 wa, float2 wb, float2 wc) {
  asm volatile("s_waitcnt lgkmcnt(0)" ::: "memory");
  const float sg = (DIR < 0) ? -1.f : 1.f;
  const int base = (H == 1) ? (l << 3)
                 : (H == 8) ? (((l >> 3) << 6) | (l & 7))
                            : l;
  const float2 x0 = z[padz(base)],         x1 = z[padz(base + H)];
  const float2 x2 = z[padz(base + 2 * H)], x3 = z[padz(base + 3 * H)];
  const float2 x4 = z[padz(base + 4 * H)], x5 = z[padz(base + 5 * H)];
  const float2 x6 = z[padz(base + 6 * H)], x7 = z[padz(base + 7 * H)];
  const float2 WA = make_float2(wa.x, sg * wa.y);
  const float2 WB = make_float2(wb.x, sg * wb.y);
  const float2 WC = make_float2(wc.x, sg * wc.y);
  const float2 WBp = make_float2(-sg * WB.y, sg * WB.x);  // WB * W4
  float2 t, u;
  t = TRIV ? x1 : cmulf(x1, WA); const float2 A0 = cadd(x0, t), A1 = csub(x0, t);
  t = TRIV ? x3 : cmulf(x3, WA); const float2 A2 = cadd(x2, t), A3 = csub(x2, t);
  t = TRIV ? x5 : cmulf(x5, WA); const float2 A4 = cadd(x4, t), A5 = csub(x4, t);
  t = TRIV ? x7 : cmulf(x7, WA); const float2 A6 = cadd(x6, t), A7 = csub(x6, t);
  t = TRIV ? A2 : cmulf(A2, WB);
  u = TRIV ? make_float2(-sg * A3.y, sg * A3.x) : cmulf(A3, WBp);
  const float2 B0 = cadd(A0, t), B2 = csub(A0, t);
  const float2 B1 = cadd(A1, u), B3 = csub(A1, u);
  t = TRIV ? A6 : cmulf(A6, WB);
  u = TRIV ? make_float2(-sg * A7.y, sg * A7.x) : cmulf(A7, WBp);
  const float2 B4 = cadd(A4, t), B6 = csub(A4, t);
  const float2 B5 = cadd(A5, u), B7 = csub(A5, u);
  const float r_ = 0.70710678118654752440f;
  const float2 F1 = TRIV ? make_float2(r_, sg * r_)
                         : cmulf(WC, make_float2(r_, sg * r_));
  const float2 F2 = TRIV ? make_float2(0.f, sg)
                         : make_float2(-sg * WC.y, sg * WC.x);
  const float2 F3 = TRIV ? make_float2(-r_, sg * r_)
                         : cmulf(WC, make_float2(-r_, sg * r_));
  t = TRIV ? B4 : cmulf(B4, WC);
  z[padz(base)]         = cadd(B0, t);
  z[padz(base + 4 * H)] = csub(B0, t);
  t = cmulf(B5, F1);
  z[padz(base + H)]     = cadd(B1, t);
  z[padz(base + 5 * H)] = csub(B1, t);
  t = cmulf(B6, F2);
  z[padz(base + 2 * H)] = cadd(B2, t);
  z[padz(base + 6 * H)] = csub(B2, t);
  t = cmulf(B7, F3);
  z[padz(base + 3 * H)] = cadd(B3, t);
  z[padz(base + 7 * H)] = csub(B3, t);
}

template <int FA, int FB>
__device__ __forceinline__ void scatter_buf(float2* z, const float (&s)[8],
                                            float wlo, float whi, int rlo, int rhi) {
  constexpr int iAlo = (FA > 0) ? FA - 1 : 0;
  constexpr int iAhi = (FA < 8) ? FA : 0;
  constexpr int iBlo = (FB > 0) ? FB - 1 : 0;
  constexpr int iBhi = (FB >= 0 && FB < 8) ? FB : 0;
  const float aLo = (FA == 0) ? 0.f : s[iAlo] * wlo;
  const float aHi = (FA == 8) ? 0.f : s[iAhi] * whi;
  const float bLo = (FB <= 0) ? 0.f : s[iBlo] * wlo;
  const float bHi = (FB < 0 || FB == 8) ? 0.f : s[iBhi] * whi;
  z[rlo] = make_float2(aLo, bLo);
  z[rhi] = make_float2(aHi, bHi);
}

template <int FA, int FB>
__device__ __forceinline__ void filt_pack(const float2* z, int k, float g,
                                          float2 cA, float2 cB,
                                          float2& Ck, float2& Cm) {
  const int q = (512 - k) & 511;
  const float2 Zk = z[padz(k)], Zq = z[padz(q)];
  const float sc = 0.5f / 256.f;
  const float ar = (Zk.x + Zq.x) * sc, ai = (Zk.y - Zq.y) * sc;
  float yar, yai, ybr = 0.f, ybi = 0.f;
  {
    const float pr = (ar * ar - ai * ai) * (1.f / 2313.f);
    const float pi = (2.f * ar * ai) * (1.f / 2313.f);
    yar = (pr * cA.x - pi * cA.y) * g;
    yai = (pr * cA.y + pi * cA.x) * g;
  }
  if (FB >= 0) {
    const float br = (Zk.y + Zq.y) * sc, bi = (Zq.x - Zk.x) * sc;
    const float pr = (br * br - bi * bi) * (1.f / 2313.f);
    const float pi = (2.f * br * bi) * (1.f / 2313.f);
    ybr = (pr * cB.x - pi * cB.y) * g;
    ybi = (pr * cB.y + pi * cB.x) * g;
  }
  if (k == 0 || k == 256) {
    Ck = make_float2(yar, ybr);
    Cm = Ck;
  } else {
    Ck = make_float2(yar - ybi, yai + ybr);
    Cm = make_float2(yar + ybi, ybr - yai);
  }
}

// one super-pass over up to 4 packed FFT buffers; wave w owns buffer w
template <int FA0, int FB0, int FA1, int FB1, int FA2, int FB2, int FA3, int FB3,
          int NBUF>
__device__ __forceinline__ void ecg_super4(int tid, float g,
                                           const float2* __restrict__ fc,
                                           const float (&s)[8], const float2 (&ptw)[6],
                                           float2 t8, float2* zA, float2* zB,
                                           float2* zC, float2* zD, float* accr) {
  const float c0 = t8.x;
  const float wlo = 0.5f - 0.5f * c0;
  const float whi = 0.5f + 0.5f * c0;
  // per-bin filter coefs (global prefetch)
  float2 cA0 = fc[FA0 * 257 + tid];
  float2 cB0 = make_float2(0.f, 0.f), cA1 = cB0, cB1 = cB0;
  float2 cA2 = cB0, cB2 = cB0, cA3 = cB0, cB3 = cB0;
  if (FB0 >= 0) cB0 = fc[FB0 * 257 + tid];
  if (NBUF > 1) { cA1 = fc[FA1 * 257 + tid]; cB1 = fc[FB1 * 257 + tid]; }
  if (NBUF > 2) { cA2 = fc[FA2 * 257 + tid]; cB2 = fc[FB2 * 257 + tid]; }
  if (NBUF > 3) { cA3 = fc[FA3 * 257 + tid]; cB3 = fc[FB3 * 257 + tid]; }
  __syncthreads();  // prior OA reads done before scatter overwrites
  const int rlo = padz(rev9(tid)), rhi = padz(rev9(tid + 256));
  scatter_buf<FA0, FB0>(zA, s, wlo, whi, rlo, rhi);
  if (NBUF > 1) scatter_buf<FA1, FB1>(zB, s, wlo, whi, rlo, rhi);
  if (NBUF > 2) scatter_buf<FA2, FB2>(zC, s, wlo, whi, rlo, rhi);
  if (NBUF > 3) scatter_buf<FA3, FB3>(zD, s, wlo, whi, rlo, rhi);
  __syncthreads();
  // ---- forward FFT: wave w -> buffer w ----
  const int wid = tid >> 6, l = tid & 63;
  if (wid < NBUF) {
    float2* zz = (wid == 0) ? zA : (wid == 1) ? zB : (wid == 2) ? zC : zD;
    pass8<1, -1, true>(zz, l, ptw[0], ptw[1], ptw[2]);
    pass8<8, -1, false>(zz, l, ptw[0], ptw[1], ptw[2]);
    pass8<64, -1, false>(zz, l, ptw[3], ptw[4], ptw[5]);
  }
  __syncthreads();
  // ---- filter + conjugate pack (registers) ----
  float2 Ck0, Cm0, Ck1, Cm1, Ck2, Cm2, Ck3, Cm3;
  float2 Cn0, Cn1, Cn2, Cn3, dum;
  filt_pack<FA0, FB0>(zA, tid, g, cA0, cB0, Ck0, Cm0);
  if (NBUF > 1) filt_pack<FA1, FB1>(zB, tid, g, cA1, cB1, Ck1, Cm1);
  if (NBUF > 2) filt_pack<FA2, FB2>(zC, tid, g, cA2, cB2, Ck2, Cm2);
  if (NBUF > 3) filt_pack<FA3, FB3>(zD, tid, g, cA3, cB3, Ck3, Cm3);
  if (tid == 0) {  // Nyquist bin (coefs loaded at use to save VGPR)
    float2 nA, nB = make_float2(0.f, 0.f);
    nA = fc[FA0 * 257 + 256];
    if (FB0 >= 0) nB = fc[FB0 * 257 + 256];
    filt_pack<FA0, FB0>(zA, 256, g, nA, nB, Cn0, dum);
    if (NBUF > 1) {
      nA = fc[FA1 * 257 + 256]; nB = fc[FB1 * 257 + 256];
      filt_pack<FA1, FB1>(zB, 256, g, nA, nB, Cn1, dum);
    }
    if (NBUF > 2) {
      nA = fc[FA2 * 257 + 256]; nB = fc[FB2 * 257 + 256];
      filt_pack<FA2, FB2>(zC, 256, g, nA, nB, Cn2, dum);
    }
    if (NBUF > 3) {
      nA = fc[FA3 * 257 + 256]; nB = fc[FB3 * 257 + 256];
      filt_pack<FA3, FB3>(zD, 256, g, nA, nB, Cn3, dum);
    }
  }
  __syncthreads();  // all Z reads done before pack-scatter
  {
    zA[rlo] = Ck0;
    if (NBUF > 1) zB[rlo] = Ck1;
    if (NBUF > 2) zC[rlo] = Ck2;
    if (NBUF > 3) zD[rlo] = Ck3;
    if (tid == 0) {
      zA[padz(1)] = Cn0;               // rev9(256) = 1
      if (NBUF > 1) zB[padz(1)] = Cn1;
      if (NBUF > 2) zC[padz(1)] = Cn2;
      if (NBUF > 3) zD[padz(1)] = Cn3;
    } else {
      const int rm = padz(rev9(512 - tid));
      zA[rm] = Cm0;
      if (NBUF > 1) zB[rm] = Cm1;
      if (NBUF > 2) zC[rm] = Cm2;
      if (NBUF > 3) zD[rm] = Cm3;
    }
  }
  __syncthreads();
  // ---- inverse FFT ----
  if (wid < NBUF) {
    float2* zz = (wid == 0) ? zA : (wid == 1) ? zB : (wid == 2) ? zC : zD;
    pass8<1, 1, true>(zz, l, ptw[0], ptw[1], ptw[2]);
    pass8<8, 1, false>(zz, l, ptw[0], ptw[1], ptw[2]);
    pass8<64, 1, false>(zz, l, ptw[3], ptw[4], ptw[5]);
  }
  __syncthreads();
  // ---- overlap-add ----
  {
    const float2 vLo = zA[padz(tid)], vHi = zA[padz(tid + 256)];
    accr[FA0] += 0.5f * wlo * vLo.x;
    accr[FA0 + 1] += 0.5f * whi * vHi.x;
    if (FB0 >= 0) {
      accr[FB0] += 0.5f * wlo * vLo.y;
      accr[FB0 + 1] += 0.5f * whi * vHi.y;
    }
    if (NBUF > 1) {
      const float2 uLo = zB[padz(tid)], uHi = zB[padz(tid + 256)];
      accr[FA1] += 0.5f * wlo * uLo.x;
      accr[FA1 + 1] += 0.5f * whi * uHi.x;
      accr[FB1] += 0.5f * wlo * uLo.y;
      accr[FB1 + 1] += 0.5f * whi * uHi.y;
    }
    if (NBUF > 2) {
      const float2 uLo = zC[padz(tid)], uHi = zC[padz(tid + 256)];
      accr[FA2] += 0.5f * wlo * uLo.x;
      accr[FA2 + 1] += 0.5f * whi * uHi.x;
      accr[FB2] += 0.5f * wlo * uLo.y;
      accr[FB2 + 1] += 0.5f * whi * uHi.y;
    }
    if (NBUF > 3) {
      const float2 uLo = zD[padz(tid)], uHi = zD[padz(tid + 256)];
      accr[FA3] += 0.5f * wlo * uLo.x;
      accr[FA3 + 1] += 0.5f * whi * uHi.x;
      accr[FB3] += 0.5f * wlo * uLo.y;
      accr[FB3 + 1] += 0.5f * whi * uHi.y;
    }
  }
}

__global__ __launch_bounds__(256) void k_ecg_fft(
    const float* __restrict__ ecgT, const float2* __restrict__ FcT,
    const float* __restrict__ gate, const float2* __restrict__ twg,
    unsigned short* __restrict__ xtT) {
  const int bd = blockIdx.x;
  const int d = bd % D_;
  const int tid = threadIdx.x;

  __shared__ float2 zA[544], zB[544], zC[544], zD[544];  // 17 KB

  float s[8];
  const float* src = ecgT + (size_t)bd * S_;
#pragma unroll
  for (int k = 0; k < 8; ++k) s[k] = src[k * 256 + tid];

  const int l6 = tid & 63;
  float2 ptw[6];
  ptw[0] = twg[7 + (l6 & 7)];     // H=8:  W_16^j
  ptw[1] = twg[15 + (l6 & 7)];    // H=8:  W_32^j
  ptw[2] = twg[31 + (l6 & 7)];    // H=8:  W_64^j
  ptw[3] = twg[63 + l6];          // H=64: W_128^j
  ptw[4] = twg[127 + l6];         // H=64: W_256^j
  ptw[5] = twg[255 + l6];         // H=64: W_512^j
  const float2 t8 = twg[255 + tid];  // window / norm only

  const float g = gate[bd];
  const float2* fc = FcT + (size_t)d * NBINS_;
  float accr[10];
#pragma unroll
  for (int i = 0; i < 10; ++i) accr[i] = 0.f;

  ecg_super4<0, 8, 1, 2, 3, 4, 5, 6, 4>(tid, g, fc, s, ptw, t8, zA, zB, zC, zD, accr);
  ecg_super4<7, -1, 0, 0, 0, 0, 0, 0, 1>(tid, g, fc, s, ptw, t8, zA, zB, zC, zD, accr);

  const float c0 = t8.x;
  const float rinv = 1.0f / (0.5f + 0.5f * c0 * c0);
  unsigned short* dst = xtT + (size_t)bd * S_;
#pragma unroll
  for (int i2 = 0; i2 < 8; ++i2)
    dst[i2 * 256 + tid] = f2bf(accr[i2 + 1] * rinv + s[i2]);
}

// ---- per-(b,t) LN stats over d, reading bf16 xtT[b][d][t] as uint pairs ----
__global__ __launch_bounds__(256) void k_colstats_bf(const unsigned short* __restrict__ xtT,
                                                     float2* __restrict__ stats) {
  const int b = blockIdx.y;
  const int t0 = blockIdx.x * 128;
  const int tx = threadIdx.x & 63;
  const int ty = threadIdx.x >> 6;
  float s0 = 0.f, q0 = 0.f, s1 = 0.f, q1 = 0.f;
  const unsigned int* base = (const unsigned int*)(xtT + (size_t)b * D_ * S_);
  for (int dd = ty; dd < D_; dd += 4) {
    const unsigned int u = base[(size_t)dd * (S_ / 2) + (t0 >> 1) + tx];
    const float v0 = bf2f((unsigned short)(u & 0xffffu));
    const float v1 = bf2f((unsigned short)(u >> 16));
    s0 += v0; q0 = fmaf(v0, v0, q0);
    s1 += v1; q1 = fmaf(v1, v1, q1);
  }
  __shared__ float sh[4][64][4];
  sh[ty][tx][0] = s0; sh[ty][tx][1] = q0; sh[ty][tx][2] = s1; sh[ty][tx][3] = q1;
  __syncthreads();
  if (ty == 0) {
    s0 = sh[0][tx][0] + sh[1][tx][0] + sh[2][tx][0] + sh[3][tx][0];
    q0 = sh[0][tx][1] + sh[1][tx][1] + sh[2][tx][1] + sh[3][tx][1];
    s1 = sh[0][tx][2] + sh[1][tx][2] + sh[2][tx][2] + sh[3][tx][2];
    q1 = sh[0][tx][3] + sh[1][tx][3] + sh[2][tx][3] + sh[3][tx][3];
    stats[(size_t)b * S_ + t0 + 2 * tx]     = make_float2(s0, q0);
    stats[(size_t)b * S_ + t0 + 2 * tx + 1] = make_float2(s1, q1);
  }
}

// ---- transpose + LN apply, bf16 in -> bf16 out ----
__global__ __launch_bounds__(256) void k_transpose_ln(
    const unsigned short* __restrict__ xtT, const float2* __restrict__ stats,
    const float* __restrict__ g, const float* __restrict__ bia,
    unsigned short* __restrict__ xhat) {
  __shared__ float tile[32][33];
  const int b = blockIdx.z;
  const int t0 = blockIdx.x * 32;
  const int d0 = blockIdx.y * 32;
  const int tx = threadIdx.x & 31, ty = threadIdx.x >> 5;
  for (int i = ty; i < 32; i += 8)
    tile[i][tx] = bf2f(xtT[((size_t)b * D_ + d0 + i) * S_ + t0 + tx]);
  __syncthreads();
  const float gv = g[d0 + tx], bv = bia[d0 + tx];
  for (int i = ty; i < 32; i += 8) {
    const float2 st = stats[(size_t)b * S_ + t0 + i];
    const float mean = st.x * (1.0f / 768.0f);
    const float var = st.y * (1.0f / 768.0f) - mean * mean;
    const float inv = rsqrtf(var + 1e-5f);
    xhat[((size_t)b * S_ + t0 + i) * D_ + d0 + tx] =
        f2bf((tile[tx][i] - mean) * inv * gv + bv);
  }
}

// ---- dual-segment LayerNorm, bf16 in -> f32 out ----
__global__ __launch_bounds__(256) void k_layernorm_dual(
    const unsigned short* __restrict__ x1, const float* __restrict__ g1,
    const float* __restrict__ b1, float* __restrict__ o1, int n1,
    const unsigned short* __restrict__ x2, const float* __restrict__ g2,
    const float* __restrict__ b2, float* __restrict__ o2) {
  int row = blockIdx.x;
  const unsigned short* x; const float *g, *b; float* o;
  if (row < n1) { x = x1; g = g1; b = b1; o = o1; }
  else { row -= n1; x = x2; g = g2; b = b2; o = o2; }
  const int tid = threadIdx.x;
  const unsigned short* xr = x + (size_t)row * D_;
  const float v0 = bf2f(xr[tid]), v1 = bf2f(xr[tid + 256]), v2 = bf2f(xr[tid + 512]);
  float s = v0 + v1 + v2;
  float q = v0 * v0 + v1 * v1 + v2 * v2;
  __shared__ float red[8];
  for (int off = 32; off > 0; off >>= 1) {
    s += __shfl_down(s, off);
    q += __shfl_down(q, off);
  }
  if ((tid & 63) == 0) { red[tid >> 6] = s; red[4 + (tid >> 6)] = q; }
  __syncthreads();
  s = red[0] + red[1] + red[2] + red[3];
  q = red[4] + red[5] + red[6] + red[7];
  const float mean = s * (1.0f / 768.0f);
  const float var = q * (1.0f / 768.0f) - mean * mean;
  const float inv = rsqrtf(var + 1e-5f);
  float* orow = o + (size_t)row * D_;
  orow[tid]       = (v0 - mean) * inv * g[tid]       + b[tid];
  orow[tid + 256] = (v1 - mean) * inv * g[tid + 256] + b[tid + 256];
  orow[tid + 512] = (v2 - mean) * inv * g[tid + 512] + b[tid + 512];
}

// ---------- dual-segment MFMA GEMM, double-buffered pipeline ----------
// MODE 0: exact GELU -> bf16 ; MODE 1: +resid(bf16) -> bf16
template <int MODE>
__global__ __launch_bounds__(256) void k_gemm_dual(
    const unsigned short* __restrict__ A1, const unsigned short* __restrict__ W1,
    const float* __restrict__ b1, const unsigned short* __restrict__ r1,
    unsigned short* __restrict__ o1, int M1, int nby1,
    const unsigned short* __restrict__ A2, const unsigned short* __restrict__ W2,
    const float* __restrict__ b2, const unsigned short* __restrict__ r2,
    unsigned short* __restrict__ o2, int M2) {
  __shared__ unsigned short Asm[2][128 * 64];
  __shared__ unsigned short Bsm[2][128 * 64];
  const int tid = threadIdx.x;
  const int lane = tid & 63, wid = tid >> 6;
  const int wr = wid >> 1, wc = wid & 1;
  // bijective XCD swizzle for arbitrary nwg (m204 variant)
  int bx, by;
  {
    const int nwg = gridDim.x * gridDim.y;
    const int bid = blockIdx.y * gridDim.x + blockIdx.x;
    const int xcd = bid & 7, lin = bid >> 3;
    const int qq = nwg >> 3, rr = nwg & 7;
    const int nbid = (xcd < rr) ? xcd * (qq + 1) + lin
                                : rr * (qq + 1) + (xcd - rr) * qq + lin;
    bx = nbid % gridDim.x;
    by = nbid / gridDim.x;
  }
  const unsigned short* Abf; const unsigned short* Wbf; const float* bias;
  const unsigned short* resid; unsigned short* outb; int M;
  if (by < nby1) { Abf = A1; Wbf = W1; bias = b1; resid = r1; outb = o1; M = M1; }
  else { by -= nby1; Abf = A2; Wbf = W2; bias = b2; resid = r2; outb = o2; M = M2; }
  const int n0 = bx * 128, m0 = by * 128;

  auto STAGE = [&](int buf, int kt) {
    const int k0 = kt * 64;
#pragma unroll
    for (int i = 0; i < 4; ++i) {
      const int c = tid + 256 * i;
      const int row = c >> 3, sl = c & 7;
      const int gsl = sl ^ (row & 7);
      gload16(Abf + (size_t)(m0 + row) * 768 + k0 + gsl * 8, &Asm[buf][c * 8]);
      gload16(Wbf + (size_t)(n0 + row) * 768 + k0 + gsl * 8, &Bsm[buf][c * 8]);
    }
  };

  f32x4 acc[4][4] = {};
  STAGE(0, 0);
  for (int kt = 0; kt < 12; ++kt) {
    const int cur = kt & 1;
    if (kt < 11) {
      STAGE(cur ^ 1, kt + 1);
      asm volatile("s_waitcnt vmcnt(8)" ::: "memory");
    } else {
      asm volatile("s_waitcnt vmcnt(0)" ::: "memory");
    }
    __builtin_amdgcn_sched_barrier(0);
    __builtin_amdgcn_s_barrier();
#pragma unroll
    for (int ks = 0; ks < 2; ++ks) {
      bf16x8 af[4], bfv[4];
#pragma unroll
      for (int mi = 0; mi < 4; ++mi) {
        const int row = wr * 64 + mi * 16 + (lane & 15);
        const int sl = (ks * 4 + (lane >> 4)) ^ (row & 7);
        af[mi] = *(const bf16x8*)((const char*)Asm[cur] + row * 128 + sl * 16);
      }
#pragma unroll
      for (int ni = 0; ni < 4; ++ni) {
        const int row = wc * 64 + ni * 16 + (lane & 15);
        const int sl = (ks * 4 + (lane >> 4)) ^ (row & 7);
        bfv[ni] = *(const bf16x8*)((const char*)Bsm[cur] + row * 128 + sl * 16);
      }
#pragma unroll
      for (int mi = 0; mi < 4; ++mi)
#pragma unroll
        for (int ni = 0; ni < 4; ++ni)
          acc[mi][ni] = __builtin_amdgcn_mfma_f32_16x16x32_bf16(af[mi], bfv[ni],
                                                                acc[mi][ni], 0, 0, 0);
    }
    __builtin_amdgcn_sched_barrier(0);
    __builtin_amdgcn_s_barrier();
  }
#pragma unroll
  for (int mi = 0; mi < 4; ++mi) {
#pragma unroll
    for (int ni = 0; ni < 4; ++ni) {
      const int col = n0 + wc * 64 + ni * 16 + (lane & 15);
#pragma unroll
      for (int e = 0; e < 4; ++e) {
        const int row = m0 + wr * 64 + mi * 16 + (lane >> 4) * 4 + e;
        if (row >= M) continue;
        float v = acc[mi][ni][e] + bias[col];
        if (MODE == 0) {
          v = gelu_f(v);
        } else {
          v += bf2f(resid[(size_t)row * 768 + col]);
        }
        outb[(size_t)row * 768 + col] = f2bf(v);
      }
    }
  }
}

}  // namespace

extern "C" void kernel_launch(void* const* d_in, const int* in_sizes, int n_in,
                              void* d_out, int out_size, void* d_ws, size_t ws_size,
                              hipStream_t stream) {
  (void)in_sizes; (void)n_in; (void)out_size; (void)ws_size;
  const float* ecg     = (const float*)d_in[0];
  const float* image   = (const float*)d_in[1];
  const float* ebank   = (const float*)d_in[2];
  const float* cbank   = (const float*)d_in[3];
  const float* gsel    = (const float*)d_in[4];
  const float* gw      = (const float*)d_in[5];
  const float* gb      = (const float*)d_in[6];
  const float* e_ln1_g = (const float*)d_in[7];
  const float* e_ln1_b = (const float*)d_in[8];
  const float* e_w1    = (const float*)d_in[9];
  const float* e_b1    = (const float*)d_in[10];
  const float* e_w2    = (const float*)d_in[11];
  const float* e_b2    = (const float*)d_in[12];
  const float* e_ln2_g = (const float*)d_in[13];
  const float* e_ln2_b = (const float*)d_in[14];
  const float* c_ln1_g = (const float*)d_in[15];
  const float* c_ln1_b = (const float*)d_in[16];
  const float* c_w1    = (const float*)d_in[17];
  const float* c_b1    = (const float*)d_in[18];
  const float* c_w2    = (const float*)d_in[19];
  const float* c_b2    = (const float*)d_in[20];
  const float* c_ln2_g = (const float*)d_in[21];
  const float* c_ln2_b = (const float*)d_in[22];

  float* out = (float*)d_out;
  float* ws = (float*)d_ws;

  constexpr size_t TXT = (size_t)8 * 2048 * 768;   // 12,582,912 floats
  constexpr size_t IMG = (size_t)8 * 196 * 768;    // 1,204,224 elems

  // ws layout: A | Bb | wbf | gatev | stats | gpart | twg
  float* A  = ws;
  float* Bb = A + TXT;
  unsigned short* wbf = (unsigned short*)(Bb + TXT);
  unsigned short* ew1b = wbf;
  unsigned short* ew2b = wbf + NW_;
  unsigned short* cw1b = wbf + 2 * NW_;
  unsigned short* cw2b = wbf + 3 * NW_;
  float* gatev = (float*)(wbf + 4 * (size_t)NW_);
  float2* stats = (float2*)(gatev + 8 * 768);
  float* gpart = (float*)(stats + 8 * 2048);   // 8*11*768 floats
  float2* twg = (float2*)(gpart + 8 * 11 * 768);

  float2* FcT = (float2*)out;  // parked in d_out (dead before final LN)

  // text buffers: A = xhat (first half, bf16) | y_tb (second half, bf16)
  unsigned short* xhat = (unsigned short*)A;
  unsigned short* y_tb = (unsigned short*)A + TXT;
  // Bb first half: xtT then h_t (bf16); second half: image scratch
  unsigned short* xtT = (unsigned short*)Bb;
  unsigned short* h_t = (unsigned short*)Bb;
  float* Bb2 = Bb + TXT / 2;
  float2* imgF = (float2*)Bb2;                               // 1,216,512 floats
  float* xi = Bb2 + 1216512;                                 // 1,204,224 floats
  unsigned short* xh_i = (unsigned short*)(xi + IMG);        // bf16 LN1 / resid
  unsigned short* h_i  = xh_i + IMG;
  unsigned short* y_ib = h_i + IMG;

  // ---- one-time prep (fused) ----
  k_prep<<<PREP_WALL + PREP_FC + 2, 256, 0, stream>>>(
      e_w1, e_w2, c_w1, c_w2, wbf, (const float2*)ebank, FcT, twg);

  // ---- image path front (produces gate + xh_i) ----
  k_img_dft_f<<<dim3(11, 3, 8), 256, 0, stream>>>(image, (const float2*)cbank,
                                                  (const float2*)gsel, imgF, gpart);
  k_gate_mm2<<<48, 256, 0, stream>>>(gpart, gw, gb, gatev);
  k_img_idft<<<dim3(14, 3, 8), 256, 0, stream>>>(imgF, image, xi);
  k_layernorm_f2b<<<1568, 256, 0, stream>>>(xi, c_ln1_g, c_ln1_b, xh_i);

  // ---- ecg path ----
  k_transpose_g<<<dim3(24, 64, 8), 256, 0, stream>>>(ecg, A, 2048, 768);
  k_ecg_fft<<<8 * 768, 256, 0, stream>>>(A, FcT, gatev, twg, xtT);
  k_colstats_bf<<<dim3(16, 8), 256, 0, stream>>>(xtT, stats);
  k_transpose_ln<<<dim3(64, 24, 8), 256, 0, stream>>>(xtT, stats, e_ln1_g, e_ln1_b, xhat);

  // ---- combined FFN: text (128 by-blocks) + image (13 by-blocks) ----
  k_gemm_dual<0><<<dim3(6, 141), 256, 0, stream>>>(
      xhat, ew1b, e_b1, nullptr, h_t, 16384, 128,
      xh_i, cw1b, c_b1, nullptr, h_i, 1568);
  k_gemm_dual<1><<<dim3(6, 141), 256, 0, stream>>>(
      h_t, ew2b, e_b2, xhat, y_tb, 16384, 128,
      h_i, cw2b, c_b2, xh_i, y_ib, 1568);
  k_layernorm_dual<<<16384 + 1568, 256, 0, stream>>>(
      y_tb, e_ln2_g, e_ln2_b, out, 16384,
      y_ib, c_ln2_g, c_ln2_b, out + TXT);
}